// Round 4
// baseline (2898.860 us; speedup 1.0000x reference)
//
#include <hip/hip_runtime.h>
#include <hip/hip_bf16.h>

#define N_NODES 100000
#define N_EDGES 3200000
#define HID 16
#define NB 256       // buckets (one per CU-ish); bucket = NPB consecutive nodes
#define NPB 391      // 256*391 = 100096 >= 100000
#define SCAP 15360   // pass-1 per-bucket staging cap (mean 12500, +25 sigma)
#define RCAP 15360   // pass-2 per-bucket staging cap
#define FDEPTH 32    // LDS FIFO depth in split kernels
#define LCAP1 8704   // bsort1 LDS chunk entries (12 B) -> ~104 KB
#define LCAP2 13312  // rsort LDS chunk entries (8 B) -> ~106 KB

static constexpr int BLK = 256;

__device__ __forceinline__ float frelu(float x) { return fmaxf(x, 0.f); }
__device__ __forceinline__ float bflo(unsigned int u) {
  return __uint_as_float(u << 16);
}
__device__ __forceinline__ float bfhi(unsigned int u) {
  return __uint_as_float(u & 0xFFFF0000u);
}

union E16 {
  float4 f4[2];
  __hip_bfloat16 h[16];
};

// ---------------------------------------------------------------------------
// K0: norm = max |edges_init|
// ---------------------------------------------------------------------------
__global__ __launch_bounds__(256) void k_norm(const float* __restrict__ edges,
                                              unsigned int* __restrict__ normbits) {
  float m = 0.f;
  for (int i = blockIdx.x * blockDim.x + threadIdx.x; i < N_EDGES;
       i += gridDim.x * blockDim.x)
    m = fmaxf(m, fabsf(edges[i]));
#pragma unroll
  for (int off = 32; off > 0; off >>= 1)
    m = fmaxf(m, __shfl_down(m, off, 64));
  __shared__ float smax[BLK / 64];
  if ((threadIdx.x & 63) == 0) smax[threadIdx.x >> 6] = m;
  __syncthreads();
  if (threadIdx.x == 0) {
    float b = smax[0];
#pragma unroll
    for (int w = 1; w < BLK / 64; ++w) b = fmaxf(b, smax[w]);
    atomicMax(normbits, __float_as_uint(b));
  }
}

// ---------------------------------------------------------------------------
// K1: bucket edges by SENDER via LDS FIFOs (line-granular flushes).
// record: m = (sender_local<<22) | orig_edge(22b), v = edges_init, o = recv
// ---------------------------------------------------------------------------
__global__ __launch_bounds__(1024) void k_split(
    const int* __restrict__ senders, const int* __restrict__ receivers,
    const float* __restrict__ edges, int* __restrict__ gcnt,
    unsigned int* __restrict__ pM, float* __restrict__ pV,
    unsigned int* __restrict__ pO) {
  __shared__ __align__(16) unsigned int fM[NB][FDEPTH];
  __shared__ __align__(16) unsigned int fV[NB][FDEPTH];
  __shared__ __align__(16) unsigned int fO[NB][FDEPTH];
  __shared__ int fcnt[NB];
  const int t = threadIdx.x;
  if (t < NB) fcnt[t] = 0;
  __syncthreads();
  const int e0 = blockIdx.x * (N_EDGES / 256);
  const int e1 = e0 + (N_EDGES / 256);
  for (int base = e0; base < e1; base += 1024) {
    const int i = base + t;
    if (i < e1) {
      int s = senders[i];
      unsigned int b = (unsigned int)s / NPB;
      unsigned int m = (((unsigned int)s - b * NPB) << 22) | (unsigned int)i;
      unsigned int v = __float_as_uint(edges[i]);
      unsigned int o = (unsigned int)receivers[i];
      int pos = atomicAdd(&fcnt[b], 1);
      if (pos < FDEPTH) {
        fM[b][pos] = m; fV[b][pos] = v; fO[b][pos] = o;
      } else {  // rare overflow: direct append
        int gb = atomicAdd(&gcnt[b], 1);
        if (gb < SCAP) {
          pM[(size_t)b * SCAP + gb] = m;
          pV[(size_t)b * SCAP + gb] = __uint_as_float(v);
          pO[(size_t)b * SCAP + gb] = o;
        }
      }
    }
    __syncthreads();
    const bool last = (base + 1024 >= e1);
    if (t < NB) {
      int c = fcnt[t]; if (c > FDEPTH) c = FDEPTH;
      int nf = last ? c : (c & ~15);
      if (nf > 0) {
        int gb = atomicAdd(&gcnt[t], nf);
        size_t db = (size_t)t * SCAP + gb;
        if ((gb & 3) == 0 && gb + nf <= SCAP) {
          int k = 0;
          for (; k + 4 <= nf; k += 4) {
            *(uint4*)(pM + db + k) = *(const uint4*)(&fM[t][k]);
            *(uint4*)((unsigned int*)pV + db + k) = *(const uint4*)(&fV[t][k]);
            *(uint4*)(pO + db + k) = *(const uint4*)(&fO[t][k]);
          }
          for (; k < nf; ++k) {
            pM[db + k] = fM[t][k]; pV[db + k] = __uint_as_float(fV[t][k]);
            pO[db + k] = fO[t][k];
          }
        } else {
          for (int k = 0; k < nf; ++k)
            if (gb + k < SCAP) {
              pM[db + k] = fM[t][k]; pV[db + k] = __uint_as_float(fV[t][k]);
              pO[db + k] = fO[t][k];
            }
        }
        int res = c - nf;
        for (int k = 0; k < res; ++k) {
          fM[t][k] = fM[t][nf + k]; fV[t][k] = fV[t][nf + k];
          fO[t][k] = fO[t][nf + k];
        }
        fcnt[t] = res;
      } else fcnt[t] = c;
    }
    __syncthreads();
  }
}

// ---------------------------------------------------------------------------
// K2: per-bucket counting sort by sender_local -> EXACT global sender CSR.
// Writes srecv/sorig/sval in sorted order + soff. No degree caps.
// ---------------------------------------------------------------------------
__global__ __launch_bounds__(1024) void k_bsort1(
    const unsigned int* __restrict__ pM, const float* __restrict__ pV,
    const unsigned int* __restrict__ pO, const int* __restrict__ gcnt,
    unsigned int* __restrict__ srecv, unsigned int* __restrict__ sorig,
    float* __restrict__ sval, int* __restrict__ soff) {
  __shared__ unsigned int sM[LCAP1];
  __shared__ float sV[LCAP1];
  __shared__ unsigned int sO[LCAP1];
  __shared__ int hist[NPB], pref[NPB + 1], sc[NPB], cur[NPB];
  __shared__ int bb[NB];
  __shared__ int base_s;
  const int b = blockIdx.x, t = threadIdx.x, nt = blockDim.x;
  if (t < NB) { int c = gcnt[t]; bb[t] = c > SCAP ? SCAP : c; }
  for (int k = t; k < NPB; k += nt) hist[k] = 0;
  __syncthreads();
  if (t == 0) { int s = 0; for (int k = 0; k < b; ++k) s += bb[k]; base_s = s; }
  int nb = gcnt[b]; if (nb > SCAP) nb = SCAP;
  const unsigned int* PM = pM + (size_t)b * SCAP;
  const float* PV = pV + (size_t)b * SCAP;
  const unsigned int* PO = pO + (size_t)b * SCAP;
  for (int i = t; i < nb; i += nt) atomicAdd(&hist[PM[i] >> 22], 1);
  __syncthreads();
  if (t < NPB) sc[t] = hist[t];
  __syncthreads();
  for (int d = 1; d < NPB; d <<= 1) {
    int add = 0;
    if (t < NPB && t >= d) add = sc[t - d];
    __syncthreads();
    if (t < NPB && t >= d) sc[t] += add;
    __syncthreads();
  }
  if (t < NPB) pref[t] = sc[t] - hist[t];
  if (t == 0) pref[NPB] = sc[NPB - 1];
  __syncthreads();
  const int base = base_s;
  const int node0 = b * NPB;
  for (int k = t; k < NPB; k += nt) {
    int n = node0 + k;
    if (n < N_NODES) soff[n] = base + pref[k];
  }
  if (b == NB - 1 && t == 0) soff[N_NODES] = base + nb;
  __syncthreads();
  int klo = 0;
  while (klo < NPB) {
    int base0 = pref[klo];
    int khi = klo;
    while (khi < NPB && pref[khi + 1] - base0 <= LCAP1) ++khi;
    if (khi == klo) khi = klo + 1;  // safety (cannot happen: deg << LCAP1)
    for (int k = klo + t; k < khi; k += nt) cur[k] = pref[k];
    __syncthreads();
    for (int i = t; i < nb; i += nt) {
      unsigned int m = PM[i];
      int key = (int)(m >> 22);
      if (key >= klo && key < khi) {
        int p = atomicAdd(&cur[key], 1) - base0;
        if (p < LCAP1) { sM[p] = m; sV[p] = PV[i]; sO[p] = PO[i]; }
      }
    }
    __syncthreads();
    int csz = pref[khi] - base0;
    for (int i = t; i < csz; i += nt) {
      int g = base + base0 + i;
      srecv[g] = sO[i]; sorig[g] = sM[i] & 0x3FFFFFu; sval[g] = sV[i];
    }
    __syncthreads();
    klo = khi;
  }
}

// ---------------------------------------------------------------------------
// K3: fill ssend[i] = sender of sorted edge i (node-major, coalesced)
// ---------------------------------------------------------------------------
__global__ __launch_bounds__(256) void k_sfill(const int* __restrict__ soff,
                                               unsigned int* __restrict__ ssend) {
  int wave = (blockIdx.x * blockDim.x + threadIdx.x) >> 6;
  int lane = threadIdx.x & 63, half = lane >> 5, l32 = lane & 31;
  int n = wave * 2 + half;
  int s0 = soff[n], s1 = soff[n + 1];
  for (int k = s0 + l32; k < s1; k += 32) ssend[k] = (unsigned int)n;
}

// ---------------------------------------------------------------------------
// K4: bucket sorted edges by RECEIVER (carries sorted idx + sender)
// ---------------------------------------------------------------------------
__global__ __launch_bounds__(1024) void k_rsplit(
    const unsigned int* __restrict__ srecv, const unsigned int* __restrict__ ssend,
    int* __restrict__ gcnt2, unsigned int* __restrict__ rpA,
    unsigned int* __restrict__ rpB) {
  __shared__ __align__(16) unsigned int fA[NB][FDEPTH];
  __shared__ __align__(16) unsigned int fB[NB][FDEPTH];
  __shared__ int fcnt[NB];
  const int t = threadIdx.x;
  if (t < NB) fcnt[t] = 0;
  __syncthreads();
  const int e0 = blockIdx.x * (N_EDGES / 256);
  const int e1 = e0 + (N_EDGES / 256);
  for (int base = e0; base < e1; base += 1024) {
    const int i = base + t;
    if (i < e1) {
      unsigned int r = srecv[i];
      unsigned int b = r / NPB;
      unsigned int a = ((r - b * NPB) << 22) | (unsigned int)i;
      unsigned int s = ssend[i];
      int pos = atomicAdd(&fcnt[b], 1);
      if (pos < FDEPTH) {
        fA[b][pos] = a; fB[b][pos] = s;
      } else {
        int gb = atomicAdd(&gcnt2[b], 1);
        if (gb < RCAP) {
          rpA[(size_t)b * RCAP + gb] = a; rpB[(size_t)b * RCAP + gb] = s;
        }
      }
    }
    __syncthreads();
    const bool last = (base + 1024 >= e1);
    if (t < NB) {
      int c = fcnt[t]; if (c > FDEPTH) c = FDEPTH;
      int nf = last ? c : (c & ~15);
      if (nf > 0) {
        int gb = atomicAdd(&gcnt2[t], nf);
        size_t db = (size_t)t * RCAP + gb;
        if ((gb & 3) == 0 && gb + nf <= RCAP) {
          int k = 0;
          for (; k + 4 <= nf; k += 4) {
            *(uint4*)(rpA + db + k) = *(const uint4*)(&fA[t][k]);
            *(uint4*)(rpB + db + k) = *(const uint4*)(&fB[t][k]);
          }
          for (; k < nf; ++k) { rpA[db + k] = fA[t][k]; rpB[db + k] = fB[t][k]; }
        } else {
          for (int k = 0; k < nf; ++k)
            if (gb + k < RCAP) { rpA[db + k] = fA[t][k]; rpB[db + k] = fB[t][k]; }
        }
        int res = c - nf;
        for (int k = 0; k < res; ++k) { fA[t][k] = fA[t][nf + k]; fB[t][k] = fB[t][nf + k]; }
        fcnt[t] = res;
      } else fcnt[t] = c;
    }
    __syncthreads();
  }
}

// ---------------------------------------------------------------------------
// K5: per-bucket counting sort by recv_local -> receiver CSR (roff) +
// packed rlist: A = (sortedidx<<10)|(sender&1023), B(u8) = sender>>10
// ---------------------------------------------------------------------------
__global__ __launch_bounds__(1024) void k_rsort(
    const unsigned int* __restrict__ rpA, const unsigned int* __restrict__ rpB,
    const int* __restrict__ gcnt2, unsigned int* __restrict__ rlistA,
    unsigned char* __restrict__ rlistB, int* __restrict__ roff) {
  __shared__ unsigned int sA[LCAP2];
  __shared__ unsigned int sB[LCAP2];
  __shared__ int hist[NPB], pref[NPB + 1], sc[NPB], cur[NPB];
  __shared__ int bb[NB];
  __shared__ int base_s;
  const int b = blockIdx.x, t = threadIdx.x, nt = blockDim.x;
  if (t < NB) { int c = gcnt2[t]; bb[t] = c > RCAP ? RCAP : c; }
  for (int k = t; k < NPB; k += nt) hist[k] = 0;
  __syncthreads();
  if (t == 0) { int s = 0; for (int k = 0; k < b; ++k) s += bb[k]; base_s = s; }
  int nb = gcnt2[b]; if (nb > RCAP) nb = RCAP;
  const unsigned int* PA = rpA + (size_t)b * RCAP;
  const unsigned int* PB = rpB + (size_t)b * RCAP;
  for (int i = t; i < nb; i += nt) atomicAdd(&hist[PA[i] >> 22], 1);
  __syncthreads();
  if (t < NPB) sc[t] = hist[t];
  __syncthreads();
  for (int d = 1; d < NPB; d <<= 1) {
    int add = 0;
    if (t < NPB && t >= d) add = sc[t - d];
    __syncthreads();
    if (t < NPB && t >= d) sc[t] += add;
    __syncthreads();
  }
  if (t < NPB) pref[t] = sc[t] - hist[t];
  if (t == 0) pref[NPB] = sc[NPB - 1];
  __syncthreads();
  const int base = base_s;
  const int node0 = b * NPB;
  for (int k = t; k < NPB; k += nt) {
    int n = node0 + k;
    if (n < N_NODES) roff[n] = base + pref[k];
  }
  if (b == NB - 1 && t == 0) roff[N_NODES] = base + nb;
  __syncthreads();
  int klo = 0;
  while (klo < NPB) {
    int base0 = pref[klo];
    int khi = klo;
    while (khi < NPB && pref[khi + 1] - base0 <= LCAP2) ++khi;
    if (khi == klo) khi = klo + 1;
    for (int k = klo + t; k < khi; k += nt) cur[k] = pref[k];
    __syncthreads();
    for (int i = t; i < nb; i += nt) {
      unsigned int a = PA[i];
      int key = (int)(a >> 22);
      if (key >= klo && key < khi) {
        int p = atomicAdd(&cur[key], 1) - base0;
        if (p < LCAP2) { sA[p] = a; sB[p] = PB[i]; }
      }
    }
    __syncthreads();
    int csz = pref[khi] - base0;
    for (int i = t; i < csz; i += nt) {
      int g = base + base0 + i;
      unsigned int sidx = sA[i] & 0x3FFFFFu;
      unsigned int snd = sB[i];
      rlistA[g] = (sidx << 10) | (snd & 1023u);
      rlistB[g] = (unsigned char)(snd >> 10);
    }
    __syncthreads();
    klo = khi;
  }
}

// ---------------------------------------------------------------------------
// K6: edge encoder (1 -> HID -> HID) in sorted order, coalesced.
// ---------------------------------------------------------------------------
__global__ __launch_bounds__(256) void k_encode(
    const float* __restrict__ sval, const float* __restrict__ w1,
    const float* __restrict__ b1, const float* __restrict__ w2,
    const float* __restrict__ b2, const unsigned int* __restrict__ normbits,
    unsigned short* __restrict__ e) {
  int i = blockIdx.x * blockDim.x + threadIdx.x;
  float norm = __uint_as_float(*normbits);
  float x = sval[i] / norm;
  float h[HID];
#pragma unroll
  for (int j = 0; j < HID; ++j) h[j] = frelu(fmaf(w1[j], x, b1[j]));
  E16 o;
#pragma unroll
  for (int j = 0; j < HID; ++j) {
    float acc = b2[j];
#pragma unroll
    for (int k = 0; k < HID; ++k) acc = fmaf(w2[j * HID + k], h[k], acc);
    o.h[j] = __float2bfloat16(acc);
  }
  float4* ep = (float4*)(e + (size_t)i * HID);
  ep[0] = o.f4[0];
  ep[1] = o.f4[1];
}

// ---------------------------------------------------------------------------
// K7 (kA): receiver-side aggregate. 2 nodes/wave, 2 lanes/entry (16 B each,
// 1 line per entry -> minimal scattered transactions). REC=1: recompute this
// round's edge MLP on the fly (e buffer holds previous features).
// ---------------------------------------------------------------------------
template <int REC>
__global__ __launch_bounds__(256) void k_aggR(
    const unsigned short* __restrict__ e, const int* __restrict__ roff,
    const unsigned int* __restrict__ rlistA,
    const unsigned char* __restrict__ rlistB, const float* __restrict__ nodesr,
    const float* __restrict__ w1, const float* __restrict__ b1,
    const float* __restrict__ w2, const float* __restrict__ b2,
    float* __restrict__ aggR) {
  int wave = (blockIdx.x * blockDim.x + threadIdx.x) >> 6;
  int lane = threadIdx.x & 63, half = lane >> 5, l32 = lane & 31;
  int sub = l32 & 1, j16 = l32 >> 1;
  int n = wave * 2 + half;
  int r0 = roff[n], rdeg = roff[n + 1] - r0;
  float nrv = REC ? nodesr[n] : 0.f;
  float acc[8] = {0, 0, 0, 0, 0, 0, 0, 0};
  for (int s0 = 0; s0 < rdeg; s0 += 16) {
    int slot = s0 + j16;
    bool ok = slot < rdeg;
    int idx = r0 + (ok ? slot : 0);
    unsigned int a = rlistA[idx];
    unsigned int si = a >> 10;
    uint4 raw = *(const uint4*)(e + (size_t)si * HID + sub * 8);
    float xm[8] = {bflo(raw.x), bfhi(raw.x), bflo(raw.y), bfhi(raw.y),
                   bflo(raw.z), bfhi(raw.z), bflo(raw.w), bfhi(raw.w)};
    if (REC) {
      unsigned int snd = (((unsigned int)rlistB[idx]) << 10) | (a & 1023u);
      float nsv = nodesr[snd];
      float xo[8];
#pragma unroll
      for (int c = 0; c < 8; ++c) xo[c] = __shfl_xor(xm[c], 1, 64);
      float x[16];
#pragma unroll
      for (int c = 0; c < 8; ++c) {
        x[sub * 8 + c] = xm[c];
        x[(1 - sub) * 8 + c] = xo[c];
      }
      float h[8];
#pragma unroll
      for (int j = 0; j < 8; ++j) {
        int row = sub * 8 + j;
        float a1 = b1[row];
#pragma unroll
        for (int k = 0; k < 16; ++k) a1 = fmaf(w1[row * 18 + k], x[k], a1);
        a1 = fmaf(w1[row * 18 + 16], nsv, a1);
        a1 = fmaf(w1[row * 18 + 17], nrv, a1);
        h[j] = frelu(a1);
      }
      float ho[8];
#pragma unroll
      for (int j = 0; j < 8; ++j) ho[j] = __shfl_xor(h[j], 1, 64);
      float hf[16];
#pragma unroll
      for (int j = 0; j < 8; ++j) {
        hf[sub * 8 + j] = h[j];
        hf[(1 - sub) * 8 + j] = ho[j];
      }
#pragma unroll
      for (int c = 0; c < 8; ++c) {
        int row = sub * 8 + c;
        float a2 = b2[row];
#pragma unroll
        for (int k = 0; k < 16; ++k) a2 = fmaf(w2[row * HID + k], hf[k], a2);
        acc[c] += ok ? a2 : 0.f;
      }
    } else {
#pragma unroll
      for (int c = 0; c < 8; ++c) acc[c] += ok ? xm[c] : 0.f;
    }
  }
#pragma unroll
  for (int off = 16; off >= 2; off >>= 1)
#pragma unroll
    for (int c = 0; c < 8; ++c) acc[c] += __shfl_down(acc[c], off, 64);
  if (l32 < 2) {
    *(float4*)(aggR + (size_t)n * 16 + sub * 8) =
        make_float4(acc[0], acc[1], acc[2], acc[3]);
    *(float4*)(aggR + (size_t)n * 16 + sub * 8 + 4) =
        make_float4(acc[4], acc[5], acc[6], acc[7]);
  }
}

// ---------------------------------------------------------------------------
// K8 (kB): sender-side stream + (REC: edge MLP recompute + in-place e write)
// + fused node MLP. 2 nodes/wave, 1 lane/edge (contiguous run).
// ---------------------------------------------------------------------------
template <int REC>
__global__ __launch_bounds__(256) void k_nodeup(
    unsigned short* __restrict__ e, const int* __restrict__ soff,
    const unsigned int* __restrict__ srecv, const float* __restrict__ aggR,
    const float* __restrict__ nodesr, const float* __restrict__ ew1,
    const float* __restrict__ eb1, const float* __restrict__ ew2,
    const float* __restrict__ eb2, const float* __restrict__ nw1,
    const float* __restrict__ nb1_, const float* __restrict__ nw2,
    const float* __restrict__ nb2_, float* __restrict__ nodesw) {
  int wave = (blockIdx.x * blockDim.x + threadIdx.x) >> 6;
  int lane = threadIdx.x & 63, half = lane >> 5, l32 = lane & 31;
  int n = wave * 2 + half;
  int s0 = soff[n], sdeg = soff[n + 1] - s0;
  float nsv = nodesr[n];
  float accS[16];
#pragma unroll
  for (int c = 0; c < 16; ++c) accS[c] = 0.f;
  for (int c0 = 0; c0 < sdeg; c0 += 32) {
    int k = c0 + l32;
    bool ok = k < sdeg;
    int idx = s0 + (ok ? k : 0);
    uint4 ra = *(const uint4*)(e + (size_t)idx * HID);
    uint4 rb = *(const uint4*)(e + (size_t)idx * HID + 8);
    float x[16] = {bflo(ra.x), bfhi(ra.x), bflo(ra.y), bfhi(ra.y),
                   bflo(ra.z), bfhi(ra.z), bflo(ra.w), bfhi(ra.w),
                   bflo(rb.x), bfhi(rb.x), bflo(rb.y), bfhi(rb.y),
                   bflo(rb.z), bfhi(rb.z), bflo(rb.w), bfhi(rb.w)};
    if (REC) {
      float nrv = nodesr[srecv[idx]];
      float h[16];
#pragma unroll
      for (int j = 0; j < 16; ++j) {
        float a1 = eb1[j];
#pragma unroll
        for (int kk = 0; kk < 16; ++kk) a1 = fmaf(ew1[j * 18 + kk], x[kk], a1);
        a1 = fmaf(ew1[j * 18 + 16], nsv, a1);
        a1 = fmaf(ew1[j * 18 + 17], nrv, a1);
        h[j] = frelu(a1);
      }
      float y[16];
#pragma unroll
      for (int c = 0; c < 16; ++c) {
        float a2 = eb2[c];
#pragma unroll
        for (int j = 0; j < 16; ++j) a2 = fmaf(ew2[c * HID + j], h[j], a2);
        y[c] = a2;
      }
      if (ok) {
        E16 o;
#pragma unroll
        for (int c = 0; c < 16; ++c) o.h[c] = __float2bfloat16(y[c]);
        *(float4*)(e + (size_t)idx * HID) = o.f4[0];
        *(float4*)(e + (size_t)idx * HID + 8) = o.f4[1];
      }
#pragma unroll
      for (int c = 0; c < 16; ++c) accS[c] += ok ? y[c] : 0.f;
    } else {
#pragma unroll
      for (int c = 0; c < 16; ++c) accS[c] += ok ? x[c] : 0.f;
    }
  }
#pragma unroll
  for (int off = 16; off >= 1; off >>= 1)
#pragma unroll
    for (int c = 0; c < 16; ++c) accS[c] += __shfl_down(accS[c], off, 64);
  float aS[16];
#pragma unroll
  for (int c = 0; c < 16; ++c) aS[c] = __shfl(accS[c], half * 32, 64);
  float pv = 0.f;
  if (l32 < 16) {
    int j = l32;
    float a1 = fmaf(nw1[j * 33], nsv, nb1_[j]);
#pragma unroll
    for (int k = 0; k < 16; ++k) a1 = fmaf(nw1[j * 33 + 1 + k], aS[k], a1);
#pragma unroll
    for (int k = 0; k < 16; ++k)
      a1 = fmaf(nw1[j * 33 + 17 + k], aggR[(size_t)n * 16 + k], a1);
    pv = nw2[j] * frelu(a1);
  }
#pragma unroll
  for (int off = 8; off >= 1; off >>= 1) pv += __shfl_down(pv, off, 64);
  if (l32 == 0) nodesw[n] = pv + nb2_[0];
}

// ---------------------------------------------------------------------------
// K9: final — round-3 edge MLP + decoder + out = edges_init + alpha*e*norm.
// Node-major sender runs; one scattered 4 B store per edge.
// ---------------------------------------------------------------------------
__global__ __launch_bounds__(256) void k_final(
    const unsigned short* __restrict__ e, const int* __restrict__ soff,
    const unsigned int* __restrict__ srecv, const unsigned int* __restrict__ sorig,
    const float* __restrict__ sval, const float* __restrict__ nodes,
    const float* __restrict__ ew1, const float* __restrict__ eb1,
    const float* __restrict__ ew2, const float* __restrict__ eb2,
    const float* __restrict__ dw1, const float* __restrict__ db1,
    const float* __restrict__ dw2, const float* __restrict__ db2,
    const unsigned int* __restrict__ normbits, const float* __restrict__ alpha,
    float* __restrict__ out) {
  int wave = (blockIdx.x * blockDim.x + threadIdx.x) >> 6;
  int lane = threadIdx.x & 63, half = lane >> 5, l32 = lane & 31;
  int n = wave * 2 + half;
  int s0 = soff[n], sdeg = soff[n + 1] - s0;
  float nsv = nodes[n];
  float alphaN = alpha[0] * __uint_as_float(*normbits);
  for (int c0 = 0; c0 < sdeg; c0 += 32) {
    int k = c0 + l32;
    bool ok = k < sdeg;
    int idx = s0 + (ok ? k : 0);
    uint4 ra = *(const uint4*)(e + (size_t)idx * HID);
    uint4 rb = *(const uint4*)(e + (size_t)idx * HID + 8);
    float x[16] = {bflo(ra.x), bfhi(ra.x), bflo(ra.y), bfhi(ra.y),
                   bflo(ra.z), bfhi(ra.z), bflo(ra.w), bfhi(ra.w),
                   bflo(rb.x), bfhi(rb.x), bflo(rb.y), bfhi(rb.y),
                   bflo(rb.z), bfhi(rb.z), bflo(rb.w), bfhi(rb.w)};
    float nrv = nodes[srecv[idx]];
    float h[16];
#pragma unroll
    for (int j = 0; j < 16; ++j) {
      float a1 = eb1[j];
#pragma unroll
      for (int kk = 0; kk < 16; ++kk) a1 = fmaf(ew1[j * 18 + kk], x[kk], a1);
      a1 = fmaf(ew1[j * 18 + 16], nsv, a1);
      a1 = fmaf(ew1[j * 18 + 17], nrv, a1);
      h[j] = frelu(a1);
    }
    float y[16];
#pragma unroll
    for (int c = 0; c < 16; ++c) {
      float a2 = eb2[c];
#pragma unroll
      for (int j = 0; j < 16; ++j) a2 = fmaf(ew2[c * HID + j], h[j], a2);
      y[c] = a2;
    }
    float d = db2[0];
#pragma unroll
    for (int j = 0; j < 16; ++j) {
      float a1 = db1[j];
#pragma unroll
      for (int kk = 0; kk < 16; ++kk) a1 = fmaf(dw1[j * HID + kk], y[kk], a1);
      d = fmaf(dw2[j], frelu(a1), d);
    }
    if (ok) out[sorig[idx]] = fmaf(alphaN, d, sval[idx]);
  }
}

// ---------------------------------------------------------------------------
extern "C" void kernel_launch(void* const* d_in, const int* in_sizes, int n_in,
                              void* d_out, int out_size, void* d_ws,
                              size_t ws_size, hipStream_t stream) {
  const float* nodes0 = (const float*)d_in[0];
  const float* edges0 = (const float*)d_in[1];
  const int* senders = (const int*)d_in[2];
  const int* receivers = (const int*)d_in[3];
  const float* enc_w1 = (const float*)d_in[4];
  const float* enc_b1 = (const float*)d_in[5];
  const float* enc_w2 = (const float*)d_in[6];
  const float* enc_b2 = (const float*)d_in[7];
  const float* node_w1 = (const float*)d_in[8];
  const float* node_b1 = (const float*)d_in[9];
  const float* node_w2 = (const float*)d_in[10];
  const float* node_b2 = (const float*)d_in[11];
  const float* edge_w1 = (const float*)d_in[12];
  const float* edge_b1 = (const float*)d_in[13];
  const float* edge_w2 = (const float*)d_in[14];
  const float* edge_b2 = (const float*)d_in[15];
  const float* dec_w1 = (const float*)d_in[16];
  const float* dec_b1 = (const float*)d_in[17];
  const float* dec_w2 = (const float*)d_in[18];
  const float* dec_b2 = (const float*)d_in[19];
  const float* alpha = (const float*)d_in[20];

  // Workspace layout: 164.8 MB total (< proven 167.6 MB budget).
  char* ws = (char*)d_ws;
  unsigned short* e = (unsigned short*)ws;  // 3.2M x 32 B = 102.4 MB (sorted)
  char* p = ws + (size_t)N_EDGES * HID * 2;
  unsigned int* srecv = (unsigned int*)p;  p += (size_t)N_EDGES * 4;  // 12.8
  unsigned int* sorig = (unsigned int*)p;  p += (size_t)N_EDGES * 4;  // 12.8
  float* sval = (float*)p;                 p += (size_t)N_EDGES * 4;  // 12.8
  unsigned int* rlistA = (unsigned int*)p; p += (size_t)N_EDGES * 4;  // 12.8
  unsigned char* rlistB = (unsigned char*)p; p += (size_t)N_EDGES;    // 3.2
  float* aggR = (float*)p;                 p += (size_t)N_NODES * 16 * 4;  // 6.4
  int* soff = (int*)p;                     p += (size_t)(N_NODES + 16) * 4;
  int* roff = (int*)p;                     p += (size_t)(N_NODES + 16) * 4;
  float* nbA = (float*)p;                  p += (size_t)N_NODES * 4;
  float* nbB = (float*)p;                  p += (size_t)N_NODES * 4;
  unsigned int* normbits = (unsigned int*)p; p += 64;
  int* gcnt = (int*)p;                     p += NB * 4;
  int* gcnt2 = (int*)p;                    p += NB * 4;
  // build staging aliases e (dead until k_encode):
  unsigned int* pM = (unsigned int*)ws;
  float* pV = (float*)(ws + (size_t)NB * SCAP * 4);
  unsigned int* pO = (unsigned int*)(ws + (size_t)NB * SCAP * 8);
  unsigned int* ssend = (unsigned int*)(ws + (size_t)NB * SCAP * 12);
  unsigned int* rpA =
      (unsigned int*)(ws + (size_t)NB * SCAP * 12 + (size_t)N_EDGES * 4);
  unsigned int* rpB = (unsigned int*)(ws + (size_t)NB * SCAP * 12 +
                                      (size_t)N_EDGES * 4 + (size_t)NB * RCAP * 4);

  const int ngrid = 12500;  // 2 nodes/wave x 4 waves/block -> 100000 nodes
  const int egrid = N_EDGES / BLK;  // 12500

  hipMemsetAsync(normbits, 0, 64 + 2 * NB * 4, stream);  // norm + gcnt + gcnt2
  k_norm<<<512, BLK, 0, stream>>>(edges0, normbits);
  k_split<<<256, 1024, 0, stream>>>(senders, receivers, edges0, gcnt, pM, pV, pO);
  k_bsort1<<<NB, 1024, 0, stream>>>(pM, pV, pO, gcnt, srecv, sorig, sval, soff);
  k_sfill<<<ngrid, BLK, 0, stream>>>(soff, ssend);
  k_rsplit<<<256, 1024, 0, stream>>>(srecv, ssend, gcnt2, rpA, rpB);
  k_rsort<<<NB, 1024, 0, stream>>>(rpA, rpB, gcnt2, rlistA, rlistB, roff);
  k_encode<<<egrid, BLK, 0, stream>>>(sval, enc_w1, enc_b1, enc_w2, enc_b2,
                                      normbits, e);  // clobbers staging
  // round 1: aggregate e0, node update -> nbA
  k_aggR<0><<<ngrid, BLK, 0, stream>>>(e, roff, rlistA, rlistB, nbA, edge_w1,
                                       edge_b1, edge_w2, edge_b2, aggR);
  k_nodeup<0><<<ngrid, BLK, 0, stream>>>(e, soff, srecv, aggR, nodes0, edge_w1,
                                         edge_b1, edge_w2, edge_b2, node_w1,
                                         node_b1, node_w2, node_b2, nbA);
  // round 2: recompute e1 from (e0, nbA); write e1; node update -> nbB
  k_aggR<1><<<ngrid, BLK, 0, stream>>>(e, roff, rlistA, rlistB, nbA, edge_w1,
                                       edge_b1, edge_w2, edge_b2, aggR);
  k_nodeup<1><<<ngrid, BLK, 0, stream>>>(e, soff, srecv, aggR, nbA, edge_w1,
                                         edge_b1, edge_w2, edge_b2, node_w1,
                                         node_b1, node_w2, node_b2, nbB);
  // round 3: recompute e2 from (e1, nbB); write e2; node update -> nbA
  k_aggR<1><<<ngrid, BLK, 0, stream>>>(e, roff, rlistA, rlistB, nbB, edge_w1,
                                       edge_b1, edge_w2, edge_b2, aggR);
  k_nodeup<1><<<ngrid, BLK, 0, stream>>>(e, soff, srecv, aggR, nbB, edge_w1,
                                         edge_b1, edge_w2, edge_b2, node_w1,
                                         node_b1, node_w2, node_b2, nbA);
  // final: e3 = MLP(e2, nbA) -> decoder -> out
  k_final<<<ngrid, BLK, 0, stream>>>(e, soff, srecv, sorig, sval, nbA, edge_w1,
                                     edge_b1, edge_w2, edge_b2, dec_w1, dec_b1,
                                     dec_w2, dec_b2, normbits, alpha,
                                     (float*)d_out);
}

// Round 5
// 1056.690 us; speedup vs baseline: 2.7433x; 2.7433x over previous
//
#include <hip/hip_runtime.h>
#include <hip/hip_bf16.h>

#define N_NODES 100000
#define N_EDGES 3200000
#define HID 16
#define NB 256       // buckets; bucket = NPB consecutive nodes
#define NPB 391      // 256*391 = 100096 >= 100000
#define SCAP 15360   // per-bucket staging cap (mean 12500, +25 sigma)
#define RCAP 15360
#define FDEPTH 32    // LDS FIFO depth in split kernels
#define LCAP1 8704   // bsort1 LDS chunk entries (12 B) -> ~102 KB
#define LCAP2 26624  // rsort LDS chunk entries (4 B) -> 104 KB (1 chunk/bucket)

static constexpr int BLK = 256;

__device__ __forceinline__ float frelu(float x) { return fmaxf(x, 0.f); }
__device__ __forceinline__ float bflo(unsigned int u) {
  return __uint_as_float(u << 16);
}
__device__ __forceinline__ float bfhi(unsigned int u) {
  return __uint_as_float(u & 0xFFFF0000u);
}

union E16 {
  float4 f4[2];
  __hip_bfloat16 h[16];
};

// ---------------------------------------------------------------------------
// K0: norm = max |edges_init|
// ---------------------------------------------------------------------------
__global__ __launch_bounds__(256) void k_norm(const float* __restrict__ edges,
                                              unsigned int* __restrict__ normbits) {
  float m = 0.f;
  for (int i = blockIdx.x * blockDim.x + threadIdx.x; i < N_EDGES;
       i += gridDim.x * blockDim.x)
    m = fmaxf(m, fabsf(edges[i]));
#pragma unroll
  for (int off = 32; off > 0; off >>= 1)
    m = fmaxf(m, __shfl_down(m, off, 64));
  __shared__ float smax[BLK / 64];
  if ((threadIdx.x & 63) == 0) smax[threadIdx.x >> 6] = m;
  __syncthreads();
  if (threadIdx.x == 0) {
    float b = smax[0];
#pragma unroll
    for (int w = 1; w < BLK / 64; ++w) b = fmaxf(b, smax[w]);
    atomicMax(normbits, __float_as_uint(b));
  }
}

// ---------------------------------------------------------------------------
// K1: bucket edges by SENDER via LDS FIFOs (line-granular flushes).
// record: m = (sender_local<<22) | orig_edge(22b), v = edges_init, o = recv
// ---------------------------------------------------------------------------
__global__ __launch_bounds__(1024) void k_split(
    const int* __restrict__ senders, const int* __restrict__ receivers,
    const float* __restrict__ edges, int* __restrict__ gcnt,
    unsigned int* __restrict__ pM, float* __restrict__ pV,
    unsigned int* __restrict__ pO) {
  __shared__ __align__(16) unsigned int fM[NB][FDEPTH];
  __shared__ __align__(16) unsigned int fV[NB][FDEPTH];
  __shared__ __align__(16) unsigned int fO[NB][FDEPTH];
  __shared__ int fcnt[NB];
  const int t = threadIdx.x;
  if (t < NB) fcnt[t] = 0;
  __syncthreads();
  const int e0 = blockIdx.x * (N_EDGES / 256);
  const int e1 = e0 + (N_EDGES / 256);
  for (int base = e0; base < e1; base += 1024) {
    const int i = base + t;
    if (i < e1) {
      int s = senders[i];
      unsigned int b = (unsigned int)s / NPB;
      unsigned int m = (((unsigned int)s - b * NPB) << 22) | (unsigned int)i;
      unsigned int v = __float_as_uint(edges[i]);
      unsigned int o = (unsigned int)receivers[i];
      int pos = atomicAdd(&fcnt[b], 1);
      if (pos < FDEPTH) {
        fM[b][pos] = m; fV[b][pos] = v; fO[b][pos] = o;
      } else {  // rare overflow: direct append
        int gb = atomicAdd(&gcnt[b], 1);
        if (gb < SCAP) {
          pM[(size_t)b * SCAP + gb] = m;
          pV[(size_t)b * SCAP + gb] = __uint_as_float(v);
          pO[(size_t)b * SCAP + gb] = o;
        }
      }
    }
    __syncthreads();
    const bool last = (base + 1024 >= e1);
    if (t < NB) {
      int c = fcnt[t]; if (c > FDEPTH) c = FDEPTH;
      int nf = last ? c : (c & ~15);
      if (nf > 0) {
        int gb = atomicAdd(&gcnt[t], nf);
        size_t db = (size_t)t * SCAP + gb;
        if ((gb & 3) == 0 && gb + nf <= SCAP) {
          int k = 0;
          for (; k + 4 <= nf; k += 4) {
            *(uint4*)(pM + db + k) = *(const uint4*)(&fM[t][k]);
            *(uint4*)((unsigned int*)pV + db + k) = *(const uint4*)(&fV[t][k]);
            *(uint4*)(pO + db + k) = *(const uint4*)(&fO[t][k]);
          }
          for (; k < nf; ++k) {
            pM[db + k] = fM[t][k]; pV[db + k] = __uint_as_float(fV[t][k]);
            pO[db + k] = fO[t][k];
          }
        } else {
          for (int k = 0; k < nf; ++k)
            if (gb + k < SCAP) {
              pM[db + k] = fM[t][k]; pV[db + k] = __uint_as_float(fV[t][k]);
              pO[db + k] = fO[t][k];
            }
        }
        int res = c - nf;
        for (int k = 0; k < res; ++k) {
          fM[t][k] = fM[t][nf + k]; fV[t][k] = fV[t][nf + k];
          fO[t][k] = fO[t][nf + k];
        }
        fcnt[t] = res;
      } else fcnt[t] = c;
    }
    __syncthreads();
  }
}

// ---------------------------------------------------------------------------
// K2: per-bucket counting sort by sender_local -> EXACT global sender CSR.
// Writes srecv/sorig/sval in sorted order + soff. No degree caps.
// ---------------------------------------------------------------------------
__global__ __launch_bounds__(1024) void k_bsort1(
    const unsigned int* __restrict__ pM, const float* __restrict__ pV,
    const unsigned int* __restrict__ pO, const int* __restrict__ gcnt,
    unsigned int* __restrict__ srecv, unsigned int* __restrict__ sorig,
    float* __restrict__ sval, int* __restrict__ soff) {
  __shared__ unsigned int sM[LCAP1];
  __shared__ float sV[LCAP1];
  __shared__ unsigned int sO[LCAP1];
  __shared__ int hist[NPB], pref[NPB + 1], sc[NPB], cur[NPB];
  __shared__ int bb[NB];
  __shared__ int base_s;
  const int b = blockIdx.x, t = threadIdx.x, nt = blockDim.x;
  if (t < NB) { int c = gcnt[t]; bb[t] = c > SCAP ? SCAP : c; }
  for (int k = t; k < NPB; k += nt) hist[k] = 0;
  __syncthreads();
  if (t == 0) { int s = 0; for (int k = 0; k < b; ++k) s += bb[k]; base_s = s; }
  int nb = gcnt[b]; if (nb > SCAP) nb = SCAP;
  const unsigned int* PM = pM + (size_t)b * SCAP;
  const float* PV = pV + (size_t)b * SCAP;
  const unsigned int* PO = pO + (size_t)b * SCAP;
  for (int i = t; i < nb; i += nt) atomicAdd(&hist[PM[i] >> 22], 1);
  __syncthreads();
  if (t < NPB) sc[t] = hist[t];
  __syncthreads();
  for (int d = 1; d < NPB; d <<= 1) {
    int add = 0;
    if (t < NPB && t >= d) add = sc[t - d];
    __syncthreads();
    if (t < NPB && t >= d) sc[t] += add;
    __syncthreads();
  }
  if (t < NPB) pref[t] = sc[t] - hist[t];
  if (t == 0) pref[NPB] = sc[NPB - 1];
  __syncthreads();
  const int base = base_s;
  const int node0 = b * NPB;
  for (int k = t; k < NPB; k += nt) {
    int n = node0 + k;
    if (n < N_NODES) soff[n] = base + pref[k];
  }
  if (b == NB - 1 && t == 0) soff[N_NODES] = base + nb;
  __syncthreads();
  int klo = 0;
  while (klo < NPB) {
    int base0 = pref[klo];
    int khi = klo;
    while (khi < NPB && pref[khi + 1] - base0 <= LCAP1) ++khi;
    if (khi == klo) khi = klo + 1;  // safety
    for (int k = klo + t; k < khi; k += nt) cur[k] = pref[k];
    __syncthreads();
    for (int i = t; i < nb; i += nt) {
      unsigned int m = PM[i];
      int key = (int)(m >> 22);
      if (key >= klo && key < khi) {
        int p = atomicAdd(&cur[key], 1) - base0;
        if (p < LCAP1) { sM[p] = m; sV[p] = PV[i]; sO[p] = PO[i]; }
      }
    }
    __syncthreads();
    int csz = pref[khi] - base0;
    for (int i = t; i < csz; i += nt) {
      int g = base + base0 + i;
      srecv[g] = sO[i]; sorig[g] = sM[i] & 0x3FFFFFu; sval[g] = sV[i];
    }
    __syncthreads();
    klo = khi;
  }
}

// ---------------------------------------------------------------------------
// K3: bucket sorted edges by RECEIVER. Single u32 carried:
// a = (recv_local<<22) | sorted_idx (9+22 = 31 bits).
// ---------------------------------------------------------------------------
__global__ __launch_bounds__(1024) void k_rsplit(
    const unsigned int* __restrict__ srecv, int* __restrict__ gcnt2,
    unsigned int* __restrict__ rpA) {
  __shared__ __align__(16) unsigned int fA[NB][FDEPTH];
  __shared__ int fcnt[NB];
  const int t = threadIdx.x;
  if (t < NB) fcnt[t] = 0;
  __syncthreads();
  const int e0 = blockIdx.x * (N_EDGES / 256);
  const int e1 = e0 + (N_EDGES / 256);
  for (int base = e0; base < e1; base += 1024) {
    const int i = base + t;
    if (i < e1) {
      unsigned int r = srecv[i];
      unsigned int b = r / NPB;
      unsigned int a = ((r - b * NPB) << 22) | (unsigned int)i;
      int pos = atomicAdd(&fcnt[b], 1);
      if (pos < FDEPTH) {
        fA[b][pos] = a;
      } else {
        int gb = atomicAdd(&gcnt2[b], 1);
        if (gb < RCAP) rpA[(size_t)b * RCAP + gb] = a;
      }
    }
    __syncthreads();
    const bool last = (base + 1024 >= e1);
    if (t < NB) {
      int c = fcnt[t]; if (c > FDEPTH) c = FDEPTH;
      int nf = last ? c : (c & ~15);
      if (nf > 0) {
        int gb = atomicAdd(&gcnt2[t], nf);
        size_t db = (size_t)t * RCAP + gb;
        if ((gb & 3) == 0 && gb + nf <= RCAP) {
          int k = 0;
          for (; k + 4 <= nf; k += 4)
            *(uint4*)(rpA + db + k) = *(const uint4*)(&fA[t][k]);
          for (; k < nf; ++k) rpA[db + k] = fA[t][k];
        } else {
          for (int k = 0; k < nf; ++k)
            if (gb + k < RCAP) rpA[db + k] = fA[t][k];
        }
        int res = c - nf;
        for (int k = 0; k < res; ++k) fA[t][k] = fA[t][nf + k];
        fcnt[t] = res;
      } else fcnt[t] = c;
    }
    __syncthreads();
  }
}

// ---------------------------------------------------------------------------
// K4: per-bucket counting sort by recv_local -> receiver CSR (roff) +
// rlist[g] = sorted edge idx. Bucket fill (~12500) fits one LDS chunk.
// ---------------------------------------------------------------------------
__global__ __launch_bounds__(1024) void k_rsort(
    const unsigned int* __restrict__ rpA, const int* __restrict__ gcnt2,
    unsigned int* __restrict__ rlist, int* __restrict__ roff) {
  __shared__ unsigned int sA[LCAP2];
  __shared__ int hist[NPB], pref[NPB + 1], sc[NPB], cur[NPB];
  __shared__ int bb[NB];
  __shared__ int base_s;
  const int b = blockIdx.x, t = threadIdx.x, nt = blockDim.x;
  if (t < NB) { int c = gcnt2[t]; bb[t] = c > RCAP ? RCAP : c; }
  for (int k = t; k < NPB; k += nt) hist[k] = 0;
  __syncthreads();
  if (t == 0) { int s = 0; for (int k = 0; k < b; ++k) s += bb[k]; base_s = s; }
  int nb = gcnt2[b]; if (nb > RCAP) nb = RCAP;
  const unsigned int* PA = rpA + (size_t)b * RCAP;
  for (int i = t; i < nb; i += nt) atomicAdd(&hist[PA[i] >> 22], 1);
  __syncthreads();
  if (t < NPB) sc[t] = hist[t];
  __syncthreads();
  for (int d = 1; d < NPB; d <<= 1) {
    int add = 0;
    if (t < NPB && t >= d) add = sc[t - d];
    __syncthreads();
    if (t < NPB && t >= d) sc[t] += add;
    __syncthreads();
  }
  if (t < NPB) pref[t] = sc[t] - hist[t];
  if (t == 0) pref[NPB] = sc[NPB - 1];
  __syncthreads();
  const int base = base_s;
  const int node0 = b * NPB;
  for (int k = t; k < NPB; k += nt) {
    int n = node0 + k;
    if (n < N_NODES) roff[n] = base + pref[k];
  }
  if (b == NB - 1 && t == 0) roff[N_NODES] = base + nb;
  __syncthreads();
  int klo = 0;
  while (klo < NPB) {
    int base0 = pref[klo];
    int khi = klo;
    while (khi < NPB && pref[khi + 1] - base0 <= LCAP2) ++khi;
    if (khi == klo) khi = klo + 1;
    for (int k = klo + t; k < khi; k += nt) cur[k] = pref[k];
    __syncthreads();
    for (int i = t; i < nb; i += nt) {
      unsigned int a = PA[i];
      int key = (int)(a >> 22);
      if (key >= klo && key < khi) {
        int p = atomicAdd(&cur[key], 1) - base0;
        if (p < LCAP2) sA[p] = a;
      }
    }
    __syncthreads();
    int csz = pref[khi] - base0;
    for (int i = t; i < csz; i += nt)
      rlist[base + base0 + i] = sA[i] & 0x3FFFFFu;
    __syncthreads();
    klo = khi;
  }
}

// ---------------------------------------------------------------------------
// K5: edge encoder (1 -> HID -> HID) in sorted order, coalesced.
// ---------------------------------------------------------------------------
__global__ __launch_bounds__(256) void k_encode(
    const float* __restrict__ sval, const float* __restrict__ w1,
    const float* __restrict__ b1, const float* __restrict__ w2,
    const float* __restrict__ b2, const unsigned int* __restrict__ normbits,
    unsigned short* __restrict__ e) {
  int i = blockIdx.x * blockDim.x + threadIdx.x;
  float norm = __uint_as_float(*normbits);
  float x = sval[i] / norm;
  float h[HID];
#pragma unroll
  for (int j = 0; j < HID; ++j) h[j] = frelu(fmaf(w1[j], x, b1[j]));
  E16 o;
#pragma unroll
  for (int j = 0; j < HID; ++j) {
    float acc = b2[j];
#pragma unroll
    for (int k = 0; k < HID; ++k) acc = fmaf(w2[j * HID + k], h[k], acc);
    o.h[j] = __float2bfloat16(acc);
  }
  float4* ep = (float4*)(e + (size_t)i * HID);
  ep[0] = o.f4[0];
  ep[1] = o.f4[1];
}

// ---------------------------------------------------------------------------
// K6: receiver-side aggregate — PLAIN sums (no recompute; round-4 lesson:
// recompute-in-gather collapses occupancy). 2 nodes/wave, 2 lanes/entry,
// 16 B loads -> 1 line per 32 B record. ~3.2 M scattered lines total (half
// of the old bidirectional gather). Low VGPR -> latency well hidden.
// ---------------------------------------------------------------------------
__global__ __launch_bounds__(256) void k_aggR(
    const unsigned short* __restrict__ e, const int* __restrict__ roff,
    const unsigned int* __restrict__ rlist, float* __restrict__ aggR) {
  int wave = (blockIdx.x * blockDim.x + threadIdx.x) >> 6;
  int lane = threadIdx.x & 63, half = lane >> 5, l32 = lane & 31;
  int sub = l32 & 1, j16 = l32 >> 1;
  int n = wave * 2 + half;
  int r0 = roff[n], rdeg = roff[n + 1] - r0;
  float acc[8] = {0, 0, 0, 0, 0, 0, 0, 0};
  for (int s0 = 0; s0 < rdeg; s0 += 16) {
    int slot = s0 + j16;
    bool ok = slot < rdeg;
    int idx = r0 + (ok ? slot : 0);
    unsigned int si = rlist[idx];
    uint4 raw = *(const uint4*)(e + (size_t)si * HID + sub * 8);
    float v[8] = {bflo(raw.x), bfhi(raw.x), bflo(raw.y), bfhi(raw.y),
                  bflo(raw.z), bfhi(raw.z), bflo(raw.w), bfhi(raw.w)};
#pragma unroll
    for (int c = 0; c < 8; ++c) acc[c] += ok ? v[c] : 0.f;
  }
#pragma unroll
  for (int off = 16; off >= 2; off >>= 1)
#pragma unroll
    for (int c = 0; c < 8; ++c) acc[c] += __shfl_down(acc[c], off, 64);
  if (l32 < 2) {
    *(float4*)(aggR + (size_t)n * 16 + sub * 8) =
        make_float4(acc[0], acc[1], acc[2], acc[3]);
    *(float4*)(aggR + (size_t)n * 16 + sub * 8 + 4) =
        make_float4(acc[4], acc[5], acc[6], acc[7]);
  }
}

// ---------------------------------------------------------------------------
// K7: sender-side stream (plain sums, coalesced runs) + fused node MLP.
// 2 nodes/wave, 1 lane/edge. (Round-4 k_nodeup<0>, verified passing.)
// ---------------------------------------------------------------------------
__global__ __launch_bounds__(256) void k_nodeup(
    const unsigned short* __restrict__ e, const int* __restrict__ soff,
    const float* __restrict__ aggR, const float* __restrict__ nodesr,
    const float* __restrict__ nw1, const float* __restrict__ nb1_,
    const float* __restrict__ nw2, const float* __restrict__ nb2_,
    float* __restrict__ nodesw) {
  int wave = (blockIdx.x * blockDim.x + threadIdx.x) >> 6;
  int lane = threadIdx.x & 63, half = lane >> 5, l32 = lane & 31;
  int n = wave * 2 + half;
  int s0 = soff[n], sdeg = soff[n + 1] - s0;
  float nsv = nodesr[n];
  float accS[16];
#pragma unroll
  for (int c = 0; c < 16; ++c) accS[c] = 0.f;
  for (int c0 = 0; c0 < sdeg; c0 += 32) {
    int k = c0 + l32;
    bool ok = k < sdeg;
    int idx = s0 + (ok ? k : 0);
    uint4 ra = *(const uint4*)(e + (size_t)idx * HID);
    uint4 rb = *(const uint4*)(e + (size_t)idx * HID + 8);
    float x[16] = {bflo(ra.x), bfhi(ra.x), bflo(ra.y), bfhi(ra.y),
                   bflo(ra.z), bfhi(ra.z), bflo(ra.w), bfhi(ra.w),
                   bflo(rb.x), bfhi(rb.x), bflo(rb.y), bfhi(rb.y),
                   bflo(rb.z), bfhi(rb.z), bflo(rb.w), bfhi(rb.w)};
#pragma unroll
    for (int c = 0; c < 16; ++c) accS[c] += ok ? x[c] : 0.f;
  }
#pragma unroll
  for (int off = 16; off >= 1; off >>= 1)
#pragma unroll
    for (int c = 0; c < 16; ++c) accS[c] += __shfl_down(accS[c], off, 64);
  float aS[16];
#pragma unroll
  for (int c = 0; c < 16; ++c) aS[c] = __shfl(accS[c], half * 32, 64);
  float pv = 0.f;
  if (l32 < 16) {
    int j = l32;
    float a1 = fmaf(nw1[j * 33], nsv, nb1_[j]);
#pragma unroll
    for (int k = 0; k < 16; ++k) a1 = fmaf(nw1[j * 33 + 1 + k], aS[k], a1);
#pragma unroll
    for (int k = 0; k < 16; ++k)
      a1 = fmaf(nw1[j * 33 + 17 + k], aggR[(size_t)n * 16 + k], a1);
    pv = nw2[j] * frelu(a1);
  }
#pragma unroll
  for (int off = 8; off >= 1; off >>= 1) pv += __shfl_down(pv, off, 64);
  if (l32 == 0) nodesw[n] = pv + nb2_[0];
}

// ---------------------------------------------------------------------------
// K8: edge MLP (H+2 -> HID -> HID), node-major over sender runs, in-place.
// sender is wave-uniform (no ssend array); receiver node value is a
// scattered 4 B read into the 400 KB L2-resident nodes array.
// ---------------------------------------------------------------------------
__global__ __launch_bounds__(256) void k_edgeN(
    unsigned short* __restrict__ e, const int* __restrict__ soff,
    const unsigned int* __restrict__ srecv, const float* __restrict__ nodes,
    const float* __restrict__ w1, const float* __restrict__ b1,
    const float* __restrict__ w2, const float* __restrict__ b2) {
  int wave = (blockIdx.x * blockDim.x + threadIdx.x) >> 6;
  int lane = threadIdx.x & 63, half = lane >> 5, l32 = lane & 31;
  int n = wave * 2 + half;
  int s0 = soff[n], sdeg = soff[n + 1] - s0;
  float nsv = nodes[n];
  for (int c0 = 0; c0 < sdeg; c0 += 32) {
    int k = c0 + l32;
    bool ok = k < sdeg;
    int idx = s0 + (ok ? k : 0);
    uint4 ra = *(const uint4*)(e + (size_t)idx * HID);
    uint4 rb = *(const uint4*)(e + (size_t)idx * HID + 8);
    float x[16] = {bflo(ra.x), bfhi(ra.x), bflo(ra.y), bfhi(ra.y),
                   bflo(ra.z), bfhi(ra.z), bflo(ra.w), bfhi(ra.w),
                   bflo(rb.x), bfhi(rb.x), bflo(rb.y), bfhi(rb.y),
                   bflo(rb.z), bfhi(rb.z), bflo(rb.w), bfhi(rb.w)};
    float nrv = nodes[srecv[idx]];
    float h[16];
#pragma unroll
    for (int j = 0; j < 16; ++j) {
      float a1 = b1[j];
#pragma unroll
      for (int kk = 0; kk < 16; ++kk) a1 = fmaf(w1[j * 18 + kk], x[kk], a1);
      a1 = fmaf(w1[j * 18 + 16], nsv, a1);
      a1 = fmaf(w1[j * 18 + 17], nrv, a1);
      h[j] = frelu(a1);
    }
    E16 o;
#pragma unroll
    for (int c = 0; c < 16; ++c) {
      float a2 = b2[c];
#pragma unroll
      for (int j = 0; j < 16; ++j) a2 = fmaf(w2[c * HID + j], h[j], a2);
      o.h[c] = __float2bfloat16(a2);
    }
    if (ok) {
      *(float4*)(e + (size_t)idx * HID) = o.f4[0];
      *(float4*)(e + (size_t)idx * HID + 8) = o.f4[1];
    }
  }
}

// ---------------------------------------------------------------------------
// K9: final — round-3 edge MLP + decoder + out = edges_init + alpha*e*norm.
// Node-major sender runs; one scattered 4 B store per edge.
// ---------------------------------------------------------------------------
__global__ __launch_bounds__(256) void k_final(
    const unsigned short* __restrict__ e, const int* __restrict__ soff,
    const unsigned int* __restrict__ srecv, const unsigned int* __restrict__ sorig,
    const float* __restrict__ sval, const float* __restrict__ nodes,
    const float* __restrict__ ew1, const float* __restrict__ eb1,
    const float* __restrict__ ew2, const float* __restrict__ eb2,
    const float* __restrict__ dw1, const float* __restrict__ db1,
    const float* __restrict__ dw2, const float* __restrict__ db2,
    const unsigned int* __restrict__ normbits, const float* __restrict__ alpha,
    float* __restrict__ out) {
  int wave = (blockIdx.x * blockDim.x + threadIdx.x) >> 6;
  int lane = threadIdx.x & 63, half = lane >> 5, l32 = lane & 31;
  int n = wave * 2 + half;
  int s0 = soff[n], sdeg = soff[n + 1] - s0;
  float nsv = nodes[n];
  float alphaN = alpha[0] * __uint_as_float(*normbits);
  for (int c0 = 0; c0 < sdeg; c0 += 32) {
    int k = c0 + l32;
    bool ok = k < sdeg;
    int idx = s0 + (ok ? k : 0);
    uint4 ra = *(const uint4*)(e + (size_t)idx * HID);
    uint4 rb = *(const uint4*)(e + (size_t)idx * HID + 8);
    float x[16] = {bflo(ra.x), bfhi(ra.x), bflo(ra.y), bfhi(ra.y),
                   bflo(ra.z), bfhi(ra.z), bflo(ra.w), bfhi(ra.w),
                   bflo(rb.x), bfhi(rb.x), bflo(rb.y), bfhi(rb.y),
                   bflo(rb.z), bfhi(rb.z), bflo(rb.w), bfhi(rb.w)};
    float nrv = nodes[srecv[idx]];
    float h[16];
#pragma unroll
    for (int j = 0; j < 16; ++j) {
      float a1 = eb1[j];
#pragma unroll
      for (int kk = 0; kk < 16; ++kk) a1 = fmaf(ew1[j * 18 + kk], x[kk], a1);
      a1 = fmaf(ew1[j * 18 + 16], nsv, a1);
      a1 = fmaf(ew1[j * 18 + 17], nrv, a1);
      h[j] = frelu(a1);
    }
    float y[16];
#pragma unroll
    for (int c = 0; c < 16; ++c) {
      float a2 = eb2[c];
#pragma unroll
      for (int j = 0; j < 16; ++j) a2 = fmaf(ew2[c * HID + j], h[j], a2);
      y[c] = a2;
    }
    float d = db2[0];
#pragma unroll
    for (int j = 0; j < 16; ++j) {
      float a1 = db1[j];
#pragma unroll
      for (int kk = 0; kk < 16; ++kk) a1 = fmaf(dw1[j * HID + kk], y[kk], a1);
      d = fmaf(dw2[j], frelu(a1), d);
    }
    if (ok) out[sorig[idx]] = fmaf(alphaN, d, sval[idx]);
  }
}

// ---------------------------------------------------------------------------
extern "C" void kernel_launch(void* const* d_in, const int* in_sizes, int n_in,
                              void* d_out, int out_size, void* d_ws,
                              size_t ws_size, hipStream_t stream) {
  const float* nodes0 = (const float*)d_in[0];
  const float* edges0 = (const float*)d_in[1];
  const int* senders = (const int*)d_in[2];
  const int* receivers = (const int*)d_in[3];
  const float* enc_w1 = (const float*)d_in[4];
  const float* enc_b1 = (const float*)d_in[5];
  const float* enc_w2 = (const float*)d_in[6];
  const float* enc_b2 = (const float*)d_in[7];
  const float* node_w1 = (const float*)d_in[8];
  const float* node_b1 = (const float*)d_in[9];
  const float* node_w2 = (const float*)d_in[10];
  const float* node_b2 = (const float*)d_in[11];
  const float* edge_w1 = (const float*)d_in[12];
  const float* edge_b1 = (const float*)d_in[13];
  const float* edge_w2 = (const float*)d_in[14];
  const float* edge_b2 = (const float*)d_in[15];
  const float* dec_w1 = (const float*)d_in[16];
  const float* dec_b1 = (const float*)d_in[17];
  const float* dec_w2 = (const float*)d_in[18];
  const float* dec_b2 = (const float*)d_in[19];
  const float* alpha = (const float*)d_in[20];

  // Workspace layout: ~161.4 MB (< proven 167.6 MB budget).
  char* ws = (char*)d_ws;
  unsigned short* e = (unsigned short*)ws;  // 3.2M x 32 B = 102.4 MB (sorted)
  char* p = ws + (size_t)N_EDGES * HID * 2;
  unsigned int* srecv = (unsigned int*)p;  p += (size_t)N_EDGES * 4;  // 12.8
  unsigned int* sorig = (unsigned int*)p;  p += (size_t)N_EDGES * 4;  // 12.8
  float* sval = (float*)p;                 p += (size_t)N_EDGES * 4;  // 12.8
  unsigned int* rlist = (unsigned int*)p;  p += (size_t)N_EDGES * 4;  // 12.8
  float* aggR = (float*)p;                 p += (size_t)N_NODES * 16 * 4;  // 6.4
  int* soff = (int*)p;                     p += (size_t)(N_NODES + 16) * 4;
  int* roff = (int*)p;                     p += (size_t)(N_NODES + 16) * 4;
  float* nbA = (float*)p;                  p += (size_t)N_NODES * 4;
  float* nbB = (float*)p;                  p += (size_t)N_NODES * 4;
  unsigned int* normbits = (unsigned int*)p; p += 64;
  int* gcnt = (int*)p;                     p += NB * 4;
  int* gcnt2 = (int*)p;                    p += NB * 4;
  // build staging aliases e (dead until k_encode):
  unsigned int* pM = (unsigned int*)ws;
  float* pV = (float*)(ws + (size_t)NB * SCAP * 4);
  unsigned int* pO = (unsigned int*)(ws + (size_t)NB * SCAP * 8);
  unsigned int* rpA = (unsigned int*)(ws + (size_t)NB * SCAP * 12);

  const int ngrid = 12500;  // 2 nodes/wave x 4 waves/block -> 100000 nodes
  const int egrid = N_EDGES / BLK;  // 12500

  hipMemsetAsync(normbits, 0, 64 + 2 * NB * 4, stream);  // norm + gcnt + gcnt2
  k_norm<<<512, BLK, 0, stream>>>(edges0, normbits);
  k_split<<<256, 1024, 0, stream>>>(senders, receivers, edges0, gcnt, pM, pV, pO);
  k_bsort1<<<NB, 1024, 0, stream>>>(pM, pV, pO, gcnt, srecv, sorig, sval, soff);
  k_rsplit<<<256, 1024, 0, stream>>>(srecv, gcnt2, rpA);
  k_rsort<<<NB, 1024, 0, stream>>>(rpA, gcnt2, rlist, roff);
  k_encode<<<egrid, BLK, 0, stream>>>(sval, enc_w1, enc_b1, enc_w2, enc_b2,
                                      normbits, e);  // clobbers staging
  // round 1
  k_aggR<<<ngrid, BLK, 0, stream>>>(e, roff, rlist, aggR);
  k_nodeup<<<ngrid, BLK, 0, stream>>>(e, soff, aggR, nodes0, node_w1, node_b1,
                                      node_w2, node_b2, nbA);
  k_edgeN<<<ngrid, BLK, 0, stream>>>(e, soff, srecv, nbA, edge_w1, edge_b1,
                                     edge_w2, edge_b2);
  // round 2
  k_aggR<<<ngrid, BLK, 0, stream>>>(e, roff, rlist, aggR);
  k_nodeup<<<ngrid, BLK, 0, stream>>>(e, soff, aggR, nbA, node_w1, node_b1,
                                      node_w2, node_b2, nbB);
  k_edgeN<<<ngrid, BLK, 0, stream>>>(e, soff, srecv, nbB, edge_w1, edge_b1,
                                     edge_w2, edge_b2);
  // round 3
  k_aggR<<<ngrid, BLK, 0, stream>>>(e, roff, rlist, aggR);
  k_nodeup<<<ngrid, BLK, 0, stream>>>(e, soff, aggR, nbB, node_w1, node_b1,
                                      node_w2, node_b2, nbA);
  // final: e3 = edgeMLP(e2, nbA) -> decoder -> out
  k_final<<<ngrid, BLK, 0, stream>>>(e, soff, srecv, sorig, sval, nbA, edge_w1,
                                     edge_b1, edge_w2, edge_b2, dec_w1, dec_b1,
                                     dec_w2, dec_b2, normbits, alpha,
                                     (float*)d_out);
}

// Round 6
// 993.804 us; speedup vs baseline: 2.9169x; 1.0633x over previous
//
#include <hip/hip_runtime.h>
#include <hip/hip_bf16.h>

#define N_NODES 100000
#define N_EDGES 3200000
#define HID 16
#define NB 256       // buckets; bucket = NPB consecutive nodes
#define NPB 391      // 256*391 = 100096 >= 100000
#define SCAP 15360   // per-bucket staging cap (mean 12500, +25 sigma)
#define RCAP 15360
#define FDEPTH 32    // LDS FIFO depth in split kernels
#define LCAP1 8704   // bsort1 LDS chunk entries (12 B) -> ~102 KB
#define LCAP2 26624  // rsort LDS chunk entries (4 B) -> 104 KB (1 chunk/bucket)

static constexpr int BLK = 256;

__device__ __forceinline__ float frelu(float x) { return fmaxf(x, 0.f); }
__device__ __forceinline__ float bflo(unsigned int u) {
  return __uint_as_float(u << 16);
}
__device__ __forceinline__ float bfhi(unsigned int u) {
  return __uint_as_float(u & 0xFFFF0000u);
}

// bucket of sorted-edge i: 8-step binary search over bstart[0..NB]
// (lanes in a wave share 1-2 buckets -> loads are L1-broadcast hits)
__device__ __forceinline__ int find_bucket(const int* __restrict__ bstart,
                                           int i) {
  int lo = 0, hi = NB;
#pragma unroll
  for (int s = 0; s < 8; ++s) {
    int mid = (lo + hi) >> 1;
    if (i >= bstart[mid]) lo = mid; else hi = mid;
  }
  return lo;
}

union E16 {
  float4 f4[2];
  __hip_bfloat16 h[16];
};

// ---------------------------------------------------------------------------
// K0: norm = max |edges_init|
// ---------------------------------------------------------------------------
__global__ __launch_bounds__(256) void k_norm(const float* __restrict__ edges,
                                              unsigned int* __restrict__ normbits) {
  float m = 0.f;
  for (int i = blockIdx.x * blockDim.x + threadIdx.x; i < N_EDGES;
       i += gridDim.x * blockDim.x)
    m = fmaxf(m, fabsf(edges[i]));
#pragma unroll
  for (int off = 32; off > 0; off >>= 1)
    m = fmaxf(m, __shfl_down(m, off, 64));
  __shared__ float smax[BLK / 64];
  if ((threadIdx.x & 63) == 0) smax[threadIdx.x >> 6] = m;
  __syncthreads();
  if (threadIdx.x == 0) {
    float b = smax[0];
#pragma unroll
    for (int w = 1; w < BLK / 64; ++w) b = fmaxf(b, smax[w]);
    atomicMax(normbits, __float_as_uint(b));
  }
}

// ---------------------------------------------------------------------------
// K1: bucket edges by SENDER via LDS FIFOs (line-granular flushes).
// record: m = (sender_local<<22) | orig_edge(22b), v = edges_init, o = recv
// ---------------------------------------------------------------------------
__global__ __launch_bounds__(1024) void k_split(
    const int* __restrict__ senders, const int* __restrict__ receivers,
    const float* __restrict__ edges, int* __restrict__ gcnt,
    unsigned int* __restrict__ pM, float* __restrict__ pV,
    unsigned int* __restrict__ pO) {
  __shared__ __align__(16) unsigned int fM[NB][FDEPTH];
  __shared__ __align__(16) unsigned int fV[NB][FDEPTH];
  __shared__ __align__(16) unsigned int fO[NB][FDEPTH];
  __shared__ int fcnt[NB];
  const int t = threadIdx.x;
  if (t < NB) fcnt[t] = 0;
  __syncthreads();
  const int e0 = blockIdx.x * (N_EDGES / 256);
  const int e1 = e0 + (N_EDGES / 256);
  for (int base = e0; base < e1; base += 1024) {
    const int i = base + t;
    if (i < e1) {
      int s = senders[i];
      unsigned int b = (unsigned int)s / NPB;
      unsigned int m = (((unsigned int)s - b * NPB) << 22) | (unsigned int)i;
      unsigned int v = __float_as_uint(edges[i]);
      unsigned int o = (unsigned int)receivers[i];
      int pos = atomicAdd(&fcnt[b], 1);
      if (pos < FDEPTH) {
        fM[b][pos] = m; fV[b][pos] = v; fO[b][pos] = o;
      } else {  // rare overflow: direct append
        int gb = atomicAdd(&gcnt[b], 1);
        if (gb < SCAP) {
          pM[(size_t)b * SCAP + gb] = m;
          pV[(size_t)b * SCAP + gb] = __uint_as_float(v);
          pO[(size_t)b * SCAP + gb] = o;
        }
      }
    }
    __syncthreads();
    const bool last = (base + 1024 >= e1);
    if (t < NB) {
      int c = fcnt[t]; if (c > FDEPTH) c = FDEPTH;
      int nf = last ? c : (c & ~15);
      if (nf > 0) {
        int gb = atomicAdd(&gcnt[t], nf);
        size_t db = (size_t)t * SCAP + gb;
        if ((gb & 3) == 0 && gb + nf <= SCAP) {
          int k = 0;
          for (; k + 4 <= nf; k += 4) {
            *(uint4*)(pM + db + k) = *(const uint4*)(&fM[t][k]);
            *(uint4*)((unsigned int*)pV + db + k) = *(const uint4*)(&fV[t][k]);
            *(uint4*)(pO + db + k) = *(const uint4*)(&fO[t][k]);
          }
          for (; k < nf; ++k) {
            pM[db + k] = fM[t][k]; pV[db + k] = __uint_as_float(fV[t][k]);
            pO[db + k] = fO[t][k];
          }
        } else {
          for (int k = 0; k < nf; ++k)
            if (gb + k < SCAP) {
              pM[db + k] = fM[t][k]; pV[db + k] = __uint_as_float(fV[t][k]);
              pO[db + k] = fO[t][k];
            }
        }
        int res = c - nf;
        for (int k = 0; k < res; ++k) {
          fM[t][k] = fM[t][nf + k]; fV[t][k] = fV[t][nf + k];
          fO[t][k] = fO[t][nf + k];
        }
        fcnt[t] = res;
      } else fcnt[t] = c;
    }
    __syncthreads();
  }
}

// ---------------------------------------------------------------------------
// K2: per-bucket counting sort by sender_local -> EXACT global sender CSR.
// Writes srecv/sorig/svalbf (bf16, encoder-input-only) + soff + bstart.
// ---------------------------------------------------------------------------
__global__ __launch_bounds__(1024) void k_bsort1(
    const unsigned int* __restrict__ pM, const float* __restrict__ pV,
    const unsigned int* __restrict__ pO, const int* __restrict__ gcnt,
    unsigned int* __restrict__ srecv, unsigned int* __restrict__ sorig,
    unsigned short* __restrict__ svalbf, int* __restrict__ soff,
    int* __restrict__ bstart) {
  __shared__ unsigned int sM[LCAP1];
  __shared__ float sV[LCAP1];
  __shared__ unsigned int sO[LCAP1];
  __shared__ int hist[NPB], pref[NPB + 1], sc[NPB], cur[NPB];
  __shared__ int bb[NB];
  __shared__ int base_s;
  const int b = blockIdx.x, t = threadIdx.x, nt = blockDim.x;
  if (t < NB) { int c = gcnt[t]; bb[t] = c > SCAP ? SCAP : c; }
  for (int k = t; k < NPB; k += nt) hist[k] = 0;
  __syncthreads();
  if (t == 0) { int s = 0; for (int k = 0; k < b; ++k) s += bb[k]; base_s = s; }
  int nb = gcnt[b]; if (nb > SCAP) nb = SCAP;
  const unsigned int* PM = pM + (size_t)b * SCAP;
  const float* PV = pV + (size_t)b * SCAP;
  const unsigned int* PO = pO + (size_t)b * SCAP;
  for (int i = t; i < nb; i += nt) atomicAdd(&hist[PM[i] >> 22], 1);
  __syncthreads();
  if (t < NPB) sc[t] = hist[t];
  __syncthreads();
  for (int d = 1; d < NPB; d <<= 1) {
    int add = 0;
    if (t < NPB && t >= d) add = sc[t - d];
    __syncthreads();
    if (t < NPB && t >= d) sc[t] += add;
    __syncthreads();
  }
  if (t < NPB) pref[t] = sc[t] - hist[t];
  if (t == 0) pref[NPB] = sc[NPB - 1];
  __syncthreads();
  const int base = base_s;
  const int node0 = b * NPB;
  for (int k = t; k < NPB; k += nt) {
    int n = node0 + k;
    if (n < N_NODES) soff[n] = base + pref[k];
  }
  if (t == 0) bstart[b] = base;
  if (b == NB - 1 && t == 0) {
    soff[N_NODES] = base + nb;
    bstart[NB] = base + nb;
  }
  __syncthreads();
  int klo = 0;
  while (klo < NPB) {
    int base0 = pref[klo];
    int khi = klo;
    while (khi < NPB && pref[khi + 1] - base0 <= LCAP1) ++khi;
    if (khi == klo) khi = klo + 1;  // safety
    for (int k = klo + t; k < khi; k += nt) cur[k] = pref[k];
    __syncthreads();
    for (int i = t; i < nb; i += nt) {
      unsigned int m = PM[i];
      int key = (int)(m >> 22);
      if (key >= klo && key < khi) {
        int p = atomicAdd(&cur[key], 1) - base0;
        if (p < LCAP1) { sM[p] = m; sV[p] = PV[i]; sO[p] = PO[i]; }
      }
    }
    __syncthreads();
    int csz = pref[khi] - base0;
    for (int i = t; i < csz; i += nt) {
      int g = base + base0 + i;
      srecv[g] = sO[i]; sorig[g] = sM[i] & 0x3FFFFFu;
      __hip_bfloat16 hb = __float2bfloat16(sV[i]);
      svalbf[g] = *(unsigned short*)&hb;
    }
    __syncthreads();
    klo = khi;
  }
}

// ---------------------------------------------------------------------------
// K2b: ssend16[i] = sender_local of sorted edge i (node-major, coalesced)
// ---------------------------------------------------------------------------
__global__ __launch_bounds__(256) void k_sfill(
    const int* __restrict__ soff, unsigned short* __restrict__ ssend16) {
  int wave = (blockIdx.x * blockDim.x + threadIdx.x) >> 6;
  int lane = threadIdx.x & 63, half = lane >> 5, l32 = lane & 31;
  int n = wave * 2 + half;
  unsigned short local = (unsigned short)(n - (n / NPB) * NPB);
  int s0 = soff[n], s1 = soff[n + 1];
  for (int k = s0 + l32; k < s1; k += 32) ssend16[k] = local;
}

// ---------------------------------------------------------------------------
// K3: bucket sorted edges by RECEIVER. a = (recv_local<<22) | sorted_idx
// ---------------------------------------------------------------------------
__global__ __launch_bounds__(1024) void k_rsplit(
    const unsigned int* __restrict__ srecv, int* __restrict__ gcnt2,
    unsigned int* __restrict__ rpA) {
  __shared__ __align__(16) unsigned int fA[NB][FDEPTH];
  __shared__ int fcnt[NB];
  const int t = threadIdx.x;
  if (t < NB) fcnt[t] = 0;
  __syncthreads();
  const int e0 = blockIdx.x * (N_EDGES / 256);
  const int e1 = e0 + (N_EDGES / 256);
  for (int base = e0; base < e1; base += 1024) {
    const int i = base + t;
    if (i < e1) {
      unsigned int r = srecv[i];
      unsigned int b = r / NPB;
      unsigned int a = ((r - b * NPB) << 22) | (unsigned int)i;
      int pos = atomicAdd(&fcnt[b], 1);
      if (pos < FDEPTH) {
        fA[b][pos] = a;
      } else {
        int gb = atomicAdd(&gcnt2[b], 1);
        if (gb < RCAP) rpA[(size_t)b * RCAP + gb] = a;
      }
    }
    __syncthreads();
    const bool last = (base + 1024 >= e1);
    if (t < NB) {
      int c = fcnt[t]; if (c > FDEPTH) c = FDEPTH;
      int nf = last ? c : (c & ~15);
      if (nf > 0) {
        int gb = atomicAdd(&gcnt2[t], nf);
        size_t db = (size_t)t * RCAP + gb;
        if ((gb & 3) == 0 && gb + nf <= RCAP) {
          int k = 0;
          for (; k + 4 <= nf; k += 4)
            *(uint4*)(rpA + db + k) = *(const uint4*)(&fA[t][k]);
          for (; k < nf; ++k) rpA[db + k] = fA[t][k];
        } else {
          for (int k = 0; k < nf; ++k)
            if (gb + k < RCAP) rpA[db + k] = fA[t][k];
        }
        int res = c - nf;
        for (int k = 0; k < res; ++k) fA[t][k] = fA[t][nf + k];
        fcnt[t] = res;
      } else fcnt[t] = c;
    }
    __syncthreads();
  }
}

// ---------------------------------------------------------------------------
// K4: per-bucket counting sort by recv_local -> receiver CSR (roff) + rlist.
// ---------------------------------------------------------------------------
__global__ __launch_bounds__(1024) void k_rsort(
    const unsigned int* __restrict__ rpA, const int* __restrict__ gcnt2,
    unsigned int* __restrict__ rlist, int* __restrict__ roff) {
  __shared__ unsigned int sA[LCAP2];
  __shared__ int hist[NPB], pref[NPB + 1], sc[NPB], cur[NPB];
  __shared__ int bb[NB];
  __shared__ int base_s;
  const int b = blockIdx.x, t = threadIdx.x, nt = blockDim.x;
  if (t < NB) { int c = gcnt2[t]; bb[t] = c > RCAP ? RCAP : c; }
  for (int k = t; k < NPB; k += nt) hist[k] = 0;
  __syncthreads();
  if (t == 0) { int s = 0; for (int k = 0; k < b; ++k) s += bb[k]; base_s = s; }
  int nb = gcnt2[b]; if (nb > RCAP) nb = RCAP;
  const unsigned int* PA = rpA + (size_t)b * RCAP;
  for (int i = t; i < nb; i += nt) atomicAdd(&hist[PA[i] >> 22], 1);
  __syncthreads();
  if (t < NPB) sc[t] = hist[t];
  __syncthreads();
  for (int d = 1; d < NPB; d <<= 1) {
    int add = 0;
    if (t < NPB && t >= d) add = sc[t - d];
    __syncthreads();
    if (t < NPB && t >= d) sc[t] += add;
    __syncthreads();
  }
  if (t < NPB) pref[t] = sc[t] - hist[t];
  if (t == 0) pref[NPB] = sc[NPB - 1];
  __syncthreads();
  const int base = base_s;
  const int node0 = b * NPB;
  for (int k = t; k < NPB; k += nt) {
    int n = node0 + k;
    if (n < N_NODES) roff[n] = base + pref[k];
  }
  if (b == NB - 1 && t == 0) roff[N_NODES] = base + nb;
  __syncthreads();
  int klo = 0;
  while (klo < NPB) {
    int base0 = pref[klo];
    int khi = klo;
    while (khi < NPB && pref[khi + 1] - base0 <= LCAP2) ++khi;
    if (khi == klo) khi = klo + 1;
    for (int k = klo + t; k < khi; k += nt) cur[k] = pref[k];
    __syncthreads();
    for (int i = t; i < nb; i += nt) {
      unsigned int a = PA[i];
      int key = (int)(a >> 22);
      if (key >= klo && key < khi) {
        int p = atomicAdd(&cur[key], 1) - base0;
        if (p < LCAP2) sA[p] = a;
      }
    }
    __syncthreads();
    int csz = pref[khi] - base0;
    for (int i = t; i < csz; i += nt)
      rlist[base + base0 + i] = sA[i] & 0x3FFFFFu;
    __syncthreads();
    klo = khi;
  }
}

// ---------------------------------------------------------------------------
// K5: edge encoder (1 -> HID -> HID) in sorted order, coalesced.
// ---------------------------------------------------------------------------
__global__ __launch_bounds__(256) void k_encode(
    const unsigned short* __restrict__ svalbf, const float* __restrict__ w1,
    const float* __restrict__ b1, const float* __restrict__ w2,
    const float* __restrict__ b2, const unsigned int* __restrict__ normbits,
    unsigned short* __restrict__ e) {
  int i = blockIdx.x * blockDim.x + threadIdx.x;
  float norm = __uint_as_float(*normbits);
  float x = bflo((unsigned int)svalbf[i]) / norm;
  float h[HID];
#pragma unroll
  for (int j = 0; j < HID; ++j) h[j] = frelu(fmaf(w1[j], x, b1[j]));
  E16 o;
#pragma unroll
  for (int j = 0; j < HID; ++j) {
    float acc = b2[j];
#pragma unroll
    for (int k = 0; k < HID; ++k) acc = fmaf(w2[j * HID + k], h[k], acc);
    o.h[j] = __float2bfloat16(acc);
  }
  float4* ep = (float4*)(e + (size_t)i * HID);
  ep[0] = o.f4[0];
  ep[1] = o.f4[1];
}

// ---------------------------------------------------------------------------
// K6: receiver-side aggregate — plain sums, 2 nodes/wave, 2 lanes/entry,
// 16 B loads. ~3.2 M scattered lines (the irreducible half).
// ---------------------------------------------------------------------------
__global__ __launch_bounds__(256) void k_aggR(
    const unsigned short* __restrict__ e, const int* __restrict__ roff,
    const unsigned int* __restrict__ rlist, float* __restrict__ aggR) {
  int wave = (blockIdx.x * blockDim.x + threadIdx.x) >> 6;
  int lane = threadIdx.x & 63, half = lane >> 5, l32 = lane & 31;
  int sub = l32 & 1, j16 = l32 >> 1;
  int n = wave * 2 + half;
  int r0 = roff[n], rdeg = roff[n + 1] - r0;
  float acc[8] = {0, 0, 0, 0, 0, 0, 0, 0};
  for (int s0 = 0; s0 < rdeg; s0 += 16) {
    int slot = s0 + j16;
    bool ok = slot < rdeg;
    int idx = r0 + (ok ? slot : 0);
    unsigned int si = rlist[idx];
    uint4 raw = *(const uint4*)(e + (size_t)si * HID + sub * 8);
    float v[8] = {bflo(raw.x), bfhi(raw.x), bflo(raw.y), bfhi(raw.y),
                  bflo(raw.z), bfhi(raw.z), bflo(raw.w), bfhi(raw.w)};
#pragma unroll
    for (int c = 0; c < 8; ++c) acc[c] += ok ? v[c] : 0.f;
  }
#pragma unroll
  for (int off = 16; off >= 2; off >>= 1)
#pragma unroll
    for (int c = 0; c < 8; ++c) acc[c] += __shfl_down(acc[c], off, 64);
  if (l32 < 2) {
    *(float4*)(aggR + (size_t)n * 16 + sub * 8) =
        make_float4(acc[0], acc[1], acc[2], acc[3]);
    *(float4*)(aggR + (size_t)n * 16 + sub * 8 + 4) =
        make_float4(acc[4], acc[5], acc[6], acc[7]);
  }
}

// ---------------------------------------------------------------------------
// K7: sender-side stream (plain sums, coalesced runs) + fused node MLP.
// ---------------------------------------------------------------------------
__global__ __launch_bounds__(256) void k_nodeup(
    const unsigned short* __restrict__ e, const int* __restrict__ soff,
    const float* __restrict__ aggR, const float* __restrict__ nodesr,
    const float* __restrict__ nw1, const float* __restrict__ nb1_,
    const float* __restrict__ nw2, const float* __restrict__ nb2_,
    float* __restrict__ nodesw) {
  int wave = (blockIdx.x * blockDim.x + threadIdx.x) >> 6;
  int lane = threadIdx.x & 63, half = lane >> 5, l32 = lane & 31;
  int n = wave * 2 + half;
  int s0 = soff[n], sdeg = soff[n + 1] - s0;
  float nsv = nodesr[n];
  float accS[16];
#pragma unroll
  for (int c = 0; c < 16; ++c) accS[c] = 0.f;
  for (int c0 = 0; c0 < sdeg; c0 += 32) {
    int k = c0 + l32;
    bool ok = k < sdeg;
    int idx = s0 + (ok ? k : 0);
    uint4 ra = *(const uint4*)(e + (size_t)idx * HID);
    uint4 rb = *(const uint4*)(e + (size_t)idx * HID + 8);
    float x[16] = {bflo(ra.x), bfhi(ra.x), bflo(ra.y), bfhi(ra.y),
                   bflo(ra.z), bfhi(ra.z), bflo(ra.w), bfhi(ra.w),
                   bflo(rb.x), bfhi(rb.x), bflo(rb.y), bfhi(rb.y),
                   bflo(rb.z), bfhi(rb.z), bflo(rb.w), bfhi(rb.w)};
#pragma unroll
    for (int c = 0; c < 16; ++c) accS[c] += ok ? x[c] : 0.f;
  }
#pragma unroll
  for (int off = 16; off >= 1; off >>= 1)
#pragma unroll
    for (int c = 0; c < 16; ++c) accS[c] += __shfl_down(accS[c], off, 64);
  float aS[16];
#pragma unroll
  for (int c = 0; c < 16; ++c) aS[c] = __shfl(accS[c], half * 32, 64);
  float pv = 0.f;
  if (l32 < 16) {
    int j = l32;
    float a1 = fmaf(nw1[j * 33], nsv, nb1_[j]);
#pragma unroll
    for (int k = 0; k < 16; ++k) a1 = fmaf(nw1[j * 33 + 1 + k], aS[k], a1);
#pragma unroll
    for (int k = 0; k < 16; ++k)
      a1 = fmaf(nw1[j * 33 + 17 + k], aggR[(size_t)n * 16 + k], a1);
    pv = nw2[j] * frelu(a1);
  }
#pragma unroll
  for (int off = 8; off >= 1; off >>= 1) pv += __shfl_down(pv, off, 64);
  if (l32 == 0) nodesw[n] = pv + nb2_[0];
}

// ---------------------------------------------------------------------------
// K8: edge MLP (H+2 -> HID -> HID), THREAD-PER-EDGE straight-line (round-2
// proven form: 100% lane utilization, register-resident arrays). Sorted
// arrays -> all big streams coalesced; nodes[] scatter is L2-resident.
// __launch_bounds__(256,4): 128-VGPR budget so x/h stay in registers.
// ---------------------------------------------------------------------------
__global__ __launch_bounds__(256, 4) void k_edgeE(
    unsigned short* __restrict__ e, const unsigned int* __restrict__ srecv,
    const unsigned short* __restrict__ ssend16, const int* __restrict__ bstart,
    const float* __restrict__ nodes, const float* __restrict__ w1,
    const float* __restrict__ b1, const float* __restrict__ w2,
    const float* __restrict__ b2) {
  int i = blockIdx.x * blockDim.x + threadIdx.x;
  int bk = find_bucket(bstart, i);
  int snd = bk * NPB + (int)ssend16[i];
  float ns = nodes[snd], nr = nodes[srecv[i]];
  float4* ep = (float4*)(e + (size_t)i * HID);
  E16 in;
  in.f4[0] = ep[0];
  in.f4[1] = ep[1];
  float x[HID];
#pragma unroll
  for (int k = 0; k < HID; ++k) x[k] = __bfloat162float(in.h[k]);
  float h[HID];
#pragma unroll
  for (int j = 0; j < HID; ++j) {
    float acc = b1[j];
#pragma unroll
    for (int k = 0; k < HID; ++k) acc = fmaf(w1[j * 18 + k], x[k], acc);
    acc = fmaf(w1[j * 18 + 16], ns, acc);
    acc = fmaf(w1[j * 18 + 17], nr, acc);
    h[j] = frelu(acc);
  }
  E16 o;
#pragma unroll
  for (int j = 0; j < HID; ++j) {
    float acc = b2[j];
#pragma unroll
    for (int k = 0; k < HID; ++k) acc = fmaf(w2[j * HID + k], h[k], acc);
    o.h[j] = __float2bfloat16(acc);
  }
  ep[0] = o.f4[0];
  ep[1] = o.f4[1];
}

// ---------------------------------------------------------------------------
// K9: final — round-3 edge MLP + decoder, THREAD-PER-EDGE. Writes the GNN
// delta only (out[orig] = alphaN*d, one scattered 4 B store); the residual
// add is k_resid (coalesced, reads edges0 directly).
// ---------------------------------------------------------------------------
__global__ __launch_bounds__(256, 4) void k_final(
    const unsigned short* __restrict__ e, const unsigned int* __restrict__ srecv,
    const unsigned short* __restrict__ ssend16, const int* __restrict__ bstart,
    const unsigned int* __restrict__ sorig, const float* __restrict__ nodes,
    const float* __restrict__ ew1, const float* __restrict__ eb1,
    const float* __restrict__ ew2, const float* __restrict__ eb2,
    const float* __restrict__ dw1, const float* __restrict__ db1,
    const float* __restrict__ dw2, const float* __restrict__ db2,
    const unsigned int* __restrict__ normbits, const float* __restrict__ alpha,
    float* __restrict__ out) {
  int i = blockIdx.x * blockDim.x + threadIdx.x;
  int bk = find_bucket(bstart, i);
  int snd = bk * NPB + (int)ssend16[i];
  float ns = nodes[snd], nr = nodes[srecv[i]];
  const float4* ep = (const float4*)(e + (size_t)i * HID);
  E16 in;
  in.f4[0] = ep[0];
  in.f4[1] = ep[1];
  float x[HID];
#pragma unroll
  for (int k = 0; k < HID; ++k) x[k] = __bfloat162float(in.h[k]);
  float h[HID];
#pragma unroll
  for (int j = 0; j < HID; ++j) {
    float acc = eb1[j];
#pragma unroll
    for (int k = 0; k < HID; ++k) acc = fmaf(ew1[j * 18 + k], x[k], acc);
    acc = fmaf(ew1[j * 18 + 16], ns, acc);
    acc = fmaf(ew1[j * 18 + 17], nr, acc);
    h[j] = frelu(acc);
  }
  float y[HID];
#pragma unroll
  for (int j = 0; j < HID; ++j) {
    float acc = eb2[j];
#pragma unroll
    for (int k = 0; k < HID; ++k) acc = fmaf(ew2[j * HID + k], h[k], acc);
    y[j] = acc;
  }
  float d = db2[0];
#pragma unroll
  for (int j = 0; j < HID; ++j) {
    float acc = db1[j];
#pragma unroll
    for (int k = 0; k < HID; ++k) acc = fmaf(dw1[j * HID + k], y[k], acc);
    d = fmaf(dw2[j], frelu(acc), d);
  }
  float alphaN = alpha[0] * __uint_as_float(*normbits);
  out[sorig[i]] = alphaN * d;
}

// ---------------------------------------------------------------------------
// K10: residual add, fully coalesced: out[i] += edges_init[i]
// ---------------------------------------------------------------------------
__global__ __launch_bounds__(256) void k_resid(const float* __restrict__ edges,
                                               float* __restrict__ out) {
  int i = blockIdx.x * blockDim.x + threadIdx.x;
  out[i] += edges[i];
}

// ---------------------------------------------------------------------------
extern "C" void kernel_launch(void* const* d_in, const int* in_sizes, int n_in,
                              void* d_out, int out_size, void* d_ws,
                              size_t ws_size, hipStream_t stream) {
  const float* nodes0 = (const float*)d_in[0];
  const float* edges0 = (const float*)d_in[1];
  const int* senders = (const int*)d_in[2];
  const int* receivers = (const int*)d_in[3];
  const float* enc_w1 = (const float*)d_in[4];
  const float* enc_b1 = (const float*)d_in[5];
  const float* enc_w2 = (const float*)d_in[6];
  const float* enc_b2 = (const float*)d_in[7];
  const float* node_w1 = (const float*)d_in[8];
  const float* node_b1 = (const float*)d_in[9];
  const float* node_w2 = (const float*)d_in[10];
  const float* node_b2 = (const float*)d_in[11];
  const float* edge_w1 = (const float*)d_in[12];
  const float* edge_b1 = (const float*)d_in[13];
  const float* edge_w2 = (const float*)d_in[14];
  const float* edge_b2 = (const float*)d_in[15];
  const float* dec_w1 = (const float*)d_in[16];
  const float* dec_b1 = (const float*)d_in[17];
  const float* dec_w2 = (const float*)d_in[18];
  const float* dec_b2 = (const float*)d_in[19];
  const float* alpha = (const float*)d_in[20];

  // Workspace layout: ~161.6 MB (== round-5 proven footprint).
  char* ws = (char*)d_ws;
  unsigned short* e = (unsigned short*)ws;  // 3.2M x 32 B = 102.4 MB (sorted)
  char* p = ws + (size_t)N_EDGES * HID * 2;
  unsigned int* srecv = (unsigned int*)p;    p += (size_t)N_EDGES * 4;  // 12.8
  unsigned int* sorig = (unsigned int*)p;    p += (size_t)N_EDGES * 4;  // 12.8
  unsigned int* rlist = (unsigned int*)p;    p += (size_t)N_EDGES * 4;  // 12.8
  unsigned short* ssend16 = (unsigned short*)p; p += (size_t)N_EDGES * 2;  // 6.4
  unsigned short* svalbf = (unsigned short*)p;  p += (size_t)N_EDGES * 2;  // 6.4
  float* aggR = (float*)p;                   p += (size_t)N_NODES * 16 * 4;  // 6.4
  int* soff = (int*)p;                       p += (size_t)(N_NODES + 16) * 4;
  int* roff = (int*)p;                       p += (size_t)(N_NODES + 16) * 4;
  float* nbA = (float*)p;                    p += (size_t)N_NODES * 4;
  float* nbB = (float*)p;                    p += (size_t)N_NODES * 4;
  unsigned int* normbits = (unsigned int*)p; p += 64;
  int* gcnt = (int*)p;                       p += NB * 4;
  int* gcnt2 = (int*)p;                      p += NB * 4;
  int* bstart = (int*)p;                     p += (NB + 1) * 4;
  // build staging aliases e (dead until k_encode):
  unsigned int* pM = (unsigned int*)ws;
  float* pV = (float*)(ws + (size_t)NB * SCAP * 4);
  unsigned int* pO = (unsigned int*)(ws + (size_t)NB * SCAP * 8);
  unsigned int* rpA = (unsigned int*)(ws + (size_t)NB * SCAP * 12);

  const int ngrid = 12500;  // 2 nodes/wave x 4 waves/block -> 100000 nodes
  const int egrid = N_EDGES / BLK;  // 12500

  hipMemsetAsync(normbits, 0, 64 + 2 * NB * 4, stream);  // norm + gcnt + gcnt2
  k_norm<<<512, BLK, 0, stream>>>(edges0, normbits);
  k_split<<<256, 1024, 0, stream>>>(senders, receivers, edges0, gcnt, pM, pV, pO);
  k_bsort1<<<NB, 1024, 0, stream>>>(pM, pV, pO, gcnt, srecv, sorig, svalbf,
                                    soff, bstart);
  k_sfill<<<ngrid, BLK, 0, stream>>>(soff, ssend16);
  k_rsplit<<<256, 1024, 0, stream>>>(srecv, gcnt2, rpA);
  k_rsort<<<NB, 1024, 0, stream>>>(rpA, gcnt2, rlist, roff);
  k_encode<<<egrid, BLK, 0, stream>>>(svalbf, enc_w1, enc_b1, enc_w2, enc_b2,
                                      normbits, e);  // clobbers staging
  // round 1
  k_aggR<<<ngrid, BLK, 0, stream>>>(e, roff, rlist, aggR);
  k_nodeup<<<ngrid, BLK, 0, stream>>>(e, soff, aggR, nodes0, node_w1, node_b1,
                                      node_w2, node_b2, nbA);
  k_edgeE<<<egrid, BLK, 0, stream>>>(e, srecv, ssend16, bstart, nbA, edge_w1,
                                     edge_b1, edge_w2, edge_b2);
  // round 2
  k_aggR<<<ngrid, BLK, 0, stream>>>(e, roff, rlist, aggR);
  k_nodeup<<<ngrid, BLK, 0, stream>>>(e, soff, aggR, nbA, node_w1, node_b1,
                                      node_w2, node_b2, nbB);
  k_edgeE<<<egrid, BLK, 0, stream>>>(e, srecv, ssend16, bstart, nbB, edge_w1,
                                     edge_b1, edge_w2, edge_b2);
  // round 3
  k_aggR<<<ngrid, BLK, 0, stream>>>(e, roff, rlist, aggR);
  k_nodeup<<<ngrid, BLK, 0, stream>>>(e, soff, aggR, nbB, node_w1, node_b1,
                                      node_w2, node_b2, nbA);
  // final: e3 = edgeMLP(e2, nbA) -> decoder -> delta; then residual add
  k_final<<<egrid, BLK, 0, stream>>>(e, srecv, ssend16, bstart, sorig, nbA,
                                     edge_w1, edge_b1, edge_w2, edge_b2,
                                     dec_w1, dec_b1, dec_w2, dec_b2, normbits,
                                     alpha, (float*)d_out);
  k_resid<<<egrid, BLK, 0, stream>>>(edges0, (float*)d_out);
}

// Round 7
// 918.160 us; speedup vs baseline: 3.1572x; 1.0824x over previous
//
#include <hip/hip_runtime.h>
#include <hip/hip_bf16.h>

#define N_NODES 100000
#define N_EDGES 3200000
#define HID 16
#define NB 256       // buckets; bucket = NPB consecutive nodes
#define NPB 391      // 256*391 = 100096 >= 100000
#define SCAP 15360   // per-bucket staging cap (mean 12500, +25 sigma)
#define RCAP 15360
#define FDEPTH 32    // LDS FIFO depth in split kernels
#define LCAP1 8704   // bsort1 LDS chunk entries (12 B) -> ~102 KB
#define LCAP2 26624  // rsort LDS chunk entries (4 B) -> 104 KB (1 chunk/bucket)

static constexpr int BLK = 256;

__device__ __forceinline__ float frelu(float x) { return fmaxf(x, 0.f); }
__device__ __forceinline__ float bflo(unsigned int u) {
  return __uint_as_float(u << 16);
}
__device__ __forceinline__ float bfhi(unsigned int u) {
  return __uint_as_float(u & 0xFFFF0000u);
}

// bucket of sorted-edge i: 8-step binary search over bstart[0..NB]
// (lanes in a wave share 1-2 buckets -> loads are L1-broadcast hits)
__device__ __forceinline__ int find_bucket(const int* __restrict__ bstart,
                                           int i) {
  int lo = 0, hi = NB;
#pragma unroll
  for (int s = 0; s < 8; ++s) {
    int mid = (lo + hi) >> 1;
    if (i >= bstart[mid]) lo = mid; else hi = mid;
  }
  return lo;
}

union E16 {
  float4 f4[2];
  __hip_bfloat16 h[16];
};

// ---------------------------------------------------------------------------
// K0: norm = max |edges_init|
// ---------------------------------------------------------------------------
__global__ __launch_bounds__(256) void k_norm(const float* __restrict__ edges,
                                              unsigned int* __restrict__ normbits) {
  float m = 0.f;
  for (int i = blockIdx.x * blockDim.x + threadIdx.x; i < N_EDGES;
       i += gridDim.x * blockDim.x)
    m = fmaxf(m, fabsf(edges[i]));
#pragma unroll
  for (int off = 32; off > 0; off >>= 1)
    m = fmaxf(m, __shfl_down(m, off, 64));
  __shared__ float smax[BLK / 64];
  if ((threadIdx.x & 63) == 0) smax[threadIdx.x >> 6] = m;
  __syncthreads();
  if (threadIdx.x == 0) {
    float b = smax[0];
#pragma unroll
    for (int w = 1; w < BLK / 64; ++w) b = fmaxf(b, smax[w]);
    atomicMax(normbits, __float_as_uint(b));
  }
}

// ---------------------------------------------------------------------------
// K1: bucket edges by SENDER via LDS FIFOs (line-granular flushes).
// record: m = (sender_local<<22) | orig_edge(22b), v = edges_init, o = recv
// ---------------------------------------------------------------------------
__global__ __launch_bounds__(1024) void k_split(
    const int* __restrict__ senders, const int* __restrict__ receivers,
    const float* __restrict__ edges, int* __restrict__ gcnt,
    unsigned int* __restrict__ pM, float* __restrict__ pV,
    unsigned int* __restrict__ pO) {
  __shared__ __align__(16) unsigned int fM[NB][FDEPTH];
  __shared__ __align__(16) unsigned int fV[NB][FDEPTH];
  __shared__ __align__(16) unsigned int fO[NB][FDEPTH];
  __shared__ int fcnt[NB];
  const int t = threadIdx.x;
  if (t < NB) fcnt[t] = 0;
  __syncthreads();
  const int e0 = blockIdx.x * (N_EDGES / 256);
  const int e1 = e0 + (N_EDGES / 256);
  for (int base = e0; base < e1; base += 1024) {
    const int i = base + t;
    if (i < e1) {
      int s = senders[i];
      unsigned int b = (unsigned int)s / NPB;
      unsigned int m = (((unsigned int)s - b * NPB) << 22) | (unsigned int)i;
      unsigned int v = __float_as_uint(edges[i]);
      unsigned int o = (unsigned int)receivers[i];
      int pos = atomicAdd(&fcnt[b], 1);
      if (pos < FDEPTH) {
        fM[b][pos] = m; fV[b][pos] = v; fO[b][pos] = o;
      } else {  // rare overflow: direct append
        int gb = atomicAdd(&gcnt[b], 1);
        if (gb < SCAP) {
          pM[(size_t)b * SCAP + gb] = m;
          pV[(size_t)b * SCAP + gb] = __uint_as_float(v);
          pO[(size_t)b * SCAP + gb] = o;
        }
      }
    }
    __syncthreads();
    const bool last = (base + 1024 >= e1);
    if (t < NB) {
      int c = fcnt[t]; if (c > FDEPTH) c = FDEPTH;
      int nf = last ? c : (c & ~15);
      if (nf > 0) {
        int gb = atomicAdd(&gcnt[t], nf);
        size_t db = (size_t)t * SCAP + gb;
        if ((gb & 3) == 0 && gb + nf <= SCAP) {
          int k = 0;
          for (; k + 4 <= nf; k += 4) {
            *(uint4*)(pM + db + k) = *(const uint4*)(&fM[t][k]);
            *(uint4*)((unsigned int*)pV + db + k) = *(const uint4*)(&fV[t][k]);
            *(uint4*)(pO + db + k) = *(const uint4*)(&fO[t][k]);
          }
          for (; k < nf; ++k) {
            pM[db + k] = fM[t][k]; pV[db + k] = __uint_as_float(fV[t][k]);
            pO[db + k] = fO[t][k];
          }
        } else {
          for (int k = 0; k < nf; ++k)
            if (gb + k < SCAP) {
              pM[db + k] = fM[t][k]; pV[db + k] = __uint_as_float(fV[t][k]);
              pO[db + k] = fO[t][k];
            }
        }
        int res = c - nf;
        for (int k = 0; k < res; ++k) {
          fM[t][k] = fM[t][nf + k]; fV[t][k] = fV[t][nf + k];
          fO[t][k] = fO[t][nf + k];
        }
        fcnt[t] = res;
      } else fcnt[t] = c;
    }
    __syncthreads();
  }
}

// ---------------------------------------------------------------------------
// K2: per-bucket counting sort by sender_local -> EXACT global sender CSR.
// Writes srecv/sorig/svalbf (bf16, encoder-input-only) + soff + bstart.
// ---------------------------------------------------------------------------
__global__ __launch_bounds__(1024) void k_bsort1(
    const unsigned int* __restrict__ pM, const float* __restrict__ pV,
    const unsigned int* __restrict__ pO, const int* __restrict__ gcnt,
    unsigned int* __restrict__ srecv, unsigned int* __restrict__ sorig,
    unsigned short* __restrict__ svalbf, int* __restrict__ soff,
    int* __restrict__ bstart) {
  __shared__ unsigned int sM[LCAP1];
  __shared__ float sV[LCAP1];
  __shared__ unsigned int sO[LCAP1];
  __shared__ int hist[NPB], pref[NPB + 1], sc[NPB], cur[NPB];
  __shared__ int bb[NB];
  __shared__ int base_s;
  const int b = blockIdx.x, t = threadIdx.x, nt = blockDim.x;
  if (t < NB) { int c = gcnt[t]; bb[t] = c > SCAP ? SCAP : c; }
  for (int k = t; k < NPB; k += nt) hist[k] = 0;
  __syncthreads();
  if (t == 0) { int s = 0; for (int k = 0; k < b; ++k) s += bb[k]; base_s = s; }
  int nb = gcnt[b]; if (nb > SCAP) nb = SCAP;
  const unsigned int* PM = pM + (size_t)b * SCAP;
  const float* PV = pV + (size_t)b * SCAP;
  const unsigned int* PO = pO + (size_t)b * SCAP;
  for (int i = t; i < nb; i += nt) atomicAdd(&hist[PM[i] >> 22], 1);
  __syncthreads();
  if (t < NPB) sc[t] = hist[t];
  __syncthreads();
  for (int d = 1; d < NPB; d <<= 1) {
    int add = 0;
    if (t < NPB && t >= d) add = sc[t - d];
    __syncthreads();
    if (t < NPB && t >= d) sc[t] += add;
    __syncthreads();
  }
  if (t < NPB) pref[t] = sc[t] - hist[t];
  if (t == 0) pref[NPB] = sc[NPB - 1];
  __syncthreads();
  const int base = base_s;
  const int node0 = b * NPB;
  for (int k = t; k < NPB; k += nt) {
    int n = node0 + k;
    if (n < N_NODES) soff[n] = base + pref[k];
  }
  if (t == 0) bstart[b] = base;
  if (b == NB - 1 && t == 0) {
    soff[N_NODES] = base + nb;
    bstart[NB] = base + nb;
  }
  __syncthreads();
  int klo = 0;
  while (klo < NPB) {
    int base0 = pref[klo];
    int khi = klo;
    while (khi < NPB && pref[khi + 1] - base0 <= LCAP1) ++khi;
    if (khi == klo) khi = klo + 1;  // safety
    for (int k = klo + t; k < khi; k += nt) cur[k] = pref[k];
    __syncthreads();
    for (int i = t; i < nb; i += nt) {
      unsigned int m = PM[i];
      int key = (int)(m >> 22);
      if (key >= klo && key < khi) {
        int p = atomicAdd(&cur[key], 1) - base0;
        if (p < LCAP1) { sM[p] = m; sV[p] = PV[i]; sO[p] = PO[i]; }
      }
    }
    __syncthreads();
    int csz = pref[khi] - base0;
    for (int i = t; i < csz; i += nt) {
      int g = base + base0 + i;
      srecv[g] = sO[i]; sorig[g] = sM[i] & 0x3FFFFFu;
      __hip_bfloat16 hb = __float2bfloat16(sV[i]);
      svalbf[g] = *(unsigned short*)&hb;
    }
    __syncthreads();
    klo = khi;
  }
}

// ---------------------------------------------------------------------------
// K2b: ssend16[i] = sender_local of sorted edge i (node-major, coalesced)
// ---------------------------------------------------------------------------
__global__ __launch_bounds__(256) void k_sfill(
    const int* __restrict__ soff, unsigned short* __restrict__ ssend16) {
  int wave = (blockIdx.x * blockDim.x + threadIdx.x) >> 6;
  int lane = threadIdx.x & 63, half = lane >> 5, l32 = lane & 31;
  int n = wave * 2 + half;
  unsigned short local = (unsigned short)(n - (n / NPB) * NPB);
  int s0 = soff[n], s1 = soff[n + 1];
  for (int k = s0 + l32; k < s1; k += 32) ssend16[k] = local;
}

// ---------------------------------------------------------------------------
// K3: bucket sorted edges by RECEIVER. a = (recv_local<<22) | sorted_idx
// ---------------------------------------------------------------------------
__global__ __launch_bounds__(1024) void k_rsplit(
    const unsigned int* __restrict__ srecv, int* __restrict__ gcnt2,
    unsigned int* __restrict__ rpA) {
  __shared__ __align__(16) unsigned int fA[NB][FDEPTH];
  __shared__ int fcnt[NB];
  const int t = threadIdx.x;
  if (t < NB) fcnt[t] = 0;
  __syncthreads();
  const int e0 = blockIdx.x * (N_EDGES / 256);
  const int e1 = e0 + (N_EDGES / 256);
  for (int base = e0; base < e1; base += 1024) {
    const int i = base + t;
    if (i < e1) {
      unsigned int r = srecv[i];
      unsigned int b = r / NPB;
      unsigned int a = ((r - b * NPB) << 22) | (unsigned int)i;
      int pos = atomicAdd(&fcnt[b], 1);
      if (pos < FDEPTH) {
        fA[b][pos] = a;
      } else {
        int gb = atomicAdd(&gcnt2[b], 1);
        if (gb < RCAP) rpA[(size_t)b * RCAP + gb] = a;
      }
    }
    __syncthreads();
    const bool last = (base + 1024 >= e1);
    if (t < NB) {
      int c = fcnt[t]; if (c > FDEPTH) c = FDEPTH;
      int nf = last ? c : (c & ~15);
      if (nf > 0) {
        int gb = atomicAdd(&gcnt2[t], nf);
        size_t db = (size_t)t * RCAP + gb;
        if ((gb & 3) == 0 && gb + nf <= RCAP) {
          int k = 0;
          for (; k + 4 <= nf; k += 4)
            *(uint4*)(rpA + db + k) = *(const uint4*)(&fA[t][k]);
          for (; k < nf; ++k) rpA[db + k] = fA[t][k];
        } else {
          for (int k = 0; k < nf; ++k)
            if (gb + k < RCAP) rpA[db + k] = fA[t][k];
        }
        int res = c - nf;
        for (int k = 0; k < res; ++k) fA[t][k] = fA[t][nf + k];
        fcnt[t] = res;
      } else fcnt[t] = c;
    }
    __syncthreads();
  }
}

// ---------------------------------------------------------------------------
// K4: per-bucket counting sort by recv_local -> receiver CSR (roff) + rlist.
// ---------------------------------------------------------------------------
__global__ __launch_bounds__(1024) void k_rsort(
    const unsigned int* __restrict__ rpA, const int* __restrict__ gcnt2,
    unsigned int* __restrict__ rlist, int* __restrict__ roff) {
  __shared__ unsigned int sA[LCAP2];
  __shared__ int hist[NPB], pref[NPB + 1], sc[NPB], cur[NPB];
  __shared__ int bb[NB];
  __shared__ int base_s;
  const int b = blockIdx.x, t = threadIdx.x, nt = blockDim.x;
  if (t < NB) { int c = gcnt2[t]; bb[t] = c > RCAP ? RCAP : c; }
  for (int k = t; k < NPB; k += nt) hist[k] = 0;
  __syncthreads();
  if (t == 0) { int s = 0; for (int k = 0; k < b; ++k) s += bb[k]; base_s = s; }
  int nb = gcnt2[b]; if (nb > RCAP) nb = RCAP;
  const unsigned int* PA = rpA + (size_t)b * RCAP;
  for (int i = t; i < nb; i += nt) atomicAdd(&hist[PA[i] >> 22], 1);
  __syncthreads();
  if (t < NPB) sc[t] = hist[t];
  __syncthreads();
  for (int d = 1; d < NPB; d <<= 1) {
    int add = 0;
    if (t < NPB && t >= d) add = sc[t - d];
    __syncthreads();
    if (t < NPB && t >= d) sc[t] += add;
    __syncthreads();
  }
  if (t < NPB) pref[t] = sc[t] - hist[t];
  if (t == 0) pref[NPB] = sc[NPB - 1];
  __syncthreads();
  const int base = base_s;
  const int node0 = b * NPB;
  for (int k = t; k < NPB; k += nt) {
    int n = node0 + k;
    if (n < N_NODES) roff[n] = base + pref[k];
  }
  if (b == NB - 1 && t == 0) roff[N_NODES] = base + nb;
  __syncthreads();
  int klo = 0;
  while (klo < NPB) {
    int base0 = pref[klo];
    int khi = klo;
    while (khi < NPB && pref[khi + 1] - base0 <= LCAP2) ++khi;
    if (khi == klo) khi = klo + 1;
    for (int k = klo + t; k < khi; k += nt) cur[k] = pref[k];
    __syncthreads();
    for (int i = t; i < nb; i += nt) {
      unsigned int a = PA[i];
      int key = (int)(a >> 22);
      if (key >= klo && key < khi) {
        int p = atomicAdd(&cur[key], 1) - base0;
        if (p < LCAP2) sA[p] = a;
      }
    }
    __syncthreads();
    int csz = pref[khi] - base0;
    for (int i = t; i < csz; i += nt)
      rlist[base + base0 + i] = sA[i] & 0x3FFFFFu;
    __syncthreads();
    klo = khi;
  }
}

// ---------------------------------------------------------------------------
// K5: edge encoder (1 -> HID -> HID) in sorted order, coalesced.
// ---------------------------------------------------------------------------
__global__ __launch_bounds__(256) void k_encode(
    const unsigned short* __restrict__ svalbf, const float* __restrict__ w1,
    const float* __restrict__ b1, const float* __restrict__ w2,
    const float* __restrict__ b2, const unsigned int* __restrict__ normbits,
    unsigned short* __restrict__ e) {
  int i = blockIdx.x * blockDim.x + threadIdx.x;
  float norm = __uint_as_float(*normbits);
  float x = bflo((unsigned int)svalbf[i]) / norm;
  float h[HID];
#pragma unroll
  for (int j = 0; j < HID; ++j) h[j] = frelu(fmaf(w1[j], x, b1[j]));
  E16 o;
#pragma unroll
  for (int j = 0; j < HID; ++j) {
    float acc = b2[j];
#pragma unroll
    for (int k = 0; k < HID; ++k) acc = fmaf(w2[j * HID + k], h[k], acc);
    o.h[j] = __float2bfloat16(acc);
  }
  float4* ep = (float4*)(e + (size_t)i * HID);
  ep[0] = o.f4[0];
  ep[1] = o.f4[1];
}

// ---------------------------------------------------------------------------
// K6: FUSED receiver-gather + sender-stream + node MLP (replaces
// k_aggR + k_nodeup: both read the same previous-round e; the aggR global
// buffer round-trip and 3 launches disappear). Round-4 lesson respected:
// NO edge-MLP recompute here — phases are plain sums, VGPR stays ~50.
// 2 nodes/wave. Phase A: 2 lanes/entry scattered 16 B reads (1 line per
// 32 B record). Phase B: 1 lane/edge coalesced 32 B. Recv aggregates are
// passed to the MLP lanes by shuffle (no global buffer).
// ---------------------------------------------------------------------------
__global__ __launch_bounds__(256) void k_aggN(
    const unsigned short* __restrict__ e, const int* __restrict__ roff,
    const unsigned int* __restrict__ rlist, const int* __restrict__ soff,
    const float* __restrict__ nodesr, const float* __restrict__ nw1,
    const float* __restrict__ nb1_, const float* __restrict__ nw2,
    const float* __restrict__ nb2_, float* __restrict__ nodesw) {
  int wave = (blockIdx.x * blockDim.x + threadIdx.x) >> 6;
  int lane = threadIdx.x & 63, half = lane >> 5, l32 = lane & 31;
  int n = wave * 2 + half;
  // ---- phase A: receiver-side scattered gather ----
  int sub = l32 & 1, j16 = l32 >> 1;
  int r0 = roff[n], rdeg = roff[n + 1] - r0;
  float ar[8] = {0, 0, 0, 0, 0, 0, 0, 0};
  for (int q0 = 0; q0 < rdeg; q0 += 16) {
    int slot = q0 + j16;
    bool ok = slot < rdeg;
    int idx = r0 + (ok ? slot : 0);
    unsigned int si = rlist[idx];
    uint4 raw = *(const uint4*)(e + (size_t)si * HID + sub * 8);
    float v[8] = {bflo(raw.x), bfhi(raw.x), bflo(raw.y), bfhi(raw.y),
                  bflo(raw.z), bfhi(raw.z), bflo(raw.w), bfhi(raw.w)};
#pragma unroll
    for (int c = 0; c < 8; ++c) ar[c] += ok ? v[c] : 0.f;
  }
#pragma unroll
  for (int off = 16; off >= 2; off >>= 1)
#pragma unroll
    for (int c = 0; c < 8; ++c) ar[c] += __shfl_down(ar[c], off, 64);
  // lanes half*32+{0,1} now hold recv channels {0..7} / {8..15}
  // ---- phase B: sender-side coalesced stream ----
  int s0 = soff[n], sdeg = soff[n + 1] - s0;
  float as[16];
#pragma unroll
  for (int c = 0; c < 16; ++c) as[c] = 0.f;
  for (int c0 = 0; c0 < sdeg; c0 += 32) {
    int k = c0 + l32;
    bool ok = k < sdeg;
    int idx = s0 + (ok ? k : 0);
    uint4 ra = *(const uint4*)(e + (size_t)idx * HID);
    uint4 rb = *(const uint4*)(e + (size_t)idx * HID + 8);
    float x[16] = {bflo(ra.x), bfhi(ra.x), bflo(ra.y), bfhi(ra.y),
                   bflo(ra.z), bfhi(ra.z), bflo(ra.w), bfhi(ra.w),
                   bflo(rb.x), bfhi(rb.x), bflo(rb.y), bfhi(rb.y),
                   bflo(rb.z), bfhi(rb.z), bflo(rb.w), bfhi(rb.w)};
#pragma unroll
    for (int c = 0; c < 16; ++c) as[c] += ok ? x[c] : 0.f;
  }
#pragma unroll
  for (int off = 16; off >= 1; off >>= 1)
#pragma unroll
    for (int c = 0; c < 16; ++c) as[c] += __shfl_down(as[c], off, 64);
  // ---- node MLP on lanes l32<16 ----
  float aS[16], aR[16];
#pragma unroll
  for (int c = 0; c < 16; ++c) aS[c] = __shfl(as[c], half * 32, 64);
#pragma unroll
  for (int k = 0; k < 8; ++k) aR[k] = __shfl(ar[k], half * 32, 64);
#pragma unroll
  for (int k = 0; k < 8; ++k) aR[8 + k] = __shfl(ar[k], half * 32 + 1, 64);
  float nsv = nodesr[n];
  float pv = 0.f;
  if (l32 < 16) {
    int j = l32;
    float a1 = fmaf(nw1[j * 33], nsv, nb1_[j]);
#pragma unroll
    for (int k = 0; k < 16; ++k) a1 = fmaf(nw1[j * 33 + 1 + k], aS[k], a1);
#pragma unroll
    for (int k = 0; k < 16; ++k) a1 = fmaf(nw1[j * 33 + 17 + k], aR[k], a1);
    pv = nw2[j] * frelu(a1);
  }
#pragma unroll
  for (int off = 8; off >= 1; off >>= 1) pv += __shfl_down(pv, off, 64);
  if (l32 == 0) nodesw[n] = pv + nb2_[0];
}

// ---------------------------------------------------------------------------
// K7: edge MLP, thread-per-edge, K-OUTER accumulation: each packed bf16 pair
// is unpacked ONCE and immediately FMA'd into all 16 h — minimal live set
// (h[16] + 1 pair) so the allocator can't be forced into re-unpack inflation
// (round-6 k_final: VGPR=32, 2.3x instr bloat). (256,2): 256-VGPR cap.
// ---------------------------------------------------------------------------
__global__ __launch_bounds__(256, 2) void k_edgeE(
    unsigned short* __restrict__ e, const unsigned int* __restrict__ srecv,
    const unsigned short* __restrict__ ssend16, const int* __restrict__ bstart,
    const float* __restrict__ nodes, const float* __restrict__ w1,
    const float* __restrict__ b1, const float* __restrict__ w2,
    const float* __restrict__ b2) {
  int i = blockIdx.x * blockDim.x + threadIdx.x;
  int bk = find_bucket(bstart, i);
  int snd = bk * NPB + (int)ssend16[i];
  float ns = nodes[snd], nr = nodes[srecv[i]];
  uint4* ep = (uint4*)(e + (size_t)i * HID);
  uint4 ra = ep[0], rb = ep[1];
  unsigned int pk[8] = {ra.x, ra.y, ra.z, ra.w, rb.x, rb.y, rb.z, rb.w};
  float h[16];
#pragma unroll
  for (int j = 0; j < 16; ++j)
    h[j] = fmaf(w1[j * 18 + 16], ns, fmaf(w1[j * 18 + 17], nr, b1[j]));
#pragma unroll
  for (int kp = 0; kp < 8; ++kp) {
    float x0 = bflo(pk[kp]), x1 = bfhi(pk[kp]);
#pragma unroll
    for (int j = 0; j < 16; ++j)
      h[j] = fmaf(w1[j * 18 + 2 * kp + 1], x1,
                  fmaf(w1[j * 18 + 2 * kp], x0, h[j]));
  }
#pragma unroll
  for (int j = 0; j < 16; ++j) h[j] = frelu(h[j]);
  float y[16];
#pragma unroll
  for (int c = 0; c < 16; ++c) y[c] = b2[c];
#pragma unroll
  for (int j = 0; j < 16; ++j)
#pragma unroll
    for (int c = 0; c < 16; ++c) y[c] = fmaf(w2[c * HID + j], h[j], y[c]);
  E16 o;
#pragma unroll
  for (int c = 0; c < 16; ++c) o.h[c] = __float2bfloat16(y[c]);
  float4* fp = (float4*)ep;
  fp[0] = o.f4[0];
  fp[1] = o.f4[1];
}

// ---------------------------------------------------------------------------
// K8: final — round-3 edge MLP + decoder, thread-per-edge, k-outer form.
// Writes delta only (scattered 4 B store); residual added by k_resid.
// ---------------------------------------------------------------------------
__global__ __launch_bounds__(256, 2) void k_final(
    const unsigned short* __restrict__ e, const unsigned int* __restrict__ srecv,
    const unsigned short* __restrict__ ssend16, const int* __restrict__ bstart,
    const unsigned int* __restrict__ sorig, const float* __restrict__ nodes,
    const float* __restrict__ ew1, const float* __restrict__ eb1,
    const float* __restrict__ ew2, const float* __restrict__ eb2,
    const float* __restrict__ dw1, const float* __restrict__ db1,
    const float* __restrict__ dw2, const float* __restrict__ db2,
    const unsigned int* __restrict__ normbits, const float* __restrict__ alpha,
    float* __restrict__ out) {
  int i = blockIdx.x * blockDim.x + threadIdx.x;
  int bk = find_bucket(bstart, i);
  int snd = bk * NPB + (int)ssend16[i];
  float ns = nodes[snd], nr = nodes[srecv[i]];
  const uint4* ep = (const uint4*)(e + (size_t)i * HID);
  uint4 ra = ep[0], rb = ep[1];
  unsigned int pk[8] = {ra.x, ra.y, ra.z, ra.w, rb.x, rb.y, rb.z, rb.w};
  float h[16];
#pragma unroll
  for (int j = 0; j < 16; ++j)
    h[j] = fmaf(ew1[j * 18 + 16], ns, fmaf(ew1[j * 18 + 17], nr, eb1[j]));
#pragma unroll
  for (int kp = 0; kp < 8; ++kp) {
    float x0 = bflo(pk[kp]), x1 = bfhi(pk[kp]);
#pragma unroll
    for (int j = 0; j < 16; ++j)
      h[j] = fmaf(ew1[j * 18 + 2 * kp + 1], x1,
                  fmaf(ew1[j * 18 + 2 * kp], x0, h[j]));
  }
#pragma unroll
  for (int j = 0; j < 16; ++j) h[j] = frelu(h[j]);
  float y[16];
#pragma unroll
  for (int c = 0; c < 16; ++c) y[c] = eb2[c];
#pragma unroll
  for (int j = 0; j < 16; ++j)
#pragma unroll
    for (int c = 0; c < 16; ++c) y[c] = fmaf(ew2[c * HID + j], h[j], y[c]);
  float d = db2[0];
#pragma unroll
  for (int j = 0; j < 16; ++j) {
    float a1 = db1[j];
#pragma unroll
    for (int k = 0; k < 16; ++k) a1 = fmaf(dw1[j * HID + k], y[k], a1);
    d = fmaf(dw2[j], frelu(a1), d);
  }
  float alphaN = alpha[0] * __uint_as_float(*normbits);
  out[sorig[i]] = alphaN * d;
}

// ---------------------------------------------------------------------------
// K9: residual add, fully coalesced: out[i] += edges_init[i]
// ---------------------------------------------------------------------------
__global__ __launch_bounds__(256) void k_resid(const float* __restrict__ edges,
                                               float* __restrict__ out) {
  int i = blockIdx.x * blockDim.x + threadIdx.x;
  out[i] += edges[i];
}

// ---------------------------------------------------------------------------
extern "C" void kernel_launch(void* const* d_in, const int* in_sizes, int n_in,
                              void* d_out, int out_size, void* d_ws,
                              size_t ws_size, hipStream_t stream) {
  const float* nodes0 = (const float*)d_in[0];
  const float* edges0 = (const float*)d_in[1];
  const int* senders = (const int*)d_in[2];
  const int* receivers = (const int*)d_in[3];
  const float* enc_w1 = (const float*)d_in[4];
  const float* enc_b1 = (const float*)d_in[5];
  const float* enc_w2 = (const float*)d_in[6];
  const float* enc_b2 = (const float*)d_in[7];
  const float* node_w1 = (const float*)d_in[8];
  const float* node_b1 = (const float*)d_in[9];
  const float* node_w2 = (const float*)d_in[10];
  const float* node_b2 = (const float*)d_in[11];
  const float* edge_w1 = (const float*)d_in[12];
  const float* edge_b1 = (const float*)d_in[13];
  const float* edge_w2 = (const float*)d_in[14];
  const float* edge_b2 = (const float*)d_in[15];
  const float* dec_w1 = (const float*)d_in[16];
  const float* dec_b1 = (const float*)d_in[17];
  const float* dec_w2 = (const float*)d_in[18];
  const float* dec_b2 = (const float*)d_in[19];
  const float* alpha = (const float*)d_in[20];

  // Workspace layout: ~155 MB (< proven 167.6 MB budget; aggR buffer gone).
  char* ws = (char*)d_ws;
  unsigned short* e = (unsigned short*)ws;  // 3.2M x 32 B = 102.4 MB (sorted)
  char* p = ws + (size_t)N_EDGES * HID * 2;
  unsigned int* srecv = (unsigned int*)p;    p += (size_t)N_EDGES * 4;  // 12.8
  unsigned int* sorig = (unsigned int*)p;    p += (size_t)N_EDGES * 4;  // 12.8
  unsigned int* rlist = (unsigned int*)p;    p += (size_t)N_EDGES * 4;  // 12.8
  unsigned short* ssend16 = (unsigned short*)p; p += (size_t)N_EDGES * 2;  // 6.4
  unsigned short* svalbf = (unsigned short*)p;  p += (size_t)N_EDGES * 2;  // 6.4
  int* soff = (int*)p;                       p += (size_t)(N_NODES + 16) * 4;
  int* roff = (int*)p;                       p += (size_t)(N_NODES + 16) * 4;
  float* nbA = (float*)p;                    p += (size_t)N_NODES * 4;
  float* nbB = (float*)p;                    p += (size_t)N_NODES * 4;
  unsigned int* normbits = (unsigned int*)p; p += 64;
  int* gcnt = (int*)p;                       p += NB * 4;
  int* gcnt2 = (int*)p;                      p += NB * 4;
  int* bstart = (int*)p;                     p += (NB + 1) * 4;
  // build staging aliases e (dead until k_encode):
  unsigned int* pM = (unsigned int*)ws;
  float* pV = (float*)(ws + (size_t)NB * SCAP * 4);
  unsigned int* pO = (unsigned int*)(ws + (size_t)NB * SCAP * 8);
  unsigned int* rpA = (unsigned int*)(ws + (size_t)NB * SCAP * 12);

  const int ngrid = 12500;  // 2 nodes/wave x 4 waves/block -> 100000 nodes
  const int egrid = N_EDGES / BLK;  // 12500

  hipMemsetAsync(normbits, 0, 64 + 2 * NB * 4, stream);  // norm + gcnt + gcnt2
  k_norm<<<512, BLK, 0, stream>>>(edges0, normbits);
  k_split<<<256, 1024, 0, stream>>>(senders, receivers, edges0, gcnt, pM, pV, pO);
  k_bsort1<<<NB, 1024, 0, stream>>>(pM, pV, pO, gcnt, srecv, sorig, svalbf,
                                    soff, bstart);
  k_sfill<<<ngrid, BLK, 0, stream>>>(soff, ssend16);
  k_rsplit<<<256, 1024, 0, stream>>>(srecv, gcnt2, rpA);
  k_rsort<<<NB, 1024, 0, stream>>>(rpA, gcnt2, rlist, roff);
  k_encode<<<egrid, BLK, 0, stream>>>(svalbf, enc_w1, enc_b1, enc_w2, enc_b2,
                                      normbits, e);  // clobbers staging
  // round 1
  k_aggN<<<ngrid, BLK, 0, stream>>>(e, roff, rlist, soff, nodes0, node_w1,
                                    node_b1, node_w2, node_b2, nbA);
  k_edgeE<<<egrid, BLK, 0, stream>>>(e, srecv, ssend16, bstart, nbA, edge_w1,
                                     edge_b1, edge_w2, edge_b2);
  // round 2
  k_aggN<<<ngrid, BLK, 0, stream>>>(e, roff, rlist, soff, nbA, node_w1,
                                    node_b1, node_w2, node_b2, nbB);
  k_edgeE<<<egrid, BLK, 0, stream>>>(e, srecv, ssend16, bstart, nbB, edge_w1,
                                     edge_b1, edge_w2, edge_b2);
  // round 3
  k_aggN<<<ngrid, BLK, 0, stream>>>(e, roff, rlist, soff, nbB, node_w1,
                                    node_b1, node_w2, node_b2, nbA);
  // final: e3 = edgeMLP(e2, nbA) -> decoder -> delta; then residual add
  k_final<<<egrid, BLK, 0, stream>>>(e, srecv, ssend16, bstart, sorig, nbA,
                                     edge_w1, edge_b1, edge_w2, edge_b2,
                                     dec_w1, dec_b1, dec_w2, dec_b2, normbits,
                                     alpha, (float*)d_out);
  k_resid<<<egrid, BLK, 0, stream>>>(edges0, (float*)d_out);
}

// Round 8
// 902.068 us; speedup vs baseline: 3.2136x; 1.0178x over previous
//
#include <hip/hip_runtime.h>
#include <hip/hip_bf16.h>

#define N_NODES 100000
#define N_EDGES 3200000
#define HID 16
#define NB 256       // buckets; bucket = NPB consecutive nodes
#define NPB 391      // 256*391 = 100096 >= 100000
#define SCAP 15360   // per-bucket staging cap (mean 12500, +25 sigma)
#define RCAP 15360
#define FDEPTH 32    // LDS FIFO depth in split kernels
#define LCAP1 8704   // bsort1 LDS chunk entries (12 B) -> ~102 KB
#define LCAP2 26624  // rsort LDS chunk entries (4 B) -> 104 KB (1 chunk/bucket)

static constexpr int BLK = 256;

__device__ __forceinline__ float frelu(float x) { return fmaxf(x, 0.f); }
__device__ __forceinline__ float bflo(unsigned int u) {
  return __uint_as_float(u << 16);
}
__device__ __forceinline__ float bfhi(unsigned int u) {
  return __uint_as_float(u & 0xFFFF0000u);
}
__device__ __forceinline__ unsigned int packbf(float lo, float hi) {
  __hip_bfloat16 hl = __float2bfloat16(lo), hh = __float2bfloat16(hi);
  return ((unsigned int)(*(unsigned short*)&hh) << 16) |
         (unsigned int)(*(unsigned short*)&hl);
}

union E16 {
  float4 f4[2];
  __hip_bfloat16 h[16];
};

// ---------------------------------------------------------------------------
// K0: norm = max |edges_init|
// ---------------------------------------------------------------------------
__global__ __launch_bounds__(256) void k_norm(const float* __restrict__ edges,
                                              unsigned int* __restrict__ normbits) {
  float m = 0.f;
  for (int i = blockIdx.x * blockDim.x + threadIdx.x; i < N_EDGES;
       i += gridDim.x * blockDim.x)
    m = fmaxf(m, fabsf(edges[i]));
#pragma unroll
  for (int off = 32; off > 0; off >>= 1)
    m = fmaxf(m, __shfl_down(m, off, 64));
  __shared__ float smax[BLK / 64];
  if ((threadIdx.x & 63) == 0) smax[threadIdx.x >> 6] = m;
  __syncthreads();
  if (threadIdx.x == 0) {
    float b = smax[0];
#pragma unroll
    for (int w = 1; w < BLK / 64; ++w) b = fmaxf(b, smax[w]);
    atomicMax(normbits, __float_as_uint(b));
  }
}

// ---------------------------------------------------------------------------
// K1: bucket edges by SENDER via LDS FIFOs (line-granular flushes).
// record: m = (sender_local<<22) | orig_edge(22b), v = edges_init, o = recv
// ---------------------------------------------------------------------------
__global__ __launch_bounds__(1024) void k_split(
    const int* __restrict__ senders, const int* __restrict__ receivers,
    const float* __restrict__ edges, int* __restrict__ gcnt,
    unsigned int* __restrict__ pM, float* __restrict__ pV,
    unsigned int* __restrict__ pO) {
  __shared__ __align__(16) unsigned int fM[NB][FDEPTH];
  __shared__ __align__(16) unsigned int fV[NB][FDEPTH];
  __shared__ __align__(16) unsigned int fO[NB][FDEPTH];
  __shared__ int fcnt[NB];
  const int t = threadIdx.x;
  if (t < NB) fcnt[t] = 0;
  __syncthreads();
  const int e0 = blockIdx.x * (N_EDGES / 256);
  const int e1 = e0 + (N_EDGES / 256);
  for (int base = e0; base < e1; base += 1024) {
    const int i = base + t;
    if (i < e1) {
      int s = senders[i];
      unsigned int b = (unsigned int)s / NPB;
      unsigned int m = (((unsigned int)s - b * NPB) << 22) | (unsigned int)i;
      unsigned int v = __float_as_uint(edges[i]);
      unsigned int o = (unsigned int)receivers[i];
      int pos = atomicAdd(&fcnt[b], 1);
      if (pos < FDEPTH) {
        fM[b][pos] = m; fV[b][pos] = v; fO[b][pos] = o;
      } else {  // rare overflow: direct append
        int gb = atomicAdd(&gcnt[b], 1);
        if (gb < SCAP) {
          pM[(size_t)b * SCAP + gb] = m;
          pV[(size_t)b * SCAP + gb] = __uint_as_float(v);
          pO[(size_t)b * SCAP + gb] = o;
        }
      }
    }
    __syncthreads();
    const bool last = (base + 1024 >= e1);
    if (t < NB) {
      int c = fcnt[t]; if (c > FDEPTH) c = FDEPTH;
      int nf = last ? c : (c & ~15);
      if (nf > 0) {
        int gb = atomicAdd(&gcnt[t], nf);
        size_t db = (size_t)t * SCAP + gb;
        if ((gb & 3) == 0 && gb + nf <= SCAP) {
          int k = 0;
          for (; k + 4 <= nf; k += 4) {
            *(uint4*)(pM + db + k) = *(const uint4*)(&fM[t][k]);
            *(uint4*)((unsigned int*)pV + db + k) = *(const uint4*)(&fV[t][k]);
            *(uint4*)(pO + db + k) = *(const uint4*)(&fO[t][k]);
          }
          for (; k < nf; ++k) {
            pM[db + k] = fM[t][k]; pV[db + k] = __uint_as_float(fV[t][k]);
            pO[db + k] = fO[t][k];
          }
        } else {
          for (int k = 0; k < nf; ++k)
            if (gb + k < SCAP) {
              pM[db + k] = fM[t][k]; pV[db + k] = __uint_as_float(fV[t][k]);
              pO[db + k] = fO[t][k];
            }
        }
        int res = c - nf;
        for (int k = 0; k < res; ++k) {
          fM[t][k] = fM[t][nf + k]; fV[t][k] = fV[t][nf + k];
          fO[t][k] = fO[t][nf + k];
        }
        fcnt[t] = res;
      } else fcnt[t] = c;
    }
    __syncthreads();
  }
}

// ---------------------------------------------------------------------------
// K2: per-bucket counting sort by sender_local -> EXACT global sender CSR.
// Writes srecv/sorig/svalbf/ssend32 (global sender id; k_sfill deleted) + soff.
// ---------------------------------------------------------------------------
__global__ __launch_bounds__(1024) void k_bsort1(
    const unsigned int* __restrict__ pM, const float* __restrict__ pV,
    const unsigned int* __restrict__ pO, const int* __restrict__ gcnt,
    unsigned int* __restrict__ srecv, unsigned int* __restrict__ sorig,
    unsigned short* __restrict__ svalbf, unsigned int* __restrict__ ssend32,
    int* __restrict__ soff) {
  __shared__ unsigned int sM[LCAP1];
  __shared__ float sV[LCAP1];
  __shared__ unsigned int sO[LCAP1];
  __shared__ int hist[NPB], pref[NPB + 1], sc[NPB], cur[NPB];
  __shared__ int bb[NB];
  __shared__ int base_s;
  const int b = blockIdx.x, t = threadIdx.x, nt = blockDim.x;
  if (t < NB) { int c = gcnt[t]; bb[t] = c > SCAP ? SCAP : c; }
  for (int k = t; k < NPB; k += nt) hist[k] = 0;
  __syncthreads();
  if (t == 0) { int s = 0; for (int k = 0; k < b; ++k) s += bb[k]; base_s = s; }
  int nb = gcnt[b]; if (nb > SCAP) nb = SCAP;
  const unsigned int* PM = pM + (size_t)b * SCAP;
  const float* PV = pV + (size_t)b * SCAP;
  const unsigned int* PO = pO + (size_t)b * SCAP;
  for (int i = t; i < nb; i += nt) atomicAdd(&hist[PM[i] >> 22], 1);
  __syncthreads();
  if (t < NPB) sc[t] = hist[t];
  __syncthreads();
  for (int d = 1; d < NPB; d <<= 1) {
    int add = 0;
    if (t < NPB && t >= d) add = sc[t - d];
    __syncthreads();
    if (t < NPB && t >= d) sc[t] += add;
    __syncthreads();
  }
  if (t < NPB) pref[t] = sc[t] - hist[t];
  if (t == 0) pref[NPB] = sc[NPB - 1];
  __syncthreads();
  const int base = base_s;
  const int node0 = b * NPB;
  for (int k = t; k < NPB; k += nt) {
    int n = node0 + k;
    if (n < N_NODES) soff[n] = base + pref[k];
  }
  if (b == NB - 1 && t == 0) soff[N_NODES] = base + nb;
  __syncthreads();
  int klo = 0;
  while (klo < NPB) {
    int base0 = pref[klo];
    int khi = klo;
    while (khi < NPB && pref[khi + 1] - base0 <= LCAP1) ++khi;
    if (khi == klo) khi = klo + 1;  // safety
    for (int k = klo + t; k < khi; k += nt) cur[k] = pref[k];
    __syncthreads();
    for (int i = t; i < nb; i += nt) {
      unsigned int m = PM[i];
      int key = (int)(m >> 22);
      if (key >= klo && key < khi) {
        int p = atomicAdd(&cur[key], 1) - base0;
        if (p < LCAP1) { sM[p] = m; sV[p] = PV[i]; sO[p] = PO[i]; }
      }
    }
    __syncthreads();
    int csz = pref[khi] - base0;
    for (int i = t; i < csz; i += nt) {
      int g = base + base0 + i;
      unsigned int m = sM[i];
      srecv[g] = sO[i]; sorig[g] = m & 0x3FFFFFu;
      ssend32[g] = (unsigned int)(node0 + (int)(m >> 22));
      __hip_bfloat16 hb = __float2bfloat16(sV[i]);
      svalbf[g] = *(unsigned short*)&hb;
    }
    __syncthreads();
    klo = khi;
  }
}

// ---------------------------------------------------------------------------
// K3: bucket sorted edges by RECEIVER. a = (recv_local<<22) | sorted_idx
// ---------------------------------------------------------------------------
__global__ __launch_bounds__(1024) void k_rsplit(
    const unsigned int* __restrict__ srecv, int* __restrict__ gcnt2,
    unsigned int* __restrict__ rpA) {
  __shared__ __align__(16) unsigned int fA[NB][FDEPTH];
  __shared__ int fcnt[NB];
  const int t = threadIdx.x;
  if (t < NB) fcnt[t] = 0;
  __syncthreads();
  const int e0 = blockIdx.x * (N_EDGES / 256);
  const int e1 = e0 + (N_EDGES / 256);
  for (int base = e0; base < e1; base += 1024) {
    const int i = base + t;
    if (i < e1) {
      unsigned int r = srecv[i];
      unsigned int b = r / NPB;
      unsigned int a = ((r - b * NPB) << 22) | (unsigned int)i;
      int pos = atomicAdd(&fcnt[b], 1);
      if (pos < FDEPTH) {
        fA[b][pos] = a;
      } else {
        int gb = atomicAdd(&gcnt2[b], 1);
        if (gb < RCAP) rpA[(size_t)b * RCAP + gb] = a;
      }
    }
    __syncthreads();
    const bool last = (base + 1024 >= e1);
    if (t < NB) {
      int c = fcnt[t]; if (c > FDEPTH) c = FDEPTH;
      int nf = last ? c : (c & ~15);
      if (nf > 0) {
        int gb = atomicAdd(&gcnt2[t], nf);
        size_t db = (size_t)t * RCAP + gb;
        if ((gb & 3) == 0 && gb + nf <= RCAP) {
          int k = 0;
          for (; k + 4 <= nf; k += 4)
            *(uint4*)(rpA + db + k) = *(const uint4*)(&fA[t][k]);
          for (; k < nf; ++k) rpA[db + k] = fA[t][k];
        } else {
          for (int k = 0; k < nf; ++k)
            if (gb + k < RCAP) rpA[db + k] = fA[t][k];
        }
        int res = c - nf;
        for (int k = 0; k < res; ++k) fA[t][k] = fA[t][nf + k];
        fcnt[t] = res;
      } else fcnt[t] = c;
    }
    __syncthreads();
  }
}

// ---------------------------------------------------------------------------
// K4: per-bucket counting sort by recv_local -> receiver CSR (roff) + rlist.
// ---------------------------------------------------------------------------
__global__ __launch_bounds__(1024) void k_rsort(
    const unsigned int* __restrict__ rpA, const int* __restrict__ gcnt2,
    unsigned int* __restrict__ rlist, int* __restrict__ roff) {
  __shared__ unsigned int sA[LCAP2];
  __shared__ int hist[NPB], pref[NPB + 1], sc[NPB], cur[NPB];
  __shared__ int bb[NB];
  __shared__ int base_s;
  const int b = blockIdx.x, t = threadIdx.x, nt = blockDim.x;
  if (t < NB) { int c = gcnt2[t]; bb[t] = c > RCAP ? RCAP : c; }
  for (int k = t; k < NPB; k += nt) hist[k] = 0;
  __syncthreads();
  if (t == 0) { int s = 0; for (int k = 0; k < b; ++k) s += bb[k]; base_s = s; }
  int nb = gcnt2[b]; if (nb > RCAP) nb = RCAP;
  const unsigned int* PA = rpA + (size_t)b * RCAP;
  for (int i = t; i < nb; i += nt) atomicAdd(&hist[PA[i] >> 22], 1);
  __syncthreads();
  if (t < NPB) sc[t] = hist[t];
  __syncthreads();
  for (int d = 1; d < NPB; d <<= 1) {
    int add = 0;
    if (t < NPB && t >= d) add = sc[t - d];
    __syncthreads();
    if (t < NPB && t >= d) sc[t] += add;
    __syncthreads();
  }
  if (t < NPB) pref[t] = sc[t] - hist[t];
  if (t == 0) pref[NPB] = sc[NPB - 1];
  __syncthreads();
  const int base = base_s;
  const int node0 = b * NPB;
  for (int k = t; k < NPB; k += nt) {
    int n = node0 + k;
    if (n < N_NODES) roff[n] = base + pref[k];
  }
  if (b == NB - 1 && t == 0) roff[N_NODES] = base + nb;
  __syncthreads();
  int klo = 0;
  while (klo < NPB) {
    int base0 = pref[klo];
    int khi = klo;
    while (khi < NPB && pref[khi + 1] - base0 <= LCAP2) ++khi;
    if (khi == klo) khi = klo + 1;
    for (int k = klo + t; k < khi; k += nt) cur[k] = pref[k];
    __syncthreads();
    for (int i = t; i < nb; i += nt) {
      unsigned int a = PA[i];
      int key = (int)(a >> 22);
      if (key >= klo && key < khi) {
        int p = atomicAdd(&cur[key], 1) - base0;
        if (p < LCAP2) sA[p] = a;
      }
    }
    __syncthreads();
    int csz = pref[khi] - base0;
    for (int i = t; i < csz; i += nt)
      rlist[base + base0 + i] = sA[i] & 0x3FFFFFu;
    __syncthreads();
    klo = khi;
  }
}

// ---------------------------------------------------------------------------
// K5: edge encoder (1 -> HID -> HID) in sorted order, coalesced.
// ---------------------------------------------------------------------------
__global__ __launch_bounds__(256) void k_encode(
    const unsigned short* __restrict__ svalbf, const float* __restrict__ w1,
    const float* __restrict__ b1, const float* __restrict__ w2,
    const float* __restrict__ b2, const unsigned int* __restrict__ normbits,
    unsigned short* __restrict__ e) {
  int i = blockIdx.x * blockDim.x + threadIdx.x;
  float norm = __uint_as_float(*normbits);
  float x = bflo((unsigned int)svalbf[i]) / norm;
  float h[HID];
#pragma unroll
  for (int j = 0; j < HID; ++j) h[j] = frelu(fmaf(w1[j], x, b1[j]));
  E16 o;
#pragma unroll
  for (int j = 0; j < HID; ++j) {
    float acc = b2[j];
#pragma unroll
    for (int k = 0; k < HID; ++k) acc = fmaf(w2[j * HID + k], h[k], acc);
    o.h[j] = __float2bfloat16(acc);
  }
  float4* ep = (float4*)(e + (size_t)i * HID);
  ep[0] = o.f4[0];
  ep[1] = o.f4[1];
}

// ---------------------------------------------------------------------------
// K6: FUSED receiver-gather + sender-stream + node MLP. Full chunks run
// UNMASKED (round-7 had a cndmask per element); only the tail chunk is
// predicated, mask-as-FMA (round-1 trick).
// ---------------------------------------------------------------------------
__global__ __launch_bounds__(256) void k_aggN(
    const unsigned short* __restrict__ e, const int* __restrict__ roff,
    const unsigned int* __restrict__ rlist, const int* __restrict__ soff,
    const float* __restrict__ nodesr, const float* __restrict__ nw1,
    const float* __restrict__ nb1_, const float* __restrict__ nw2,
    const float* __restrict__ nb2_, float* __restrict__ nodesw) {
  int wave = (blockIdx.x * blockDim.x + threadIdx.x) >> 6;
  int lane = threadIdx.x & 63, half = lane >> 5, l32 = lane & 31;
  int n = wave * 2 + half;
  // ---- phase A: receiver-side scattered gather ----
  int sub = l32 & 1, j16 = l32 >> 1;
  int r0 = roff[n], rdeg = roff[n + 1] - r0;
  float ar[8] = {0, 0, 0, 0, 0, 0, 0, 0};
  int fullA = rdeg & ~15;
  int q0 = 0;
  for (; q0 < fullA; q0 += 16) {
    int idx = r0 + q0 + j16;
    unsigned int si = rlist[idx];
    uint4 raw = *(const uint4*)(e + (size_t)si * HID + sub * 8);
    ar[0] += bflo(raw.x); ar[1] += bfhi(raw.x);
    ar[2] += bflo(raw.y); ar[3] += bfhi(raw.y);
    ar[4] += bflo(raw.z); ar[5] += bfhi(raw.z);
    ar[6] += bflo(raw.w); ar[7] += bfhi(raw.w);
  }
  if (q0 < rdeg) {
    int slot = q0 + j16;
    bool ok = slot < rdeg;
    int idx = r0 + (ok ? slot : 0);
    unsigned int si = rlist[idx];
    uint4 raw = *(const uint4*)(e + (size_t)si * HID + sub * 8);
    float okf = ok ? 1.f : 0.f;
    ar[0] = fmaf(bflo(raw.x), okf, ar[0]); ar[1] = fmaf(bfhi(raw.x), okf, ar[1]);
    ar[2] = fmaf(bflo(raw.y), okf, ar[2]); ar[3] = fmaf(bfhi(raw.y), okf, ar[3]);
    ar[4] = fmaf(bflo(raw.z), okf, ar[4]); ar[5] = fmaf(bfhi(raw.z), okf, ar[5]);
    ar[6] = fmaf(bflo(raw.w), okf, ar[6]); ar[7] = fmaf(bfhi(raw.w), okf, ar[7]);
  }
#pragma unroll
  for (int off = 16; off >= 2; off >>= 1)
#pragma unroll
    for (int c = 0; c < 8; ++c) ar[c] += __shfl_down(ar[c], off, 64);
  // ---- phase B: sender-side coalesced stream ----
  int s0 = soff[n], sdeg = soff[n + 1] - s0;
  float as[16];
#pragma unroll
  for (int c = 0; c < 16; ++c) as[c] = 0.f;
  int fullB = sdeg & ~31;
  int c0 = 0;
  for (; c0 < fullB; c0 += 32) {
    int idx = s0 + c0 + l32;
    uint4 ra = *(const uint4*)(e + (size_t)idx * HID);
    uint4 rb = *(const uint4*)(e + (size_t)idx * HID + 8);
    as[0] += bflo(ra.x);  as[1] += bfhi(ra.x);
    as[2] += bflo(ra.y);  as[3] += bfhi(ra.y);
    as[4] += bflo(ra.z);  as[5] += bfhi(ra.z);
    as[6] += bflo(ra.w);  as[7] += bfhi(ra.w);
    as[8] += bflo(rb.x);  as[9] += bfhi(rb.x);
    as[10] += bflo(rb.y); as[11] += bfhi(rb.y);
    as[12] += bflo(rb.z); as[13] += bfhi(rb.z);
    as[14] += bflo(rb.w); as[15] += bfhi(rb.w);
  }
  if (c0 < sdeg) {
    int k = c0 + l32;
    bool ok = k < sdeg;
    int idx = s0 + (ok ? k : 0);
    uint4 ra = *(const uint4*)(e + (size_t)idx * HID);
    uint4 rb = *(const uint4*)(e + (size_t)idx * HID + 8);
    float okf = ok ? 1.f : 0.f;
    as[0] = fmaf(bflo(ra.x), okf, as[0]);  as[1] = fmaf(bfhi(ra.x), okf, as[1]);
    as[2] = fmaf(bflo(ra.y), okf, as[2]);  as[3] = fmaf(bfhi(ra.y), okf, as[3]);
    as[4] = fmaf(bflo(ra.z), okf, as[4]);  as[5] = fmaf(bfhi(ra.z), okf, as[5]);
    as[6] = fmaf(bflo(ra.w), okf, as[6]);  as[7] = fmaf(bfhi(ra.w), okf, as[7]);
    as[8] = fmaf(bflo(rb.x), okf, as[8]);  as[9] = fmaf(bfhi(rb.x), okf, as[9]);
    as[10] = fmaf(bflo(rb.y), okf, as[10]); as[11] = fmaf(bfhi(rb.y), okf, as[11]);
    as[12] = fmaf(bflo(rb.z), okf, as[12]); as[13] = fmaf(bfhi(rb.z), okf, as[13]);
    as[14] = fmaf(bflo(rb.w), okf, as[14]); as[15] = fmaf(bfhi(rb.w), okf, as[15]);
  }
#pragma unroll
  for (int off = 16; off >= 1; off >>= 1)
#pragma unroll
    for (int c = 0; c < 16; ++c) as[c] += __shfl_down(as[c], off, 64);
  // ---- node MLP on lanes l32<16 ----
  float aS[16], aR[16];
#pragma unroll
  for (int c = 0; c < 16; ++c) aS[c] = __shfl(as[c], half * 32, 64);
#pragma unroll
  for (int k = 0; k < 8; ++k) aR[k] = __shfl(ar[k], half * 32, 64);
#pragma unroll
  for (int k = 0; k < 8; ++k) aR[8 + k] = __shfl(ar[k], half * 32 + 1, 64);
  float nsv = nodesr[n];
  float pv = 0.f;
  if (l32 < 16) {
    int j = l32;
    float a1 = fmaf(nw1[j * 33], nsv, nb1_[j]);
#pragma unroll
    for (int k = 0; k < 16; ++k) a1 = fmaf(nw1[j * 33 + 1 + k], aS[k], a1);
#pragma unroll
    for (int k = 0; k < 16; ++k) a1 = fmaf(nw1[j * 33 + 17 + k], aR[k], a1);
    pv = nw2[j] * frelu(a1);
  }
#pragma unroll
  for (int off = 8; off >= 1; off >>= 1) pv += __shfl_down(pv, off, 64);
  if (l32 == 0) nodesw[n] = pv + nb2_[0];
}

// ---------------------------------------------------------------------------
// K7: edge MLP, 4 EDGES PER THREAD — each weight is loaded once and applied
// to 4 edges (round-7 evidence: per-weight-use overhead is the 2.4x VALU
// inflation; this cuts weight-load:FMA ratio 4x). L2 chunked by 8 outputs
// with immediate 16 B store to bound live registers (~110 VGPR).
// ---------------------------------------------------------------------------
__global__ __launch_bounds__(256, 2) void k_edgeE(
    unsigned short* __restrict__ e, const unsigned int* __restrict__ srecv,
    const unsigned int* __restrict__ ssend32, const float* __restrict__ nodes,
    const float* __restrict__ w1, const float* __restrict__ b1,
    const float* __restrict__ w2, const float* __restrict__ b2) {
  int i0 = (blockIdx.x * blockDim.x + threadIdx.x) * 4;
  float ns[4], nr[4];
#pragma unroll
  for (int q = 0; q < 4; ++q) {
    ns[q] = nodes[ssend32[i0 + q]];
    nr[q] = nodes[srecv[i0 + q]];
  }
  unsigned int pk[4][8];
#pragma unroll
  for (int q = 0; q < 4; ++q) {
    const uint4* ep = (const uint4*)(e + (size_t)(i0 + q) * HID);
    uint4 ra = ep[0], rb = ep[1];
    pk[q][0] = ra.x; pk[q][1] = ra.y; pk[q][2] = ra.z; pk[q][3] = ra.w;
    pk[q][4] = rb.x; pk[q][5] = rb.y; pk[q][6] = rb.z; pk[q][7] = rb.w;
  }
  float h[4][16];
#pragma unroll
  for (int j = 0; j < 16; ++j) {
    float wA = w1[j * 18 + 16], wB = w1[j * 18 + 17], bb = b1[j];
#pragma unroll
    for (int q = 0; q < 4; ++q)
      h[q][j] = fmaf(wA, ns[q], fmaf(wB, nr[q], bb));
  }
#pragma unroll
  for (int kp = 0; kp < 8; ++kp) {
    float x0[4], x1[4];
#pragma unroll
    for (int q = 0; q < 4; ++q) {
      x0[q] = bflo(pk[q][kp]);
      x1[q] = bfhi(pk[q][kp]);
    }
#pragma unroll
    for (int j = 0; j < 16; ++j) {
      float wA = w1[j * 18 + 2 * kp], wB = w1[j * 18 + 2 * kp + 1];
#pragma unroll
      for (int q = 0; q < 4; ++q)
        h[q][j] = fmaf(wB, x1[q], fmaf(wA, x0[q], h[q][j]));
    }
  }
#pragma unroll
  for (int j = 0; j < 16; ++j)
#pragma unroll
    for (int q = 0; q < 4; ++q) h[q][j] = frelu(h[q][j]);
#pragma unroll
  for (int c0 = 0; c0 < 16; c0 += 8) {
    float y[4][8];
#pragma unroll
    for (int cc = 0; cc < 8; ++cc) {
      float bv = b2[c0 + cc];
#pragma unroll
      for (int q = 0; q < 4; ++q) y[q][cc] = bv;
    }
#pragma unroll
    for (int j = 0; j < 16; ++j) {
#pragma unroll
      for (int cc = 0; cc < 8; ++cc) {
        float wv = w2[(c0 + cc) * HID + j];
#pragma unroll
        for (int q = 0; q < 4; ++q) y[q][cc] = fmaf(wv, h[q][j], y[q][cc]);
      }
    }
#pragma unroll
    for (int q = 0; q < 4; ++q) {
      uint4 o = make_uint4(packbf(y[q][0], y[q][1]), packbf(y[q][2], y[q][3]),
                           packbf(y[q][4], y[q][5]), packbf(y[q][6], y[q][7]));
      *(uint4*)(e + (size_t)(i0 + q) * HID + c0) = o;
    }
  }
}

// ---------------------------------------------------------------------------
// K8: final — round-3 edge MLP + decoder, 2 EDGES PER THREAD (decoder needs
// full y[16] live; 2-wide keeps peak ~80 VGPR). Writes delta only.
// ---------------------------------------------------------------------------
__global__ __launch_bounds__(256, 2) void k_final(
    const unsigned short* __restrict__ e, const unsigned int* __restrict__ srecv,
    const unsigned int* __restrict__ ssend32, const unsigned int* __restrict__ sorig,
    const float* __restrict__ nodes, const float* __restrict__ ew1,
    const float* __restrict__ eb1, const float* __restrict__ ew2,
    const float* __restrict__ eb2, const float* __restrict__ dw1,
    const float* __restrict__ db1, const float* __restrict__ dw2,
    const float* __restrict__ db2, const unsigned int* __restrict__ normbits,
    const float* __restrict__ alpha, float* __restrict__ out) {
  int i0 = (blockIdx.x * blockDim.x + threadIdx.x) * 2;
  float ns[2], nr[2];
#pragma unroll
  for (int q = 0; q < 2; ++q) {
    ns[q] = nodes[ssend32[i0 + q]];
    nr[q] = nodes[srecv[i0 + q]];
  }
  unsigned int pk[2][8];
#pragma unroll
  for (int q = 0; q < 2; ++q) {
    const uint4* ep = (const uint4*)(e + (size_t)(i0 + q) * HID);
    uint4 ra = ep[0], rb = ep[1];
    pk[q][0] = ra.x; pk[q][1] = ra.y; pk[q][2] = ra.z; pk[q][3] = ra.w;
    pk[q][4] = rb.x; pk[q][5] = rb.y; pk[q][6] = rb.z; pk[q][7] = rb.w;
  }
  float h[2][16];
#pragma unroll
  for (int j = 0; j < 16; ++j) {
    float wA = ew1[j * 18 + 16], wB = ew1[j * 18 + 17], bb = eb1[j];
#pragma unroll
    for (int q = 0; q < 2; ++q)
      h[q][j] = fmaf(wA, ns[q], fmaf(wB, nr[q], bb));
  }
#pragma unroll
  for (int kp = 0; kp < 8; ++kp) {
    float x0[2], x1[2];
#pragma unroll
    for (int q = 0; q < 2; ++q) {
      x0[q] = bflo(pk[q][kp]);
      x1[q] = bfhi(pk[q][kp]);
    }
#pragma unroll
    for (int j = 0; j < 16; ++j) {
      float wA = ew1[j * 18 + 2 * kp], wB = ew1[j * 18 + 2 * kp + 1];
#pragma unroll
      for (int q = 0; q < 2; ++q)
        h[q][j] = fmaf(wB, x1[q], fmaf(wA, x0[q], h[q][j]));
    }
  }
#pragma unroll
  for (int j = 0; j < 16; ++j)
#pragma unroll
    for (int q = 0; q < 2; ++q) h[q][j] = frelu(h[q][j]);
  float y[2][16];
#pragma unroll
  for (int c = 0; c < 16; ++c) {
    float bv = eb2[c];
#pragma unroll
    for (int q = 0; q < 2; ++q) y[q][c] = bv;
  }
#pragma unroll
  for (int j = 0; j < 16; ++j) {
#pragma unroll
    for (int c = 0; c < 16; ++c) {
      float wv = ew2[c * HID + j];
#pragma unroll
      for (int q = 0; q < 2; ++q) y[q][c] = fmaf(wv, h[q][j], y[q][c]);
    }
  }
  float d[2] = {db2[0], db2[0]};
#pragma unroll
  for (int j = 0; j < 16; ++j) {
    float a1[2] = {db1[j], db1[j]};
#pragma unroll
    for (int k = 0; k < 16; ++k) {
      float wv = dw1[j * HID + k];
#pragma unroll
      for (int q = 0; q < 2; ++q) a1[q] = fmaf(wv, y[q][k], a1[q]);
    }
    float wd = dw2[j];
#pragma unroll
    for (int q = 0; q < 2; ++q) d[q] = fmaf(wd, frelu(a1[q]), d[q]);
  }
  float alphaN = alpha[0] * __uint_as_float(*normbits);
#pragma unroll
  for (int q = 0; q < 2; ++q) out[sorig[i0 + q]] = alphaN * d[q];
}

// ---------------------------------------------------------------------------
// K9: residual add, fully coalesced: out[i] += edges_init[i]
// ---------------------------------------------------------------------------
__global__ __launch_bounds__(256) void k_resid(const float* __restrict__ edges,
                                               float* __restrict__ out) {
  int i = blockIdx.x * blockDim.x + threadIdx.x;
  out[i] += edges[i];
}

// ---------------------------------------------------------------------------
extern "C" void kernel_launch(void* const* d_in, const int* in_sizes, int n_in,
                              void* d_out, int out_size, void* d_ws,
                              size_t ws_size, hipStream_t stream) {
  const float* nodes0 = (const float*)d_in[0];
  const float* edges0 = (const float*)d_in[1];
  const int* senders = (const int*)d_in[2];
  const int* receivers = (const int*)d_in[3];
  const float* enc_w1 = (const float*)d_in[4];
  const float* enc_b1 = (const float*)d_in[5];
  const float* enc_w2 = (const float*)d_in[6];
  const float* enc_b2 = (const float*)d_in[7];
  const float* node_w1 = (const float*)d_in[8];
  const float* node_b1 = (const float*)d_in[9];
  const float* node_w2 = (const float*)d_in[10];
  const float* node_b2 = (const float*)d_in[11];
  const float* edge_w1 = (const float*)d_in[12];
  const float* edge_b1 = (const float*)d_in[13];
  const float* edge_w2 = (const float*)d_in[14];
  const float* edge_b2 = (const float*)d_in[15];
  const float* dec_w1 = (const float*)d_in[16];
  const float* dec_b1 = (const float*)d_in[17];
  const float* dec_w2 = (const float*)d_in[18];
  const float* dec_b2 = (const float*)d_in[19];
  const float* alpha = (const float*)d_in[20];

  // Workspace layout: ~162 MB (< proven 167.6 MB budget).
  char* ws = (char*)d_ws;
  unsigned short* e = (unsigned short*)ws;  // 3.2M x 32 B = 102.4 MB (sorted)
  char* p = ws + (size_t)N_EDGES * HID * 2;
  unsigned int* srecv = (unsigned int*)p;    p += (size_t)N_EDGES * 4;  // 12.8
  unsigned int* sorig = (unsigned int*)p;    p += (size_t)N_EDGES * 4;  // 12.8
  unsigned int* rlist = (unsigned int*)p;    p += (size_t)N_EDGES * 4;  // 12.8
  unsigned int* ssend32 = (unsigned int*)p;  p += (size_t)N_EDGES * 4;  // 12.8
  unsigned short* svalbf = (unsigned short*)p; p += (size_t)N_EDGES * 2;  // 6.4
  int* soff = (int*)p;                       p += (size_t)(N_NODES + 16) * 4;
  int* roff = (int*)p;                       p += (size_t)(N_NODES + 16) * 4;
  float* nbA = (float*)p;                    p += (size_t)N_NODES * 4;
  float* nbB = (float*)p;                    p += (size_t)N_NODES * 4;
  unsigned int* normbits = (unsigned int*)p; p += 64;
  int* gcnt = (int*)p;                       p += NB * 4;
  int* gcnt2 = (int*)p;                      p += NB * 4;
  // build staging aliases e (dead until k_encode):
  unsigned int* pM = (unsigned int*)ws;
  float* pV = (float*)(ws + (size_t)NB * SCAP * 4);
  unsigned int* pO = (unsigned int*)(ws + (size_t)NB * SCAP * 8);
  unsigned int* rpA = (unsigned int*)(ws + (size_t)NB * SCAP * 12);

  const int ngrid = 12500;   // 2 nodes/wave x 4 waves/block -> 100000 nodes
  const int egrid = N_EDGES / BLK;        // 12500
  const int egrid4 = N_EDGES / (BLK * 4); // 3125 (4 edges/thread)
  const int egrid2 = N_EDGES / (BLK * 2); // 6250 (2 edges/thread)

  hipMemsetAsync(normbits, 0, 64 + 2 * NB * 4, stream);  // norm + gcnt + gcnt2
  k_norm<<<512, BLK, 0, stream>>>(edges0, normbits);
  k_split<<<256, 1024, 0, stream>>>(senders, receivers, edges0, gcnt, pM, pV, pO);
  k_bsort1<<<NB, 1024, 0, stream>>>(pM, pV, pO, gcnt, srecv, sorig, svalbf,
                                    ssend32, soff);
  k_rsplit<<<256, 1024, 0, stream>>>(srecv, gcnt2, rpA);
  k_rsort<<<NB, 1024, 0, stream>>>(rpA, gcnt2, rlist, roff);
  k_encode<<<egrid, BLK, 0, stream>>>(svalbf, enc_w1, enc_b1, enc_w2, enc_b2,
                                      normbits, e);  // clobbers staging
  // round 1
  k_aggN<<<ngrid, BLK, 0, stream>>>(e, roff, rlist, soff, nodes0, node_w1,
                                    node_b1, node_w2, node_b2, nbA);
  k_edgeE<<<egrid4, BLK, 0, stream>>>(e, srecv, ssend32, nbA, edge_w1,
                                      edge_b1, edge_w2, edge_b2);
  // round 2
  k_aggN<<<ngrid, BLK, 0, stream>>>(e, roff, rlist, soff, nbA, node_w1,
                                    node_b1, node_w2, node_b2, nbB);
  k_edgeE<<<egrid4, BLK, 0, stream>>>(e, srecv, ssend32, nbB, edge_w1,
                                      edge_b1, edge_w2, edge_b2);
  // round 3
  k_aggN<<<ngrid, BLK, 0, stream>>>(e, roff, rlist, soff, nbB, node_w1,
                                    node_b1, node_w2, node_b2, nbA);
  // final: e3 = edgeMLP(e2, nbA) -> decoder -> delta; then residual add
  k_final<<<egrid2, BLK, 0, stream>>>(e, srecv, ssend32, sorig, nbA, edge_w1,
                                      edge_b1, edge_w2, edge_b2, dec_w1,
                                      dec_b1, dec_w2, dec_b2, normbits, alpha,
                                      (float*)d_out);
  k_resid<<<egrid, BLK, 0, stream>>>(edges0, (float*)d_out);
}

// Round 10
// 846.932 us; speedup vs baseline: 3.4228x; 1.0651x over previous
//
#include <hip/hip_runtime.h>
#include <hip/hip_bf16.h>

#define N_NODES 100000
#define N_EDGES 3200000
#define HID 16
#define NB 256       // buckets; bucket = NPB consecutive nodes
#define NPB 391      // 256*391 = 100096 >= 100000
#define SCAP 15360   // per-bucket staging cap (mean 12500, +25 sigma)
#define RCAP 15360
#define FDEPTH 32    // LDS FIFO depth in split kernels
#define LCAP1 8704   // bsort1 LDS chunk entries (12 B) -> ~102 KB
#define LCAP2 26624  // rsort LDS chunk entries (4 B) -> 104 KB (1 chunk/bucket)

static constexpr int BLK = 256;

__device__ __forceinline__ float frelu(float x) { return fmaxf(x, 0.f); }
__device__ __forceinline__ float bflo(unsigned int u) {
  return __uint_as_float(u << 16);
}
__device__ __forceinline__ float bfhi(unsigned int u) {
  return __uint_as_float(u & 0xFFFF0000u);
}
__device__ __forceinline__ unsigned int packbf(float lo, float hi) {
  __hip_bfloat16 hl = __float2bfloat16(lo), hh = __float2bfloat16(hi);
  return ((unsigned int)(*(unsigned short*)&hh) << 16) |
         (unsigned int)(*(unsigned short*)&hl);
}

union E16 {
  float4 f4[2];
  __hip_bfloat16 h[16];
};

// ---------------------------------------------------------------------------
// K0: norm = max |edges_init|
// ---------------------------------------------------------------------------
__global__ __launch_bounds__(256) void k_norm(const float* __restrict__ edges,
                                              unsigned int* __restrict__ normbits) {
  float m = 0.f;
  for (int i = blockIdx.x * blockDim.x + threadIdx.x; i < N_EDGES;
       i += gridDim.x * blockDim.x)
    m = fmaxf(m, fabsf(edges[i]));
#pragma unroll
  for (int off = 32; off > 0; off >>= 1)
    m = fmaxf(m, __shfl_down(m, off, 64));
  __shared__ float smax[BLK / 64];
  if ((threadIdx.x & 63) == 0) smax[threadIdx.x >> 6] = m;
  __syncthreads();
  if (threadIdx.x == 0) {
    float b = smax[0];
#pragma unroll
    for (int w = 1; w < BLK / 64; ++w) b = fmaxf(b, smax[w]);
    atomicMax(normbits, __float_as_uint(b));
  }
}

// ---------------------------------------------------------------------------
// K1: bucket edges by SENDER via LDS FIFOs (line-granular flushes).
// record: m = (sender_local<<22) | orig_edge(22b), v = edges_init, o = recv
// ---------------------------------------------------------------------------
__global__ __launch_bounds__(1024) void k_split(
    const int* __restrict__ senders, const int* __restrict__ receivers,
    const float* __restrict__ edges, int* __restrict__ gcnt,
    unsigned int* __restrict__ pM, float* __restrict__ pV,
    unsigned int* __restrict__ pO) {
  __shared__ __align__(16) unsigned int fM[NB][FDEPTH];
  __shared__ __align__(16) unsigned int fV[NB][FDEPTH];
  __shared__ __align__(16) unsigned int fO[NB][FDEPTH];
  __shared__ int fcnt[NB];
  const int t = threadIdx.x;
  if (t < NB) fcnt[t] = 0;
  __syncthreads();
  const int e0 = blockIdx.x * (N_EDGES / 256);
  const int e1 = e0 + (N_EDGES / 256);
  for (int base = e0; base < e1; base += 1024) {
    const int i = base + t;
    if (i < e1) {
      int s = senders[i];
      unsigned int b = (unsigned int)s / NPB;
      unsigned int m = (((unsigned int)s - b * NPB) << 22) | (unsigned int)i;
      unsigned int v = __float_as_uint(edges[i]);
      unsigned int o = (unsigned int)receivers[i];
      int pos = atomicAdd(&fcnt[b], 1);
      if (pos < FDEPTH) {
        fM[b][pos] = m; fV[b][pos] = v; fO[b][pos] = o;
      } else {  // rare overflow: direct append
        int gb = atomicAdd(&gcnt[b], 1);
        if (gb < SCAP) {
          pM[(size_t)b * SCAP + gb] = m;
          pV[(size_t)b * SCAP + gb] = __uint_as_float(v);
          pO[(size_t)b * SCAP + gb] = o;
        }
      }
    }
    __syncthreads();
    const bool last = (base + 1024 >= e1);
    if (t < NB) {
      int c = fcnt[t]; if (c > FDEPTH) c = FDEPTH;
      int nf = last ? c : (c & ~15);
      if (nf > 0) {
        int gb = atomicAdd(&gcnt[t], nf);
        size_t db = (size_t)t * SCAP + gb;
        if ((gb & 3) == 0 && gb + nf <= SCAP) {
          int k = 0;
          for (; k + 4 <= nf; k += 4) {
            *(uint4*)(pM + db + k) = *(const uint4*)(&fM[t][k]);
            *(uint4*)((unsigned int*)pV + db + k) = *(const uint4*)(&fV[t][k]);
            *(uint4*)(pO + db + k) = *(const uint4*)(&fO[t][k]);
          }
          for (; k < nf; ++k) {
            pM[db + k] = fM[t][k]; pV[db + k] = __uint_as_float(fV[t][k]);
            pO[db + k] = fO[t][k];
          }
        } else {
          for (int k = 0; k < nf; ++k)
            if (gb + k < SCAP) {
              pM[db + k] = fM[t][k]; pV[db + k] = __uint_as_float(fV[t][k]);
              pO[db + k] = fO[t][k];
            }
        }
        int res = c - nf;
        for (int k = 0; k < res; ++k) {
          fM[t][k] = fM[t][nf + k]; fV[t][k] = fV[t][nf + k];
          fO[t][k] = fO[t][nf + k];
        }
        fcnt[t] = res;
      } else fcnt[t] = c;
    }
    __syncthreads();
  }
}

// ---------------------------------------------------------------------------
// K2: per-bucket counting sort by sender_local -> EXACT global sender CSR.
// Writes srecv/sorig/svalbf/ssend32 (global sender id) + soff.
// ---------------------------------------------------------------------------
__global__ __launch_bounds__(1024) void k_bsort1(
    const unsigned int* __restrict__ pM, const float* __restrict__ pV,
    const unsigned int* __restrict__ pO, const int* __restrict__ gcnt,
    unsigned int* __restrict__ srecv, unsigned int* __restrict__ sorig,
    unsigned short* __restrict__ svalbf, unsigned int* __restrict__ ssend32,
    int* __restrict__ soff) {
  __shared__ unsigned int sM[LCAP1];
  __shared__ float sV[LCAP1];
  __shared__ unsigned int sO[LCAP1];
  __shared__ int hist[NPB], pref[NPB + 1], sc[NPB], cur[NPB];
  __shared__ int bb[NB];
  __shared__ int base_s;
  const int b = blockIdx.x, t = threadIdx.x, nt = blockDim.x;
  if (t < NB) { int c = gcnt[t]; bb[t] = c > SCAP ? SCAP : c; }
  for (int k = t; k < NPB; k += nt) hist[k] = 0;
  __syncthreads();
  if (t == 0) { int s = 0; for (int k = 0; k < b; ++k) s += bb[k]; base_s = s; }
  int nb = gcnt[b]; if (nb > SCAP) nb = SCAP;
  const unsigned int* PM = pM + (size_t)b * SCAP;
  const float* PV = pV + (size_t)b * SCAP;
  const unsigned int* PO = pO + (size_t)b * SCAP;
  for (int i = t; i < nb; i += nt) atomicAdd(&hist[PM[i] >> 22], 1);
  __syncthreads();
  if (t < NPB) sc[t] = hist[t];
  __syncthreads();
  for (int d = 1; d < NPB; d <<= 1) {
    int add = 0;
    if (t < NPB && t >= d) add = sc[t - d];
    __syncthreads();
    if (t < NPB && t >= d) sc[t] += add;
    __syncthreads();
  }
  if (t < NPB) pref[t] = sc[t] - hist[t];
  if (t == 0) pref[NPB] = sc[NPB - 1];
  __syncthreads();
  const int base = base_s;
  const int node0 = b * NPB;
  for (int k = t; k < NPB; k += nt) {
    int n = node0 + k;
    if (n < N_NODES) soff[n] = base + pref[k];
  }
  if (b == NB - 1 && t == 0) soff[N_NODES] = base + nb;
  __syncthreads();
  int klo = 0;
  while (klo < NPB) {
    int base0 = pref[klo];
    int khi = klo;
    while (khi < NPB && pref[khi + 1] - base0 <= LCAP1) ++khi;
    if (khi == klo) khi = klo + 1;  // safety
    for (int k = klo + t; k < khi; k += nt) cur[k] = pref[k];
    __syncthreads();
    for (int i = t; i < nb; i += nt) {
      unsigned int m = PM[i];
      int key = (int)(m >> 22);
      if (key >= klo && key < khi) {
        int p = atomicAdd(&cur[key], 1) - base0;
        if (p < LCAP1) { sM[p] = m; sV[p] = PV[i]; sO[p] = PO[i]; }
      }
    }
    __syncthreads();
    int csz = pref[khi] - base0;
    for (int i = t; i < csz; i += nt) {
      int g = base + base0 + i;
      unsigned int m = sM[i];
      srecv[g] = sO[i]; sorig[g] = m & 0x3FFFFFu;
      ssend32[g] = (unsigned int)(node0 + (int)(m >> 22));
      __hip_bfloat16 hb = __float2bfloat16(sV[i]);
      svalbf[g] = *(unsigned short*)&hb;
    }
    __syncthreads();
    klo = khi;
  }
}

// ---------------------------------------------------------------------------
// K3: bucket sorted edges by RECEIVER. a = (recv_local<<22) | sorted_idx
// ---------------------------------------------------------------------------
__global__ __launch_bounds__(1024) void k_rsplit(
    const unsigned int* __restrict__ srecv, int* __restrict__ gcnt2,
    unsigned int* __restrict__ rpA) {
  __shared__ __align__(16) unsigned int fA[NB][FDEPTH];
  __shared__ int fcnt[NB];
  const int t = threadIdx.x;
  if (t < NB) fcnt[t] = 0;
  __syncthreads();
  const int e0 = blockIdx.x * (N_EDGES / 256);
  const int e1 = e0 + (N_EDGES / 256);
  for (int base = e0; base < e1; base += 1024) {
    const int i = base + t;
    if (i < e1) {
      unsigned int r = srecv[i];
      unsigned int b = r / NPB;
      unsigned int a = ((r - b * NPB) << 22) | (unsigned int)i;
      int pos = atomicAdd(&fcnt[b], 1);
      if (pos < FDEPTH) {
        fA[b][pos] = a;
      } else {
        int gb = atomicAdd(&gcnt2[b], 1);
        if (gb < RCAP) rpA[(size_t)b * RCAP + gb] = a;
      }
    }
    __syncthreads();
    const bool last = (base + 1024 >= e1);
    if (t < NB) {
      int c = fcnt[t]; if (c > FDEPTH) c = FDEPTH;
      int nf = last ? c : (c & ~15);
      if (nf > 0) {
        int gb = atomicAdd(&gcnt2[t], nf);
        size_t db = (size_t)t * RCAP + gb;
        if ((gb & 3) == 0 && gb + nf <= RCAP) {
          int k = 0;
          for (; k + 4 <= nf; k += 4)
            *(uint4*)(rpA + db + k) = *(const uint4*)(&fA[t][k]);
          for (; k < nf; ++k) rpA[db + k] = fA[t][k];
        } else {
          for (int k = 0; k < nf; ++k)
            if (gb + k < RCAP) rpA[db + k] = fA[t][k];
        }
        int res = c - nf;
        for (int k = 0; k < res; ++k) fA[t][k] = fA[t][nf + k];
        fcnt[t] = res;
      } else fcnt[t] = c;
    }
    __syncthreads();
  }
}

// ---------------------------------------------------------------------------
// K4: per-bucket counting sort by recv_local -> receiver CSR (roff) + rlist.
// ---------------------------------------------------------------------------
__global__ __launch_bounds__(1024) void k_rsort(
    const unsigned int* __restrict__ rpA, const int* __restrict__ gcnt2,
    unsigned int* __restrict__ rlist, int* __restrict__ roff) {
  __shared__ unsigned int sA[LCAP2];
  __shared__ int hist[NPB], pref[NPB + 1], sc[NPB], cur[NPB];
  __shared__ int bb[NB];
  __shared__ int base_s;
  const int b = blockIdx.x, t = threadIdx.x, nt = blockDim.x;
  if (t < NB) { int c = gcnt2[t]; bb[t] = c > RCAP ? RCAP : c; }
  for (int k = t; k < NPB; k += nt) hist[k] = 0;
  __syncthreads();
  if (t == 0) { int s = 0; for (int k = 0; k < b; ++k) s += bb[k]; base_s = s; }
  int nb = gcnt2[b]; if (nb > RCAP) nb = RCAP;
  const unsigned int* PA = rpA + (size_t)b * RCAP;
  for (int i = t; i < nb; i += nt) atomicAdd(&hist[PA[i] >> 22], 1);
  __syncthreads();
  if (t < NPB) sc[t] = hist[t];
  __syncthreads();
  for (int d = 1; d < NPB; d <<= 1) {
    int add = 0;
    if (t < NPB && t >= d) add = sc[t - d];
    __syncthreads();
    if (t < NPB && t >= d) sc[t] += add;
    __syncthreads();
  }
  if (t < NPB) pref[t] = sc[t] - hist[t];
  if (t == 0) pref[NPB] = sc[NPB - 1];
  __syncthreads();
  const int base = base_s;
  const int node0 = b * NPB;
  for (int k = t; k < NPB; k += nt) {
    int n = node0 + k;
    if (n < N_NODES) roff[n] = base + pref[k];
  }
  if (b == NB - 1 && t == 0) roff[N_NODES] = base + nb;
  __syncthreads();
  int klo = 0;
  while (klo < NPB) {
    int base0 = pref[klo];
    int khi = klo;
    while (khi < NPB && pref[khi + 1] - base0 <= LCAP2) ++khi;
    if (khi == klo) khi = klo + 1;
    for (int k = klo + t; k < khi; k += nt) cur[k] = pref[k];
    __syncthreads();
    for (int i = t; i < nb; i += nt) {
      unsigned int a = PA[i];
      int key = (int)(a >> 22);
      if (key >= klo && key < khi) {
        int p = atomicAdd(&cur[key], 1) - base0;
        if (p < LCAP2) sA[p] = a;
      }
    }
    __syncthreads();
    int csz = pref[khi] - base0;
    for (int i = t; i < csz; i += nt)
      rlist[base + base0 + i] = sA[i] & 0x3FFFFFu;
    __syncthreads();
    klo = khi;
  }
}

// ---------------------------------------------------------------------------
// K5: edge encoder (1 -> HID -> HID) in sorted order, coalesced.
// ---------------------------------------------------------------------------
__global__ __launch_bounds__(256) void k_encode(
    const unsigned short* __restrict__ svalbf, const float* __restrict__ w1,
    const float* __restrict__ b1, const float* __restrict__ w2,
    const float* __restrict__ b2, const unsigned int* __restrict__ normbits,
    unsigned short* __restrict__ e) {
  int i = blockIdx.x * blockDim.x + threadIdx.x;
  float norm = __uint_as_float(*normbits);
  float x = bflo((unsigned int)svalbf[i]) / norm;
  float h[HID];
#pragma unroll
  for (int j = 0; j < HID; ++j) h[j] = frelu(fmaf(w1[j], x, b1[j]));
  E16 o;
#pragma unroll
  for (int j = 0; j < HID; ++j) {
    float acc = b2[j];
#pragma unroll
    for (int k = 0; k < HID; ++k) acc = fmaf(w2[j * HID + k], h[k], acc);
    o.h[j] = __float2bfloat16(acc);
  }
  float4* ep = (float4*)(e + (size_t)i * HID);
  ep[0] = o.f4[0];
  ep[1] = o.f4[1];
}

// ---------------------------------------------------------------------------
// K6: FUSED receiver-gather + sender-stream + node MLP. Full chunks run
// UNMASKED; only the tail chunk is predicated, mask-as-FMA.
// ---------------------------------------------------------------------------
__global__ __launch_bounds__(256) void k_aggN(
    const unsigned short* __restrict__ e, const int* __restrict__ roff,
    const unsigned int* __restrict__ rlist, const int* __restrict__ soff,
    const float* __restrict__ nodesr, const float* __restrict__ nw1,
    const float* __restrict__ nb1_, const float* __restrict__ nw2,
    const float* __restrict__ nb2_, float* __restrict__ nodesw) {
  int wave = (blockIdx.x * blockDim.x + threadIdx.x) >> 6;
  int lane = threadIdx.x & 63, half = lane >> 5, l32 = lane & 31;
  int n = wave * 2 + half;
  // ---- phase A: receiver-side scattered gather ----
  int sub = l32 & 1, j16 = l32 >> 1;
  int r0 = roff[n], rdeg = roff[n + 1] - r0;
  float ar[8] = {0, 0, 0, 0, 0, 0, 0, 0};
  int fullA = rdeg & ~15;
  int q0 = 0;
  for (; q0 < fullA; q0 += 16) {
    int idx = r0 + q0 + j16;
    unsigned int si = rlist[idx];
    uint4 raw = *(const uint4*)(e + (size_t)si * HID + sub * 8);
    ar[0] += bflo(raw.x); ar[1] += bfhi(raw.x);
    ar[2] += bflo(raw.y); ar[3] += bfhi(raw.y);
    ar[4] += bflo(raw.z); ar[5] += bfhi(raw.z);
    ar[6] += bflo(raw.w); ar[7] += bfhi(raw.w);
  }
  if (q0 < rdeg) {
    int slot = q0 + j16;
    bool ok = slot < rdeg;
    int idx = r0 + (ok ? slot : 0);
    unsigned int si = rlist[idx];
    uint4 raw = *(const uint4*)(e + (size_t)si * HID + sub * 8);
    float okf = ok ? 1.f : 0.f;
    ar[0] = fmaf(bflo(raw.x), okf, ar[0]); ar[1] = fmaf(bfhi(raw.x), okf, ar[1]);
    ar[2] = fmaf(bflo(raw.y), okf, ar[2]); ar[3] = fmaf(bfhi(raw.y), okf, ar[3]);
    ar[4] = fmaf(bflo(raw.z), okf, ar[4]); ar[5] = fmaf(bfhi(raw.z), okf, ar[5]);
    ar[6] = fmaf(bflo(raw.w), okf, ar[6]); ar[7] = fmaf(bfhi(raw.w), okf, ar[7]);
  }
#pragma unroll
  for (int off = 16; off >= 2; off >>= 1)
#pragma unroll
    for (int c = 0; c < 8; ++c) ar[c] += __shfl_down(ar[c], off, 64);
  // ---- phase B: sender-side coalesced stream ----
  int s0 = soff[n], sdeg = soff[n + 1] - s0;
  float as[16];
#pragma unroll
  for (int c = 0; c < 16; ++c) as[c] = 0.f;
  int fullB = sdeg & ~31;
  int c0 = 0;
  for (; c0 < fullB; c0 += 32) {
    int idx = s0 + c0 + l32;
    uint4 ra = *(const uint4*)(e + (size_t)idx * HID);
    uint4 rb = *(const uint4*)(e + (size_t)idx * HID + 8);
    as[0] += bflo(ra.x);  as[1] += bfhi(ra.x);
    as[2] += bflo(ra.y);  as[3] += bfhi(ra.y);
    as[4] += bflo(ra.z);  as[5] += bfhi(ra.z);
    as[6] += bflo(ra.w);  as[7] += bfhi(ra.w);
    as[8] += bflo(rb.x);  as[9] += bfhi(rb.x);
    as[10] += bflo(rb.y); as[11] += bfhi(rb.y);
    as[12] += bflo(rb.z); as[13] += bfhi(rb.z);
    as[14] += bflo(rb.w); as[15] += bfhi(rb.w);
  }
  if (c0 < sdeg) {
    int k = c0 + l32;
    bool ok = k < sdeg;
    int idx = s0 + (ok ? k : 0);
    uint4 ra = *(const uint4*)(e + (size_t)idx * HID);
    uint4 rb = *(const uint4*)(e + (size_t)idx * HID + 8);
    float okf = ok ? 1.f : 0.f;
    as[0] = fmaf(bflo(ra.x), okf, as[0]);  as[1] = fmaf(bfhi(ra.x), okf, as[1]);
    as[2] = fmaf(bflo(ra.y), okf, as[2]);  as[3] = fmaf(bfhi(ra.y), okf, as[3]);
    as[4] = fmaf(bflo(ra.z), okf, as[4]);  as[5] = fmaf(bfhi(ra.z), okf, as[5]);
    as[6] = fmaf(bflo(ra.w), okf, as[6]);  as[7] = fmaf(bfhi(ra.w), okf, as[7]);
    as[8] = fmaf(bflo(rb.x), okf, as[8]);  as[9] = fmaf(bfhi(rb.x), okf, as[9]);
    as[10] = fmaf(bflo(rb.y), okf, as[10]); as[11] = fmaf(bfhi(rb.y), okf, as[11]);
    as[12] = fmaf(bflo(rb.z), okf, as[12]); as[13] = fmaf(bfhi(rb.z), okf, as[13]);
    as[14] = fmaf(bflo(rb.w), okf, as[14]); as[15] = fmaf(bfhi(rb.w), okf, as[15]);
  }
#pragma unroll
  for (int off = 16; off >= 1; off >>= 1)
#pragma unroll
    for (int c = 0; c < 16; ++c) as[c] += __shfl_down(as[c], off, 64);
  // ---- node MLP on lanes l32<16 ----
  float aS[16], aR[16];
#pragma unroll
  for (int c = 0; c < 16; ++c) aS[c] = __shfl(as[c], half * 32, 64);
#pragma unroll
  for (int k = 0; k < 8; ++k) aR[k] = __shfl(ar[k], half * 32, 64);
#pragma unroll
  for (int k = 0; k < 8; ++k) aR[8 + k] = __shfl(ar[k], half * 32 + 1, 64);
  float nsv = nodesr[n];
  float pv = 0.f;
  if (l32 < 16) {
    int j = l32;
    float a1 = fmaf(nw1[j * 33], nsv, nb1_[j]);
#pragma unroll
    for (int k = 0; k < 16; ++k) a1 = fmaf(nw1[j * 33 + 1 + k], aS[k], a1);
#pragma unroll
    for (int k = 0; k < 16; ++k) a1 = fmaf(nw1[j * 33 + 17 + k], aR[k], a1);
    pv = nw2[j] * frelu(a1);
  }
#pragma unroll
  for (int off = 8; off >= 1; off >>= 1) pv += __shfl_down(pv, off, 64);
  if (l32 == 0) nodesw[n] = pv + nb2_[0];
}

// ---------------------------------------------------------------------------
// K7: edge MLP, 2 EDGES PER THREAD (round-8 A/B: 4-edge collapsed occupancy
// to 19% at VGPR=88 — live set 130 > alloc; 2-edge's ~70-reg live set fits).
// Layer-2 chunked by 8 outputs with immediate 16 B stores bounds live regs
// at h[2][16]+y[2][8]=48. (256,4): 128-VGPR cap, >=4 waves/SIMD.
// ---------------------------------------------------------------------------
__global__ __launch_bounds__(256, 4) void k_edgeE(
    unsigned short* __restrict__ e, const unsigned int* __restrict__ srecv,
    const unsigned int* __restrict__ ssend32, const float* __restrict__ nodes,
    const float* __restrict__ w1, const float* __restrict__ b1,
    const float* __restrict__ w2, const float* __restrict__ b2) {
  int i0 = (blockIdx.x * blockDim.x + threadIdx.x) * 2;
  float ns[2], nr[2];
#pragma unroll
  for (int q = 0; q < 2; ++q) {
    ns[q] = nodes[ssend32[i0 + q]];
    nr[q] = nodes[srecv[i0 + q]];
  }
  unsigned int pk[2][8];
#pragma unroll
  for (int q = 0; q < 2; ++q) {
    const uint4* ep = (const uint4*)(e + (size_t)(i0 + q) * HID);
    uint4 ra = ep[0], rb = ep[1];
    pk[q][0] = ra.x; pk[q][1] = ra.y; pk[q][2] = ra.z; pk[q][3] = ra.w;
    pk[q][4] = rb.x; pk[q][5] = rb.y; pk[q][6] = rb.z; pk[q][7] = rb.w;
  }
  float h[2][16];
#pragma unroll
  for (int j = 0; j < 16; ++j) {
    float wA = w1[j * 18 + 16], wB = w1[j * 18 + 17], bb = b1[j];
#pragma unroll
    for (int q = 0; q < 2; ++q)
      h[q][j] = fmaf(wA, ns[q], fmaf(wB, nr[q], bb));
  }
#pragma unroll
  for (int kp = 0; kp < 8; ++kp) {
    float x0[2], x1[2];
#pragma unroll
    for (int q = 0; q < 2; ++q) {
      x0[q] = bflo(pk[q][kp]);
      x1[q] = bfhi(pk[q][kp]);
    }
#pragma unroll
    for (int j = 0; j < 16; ++j) {
      float wA = w1[j * 18 + 2 * kp], wB = w1[j * 18 + 2 * kp + 1];
#pragma unroll
      for (int q = 0; q < 2; ++q)
        h[q][j] = fmaf(wB, x1[q], fmaf(wA, x0[q], h[q][j]));
    }
  }
#pragma unroll
  for (int j = 0; j < 16; ++j)
#pragma unroll
    for (int q = 0; q < 2; ++q) h[q][j] = frelu(h[q][j]);
#pragma unroll
  for (int c0 = 0; c0 < 16; c0 += 8) {
    float y[2][8];
#pragma unroll
    for (int cc = 0; cc < 8; ++cc) {
      float bv = b2[c0 + cc];
#pragma unroll
      for (int q = 0; q < 2; ++q) y[q][cc] = bv;
    }
#pragma unroll
    for (int j = 0; j < 16; ++j) {
#pragma unroll
      for (int cc = 0; cc < 8; ++cc) {
        float wv = w2[(c0 + cc) * HID + j];
#pragma unroll
        for (int q = 0; q < 2; ++q) y[q][cc] = fmaf(wv, h[q][j], y[q][cc]);
      }
    }
#pragma unroll
    for (int q = 0; q < 2; ++q) {
      uint4 o = make_uint4(packbf(y[q][0], y[q][1]), packbf(y[q][2], y[q][3]),
                           packbf(y[q][4], y[q][5]), packbf(y[q][6], y[q][7]));
      *(uint4*)(e + (size_t)(i0 + q) * HID + c0) = o;
    }
  }
}

// ---------------------------------------------------------------------------
// K8: final — round-3 edge MLP + decoder, 2 EDGES PER THREAD. (256,4):
// peak live ~100 < 128 cap, no spills, >=4 waves/SIMD. Writes delta only.
// ---------------------------------------------------------------------------
__global__ __launch_bounds__(256, 4) void k_final(
    const unsigned short* __restrict__ e, const unsigned int* __restrict__ srecv,
    const unsigned int* __restrict__ ssend32, const unsigned int* __restrict__ sorig,
    const float* __restrict__ nodes, const float* __restrict__ ew1,
    const float* __restrict__ eb1, const float* __restrict__ ew2,
    const float* __restrict__ eb2, const float* __restrict__ dw1,
    const float* __restrict__ db1, const float* __restrict__ dw2,
    const float* __restrict__ db2, const unsigned int* __restrict__ normbits,
    const float* __restrict__ alpha, float* __restrict__ out) {
  int i0 = (blockIdx.x * blockDim.x + threadIdx.x) * 2;
  float ns[2], nr[2];
#pragma unroll
  for (int q = 0; q < 2; ++q) {
    ns[q] = nodes[ssend32[i0 + q]];
    nr[q] = nodes[srecv[i0 + q]];
  }
  unsigned int pk[2][8];
#pragma unroll
  for (int q = 0; q < 2; ++q) {
    const uint4* ep = (const uint4*)(e + (size_t)(i0 + q) * HID);
    uint4 ra = ep[0], rb = ep[1];
    pk[q][0] = ra.x; pk[q][1] = ra.y; pk[q][2] = ra.z; pk[q][3] = ra.w;
    pk[q][4] = rb.x; pk[q][5] = rb.y; pk[q][6] = rb.z; pk[q][7] = rb.w;
  }
  float h[2][16];
#pragma unroll
  for (int j = 0; j < 16; ++j) {
    float wA = ew1[j * 18 + 16], wB = ew1[j * 18 + 17], bb = eb1[j];
#pragma unroll
    for (int q = 0; q < 2; ++q)
      h[q][j] = fmaf(wA, ns[q], fmaf(wB, nr[q], bb));
  }
#pragma unroll
  for (int kp = 0; kp < 8; ++kp) {
    float x0[2], x1[2];
#pragma unroll
    for (int q = 0; q < 2; ++q) {
      x0[q] = bflo(pk[q][kp]);
      x1[q] = bfhi(pk[q][kp]);
    }
#pragma unroll
    for (int j = 0; j < 16; ++j) {
      float wA = ew1[j * 18 + 2 * kp], wB = ew1[j * 18 + 2 * kp + 1];
#pragma unroll
      for (int q = 0; q < 2; ++q)
        h[q][j] = fmaf(wB, x1[q], fmaf(wA, x0[q], h[q][j]));
    }
  }
#pragma unroll
  for (int j = 0; j < 16; ++j)
#pragma unroll
    for (int q = 0; q < 2; ++q) h[q][j] = frelu(h[q][j]);
  float y[2][16];
#pragma unroll
  for (int c = 0; c < 16; ++c) {
    float bv = eb2[c];
#pragma unroll
    for (int q = 0; q < 2; ++q) y[q][c] = bv;
  }
#pragma unroll
  for (int j = 0; j < 16; ++j) {
#pragma unroll
    for (int c = 0; c < 16; ++c) {
      float wv = ew2[c * HID + j];
#pragma unroll
      for (int q = 0; q < 2; ++q) y[q][c] = fmaf(wv, h[q][j], y[q][c]);
    }
  }
  float d[2] = {db2[0], db2[0]};
#pragma unroll
  for (int j = 0; j < 16; ++j) {
    float a1[2] = {db1[j], db1[j]};
#pragma unroll
    for (int k = 0; k < 16; ++k) {
      float wv = dw1[j * HID + k];
#pragma unroll
      for (int q = 0; q < 2; ++q) a1[q] = fmaf(wv, y[q][k], a1[q]);
    }
    float wd = dw2[j];
#pragma unroll
    for (int q = 0; q < 2; ++q) d[q] = fmaf(wd, frelu(a1[q]), d[q]);
  }
  float alphaN = alpha[0] * __uint_as_float(*normbits);
#pragma unroll
  for (int q = 0; q < 2; ++q) out[sorig[i0 + q]] = alphaN * d[q];
}

// ---------------------------------------------------------------------------
// K9: residual add, fully coalesced: out[i] += edges_init[i]
// ---------------------------------------------------------------------------
__global__ __launch_bounds__(256) void k_resid(const float* __restrict__ edges,
                                               float* __restrict__ out) {
  int i = blockIdx.x * blockDim.x + threadIdx.x;
  out[i] += edges[i];
}

// ---------------------------------------------------------------------------
extern "C" void kernel_launch(void* const* d_in, const int* in_sizes, int n_in,
                              void* d_out, int out_size, void* d_ws,
                              size_t ws_size, hipStream_t stream) {
  const float* nodes0 = (const float*)d_in[0];
  const float* edges0 = (const float*)d_in[1];
  const int* senders = (const int*)d_in[2];
  const int* receivers = (const int*)d_in[3];
  const float* enc_w1 = (const float*)d_in[4];
  const float* enc_b1 = (const float*)d_in[5];
  const float* enc_w2 = (const float*)d_in[6];
  const float* enc_b2 = (const float*)d_in[7];
  const float* node_w1 = (const float*)d_in[8];
  const float* node_b1 = (const float*)d_in[9];
  const float* node_w2 = (const float*)d_in[10];
  const float* node_b2 = (const float*)d_in[11];
  const float* edge_w1 = (const float*)d_in[12];
  const float* edge_b1 = (const float*)d_in[13];
  const float* edge_w2 = (const float*)d_in[14];
  const float* edge_b2 = (const float*)d_in[15];
  const float* dec_w1 = (const float*)d_in[16];
  const float* dec_b1 = (const float*)d_in[17];
  const float* dec_w2 = (const float*)d_in[18];
  const float* dec_b2 = (const float*)d_in[19];
  const float* alpha = (const float*)d_in[20];

  // Workspace layout: ~162 MB (< proven 167.6 MB budget).
  char* ws = (char*)d_ws;
  unsigned short* e = (unsigned short*)ws;  // 3.2M x 32 B = 102.4 MB (sorted)
  char* p = ws + (size_t)N_EDGES * HID * 2;
  unsigned int* srecv = (unsigned int*)p;    p += (size_t)N_EDGES * 4;  // 12.8
  unsigned int* sorig = (unsigned int*)p;    p += (size_t)N_EDGES * 4;  // 12.8
  unsigned int* rlist = (unsigned int*)p;    p += (size_t)N_EDGES * 4;  // 12.8
  unsigned int* ssend32 = (unsigned int*)p;  p += (size_t)N_EDGES * 4;  // 12.8
  unsigned short* svalbf = (unsigned short*)p; p += (size_t)N_EDGES * 2;  // 6.4
  int* soff = (int*)p;                       p += (size_t)(N_NODES + 16) * 4;
  int* roff = (int*)p;                       p += (size_t)(N_NODES + 16) * 4;
  float* nbA = (float*)p;                    p += (size_t)N_NODES * 4;
  float* nbB = (float*)p;                    p += (size_t)N_NODES * 4;
  unsigned int* normbits = (unsigned int*)p; p += 64;
  int* gcnt = (int*)p;                       p += NB * 4;
  int* gcnt2 = (int*)p;                      p += NB * 4;
  // build staging aliases e (dead until k_encode):
  unsigned int* pM = (unsigned int*)ws;
  float* pV = (float*)(ws + (size_t)NB * SCAP * 4);
  unsigned int* pO = (unsigned int*)(ws + (size_t)NB * SCAP * 8);
  unsigned int* rpA = (unsigned int*)(ws + (size_t)NB * SCAP * 12);

  const int ngrid = 12500;   // 2 nodes/wave x 4 waves/block -> 100000 nodes
  const int egrid = N_EDGES / BLK;        // 12500
  const int egrid2 = N_EDGES / (BLK * 2); // 6250 (2 edges/thread)

  hipMemsetAsync(normbits, 0, 64 + 2 * NB * 4, stream);  // norm + gcnt + gcnt2
  k_norm<<<512, BLK, 0, stream>>>(edges0, normbits);
  k_split<<<256, 1024, 0, stream>>>(senders, receivers, edges0, gcnt, pM, pV, pO);
  k_bsort1<<<NB, 1024, 0, stream>>>(pM, pV, pO, gcnt, srecv, sorig, svalbf,
                                    ssend32, soff);
  k_rsplit<<<256, 1024, 0, stream>>>(srecv, gcnt2, rpA);
  k_rsort<<<NB, 1024, 0, stream>>>(rpA, gcnt2, rlist, roff);
  k_encode<<<egrid, BLK, 0, stream>>>(svalbf, enc_w1, enc_b1, enc_w2, enc_b2,
                                      normbits, e);  // clobbers staging
  // round 1
  k_aggN<<<ngrid, BLK, 0, stream>>>(e, roff, rlist, soff, nodes0, node_w1,
                                    node_b1, node_w2, node_b2, nbA);
  k_edgeE<<<egrid2, BLK, 0, stream>>>(e, srecv, ssend32, nbA, edge_w1,
                                      edge_b1, edge_w2, edge_b2);
  // round 2
  k_aggN<<<ngrid, BLK, 0, stream>>>(e, roff, rlist, soff, nbA, node_w1,
                                    node_b1, node_w2, node_b2, nbB);
  k_edgeE<<<egrid2, BLK, 0, stream>>>(e, srecv, ssend32, nbB, edge_w1,
                                      edge_b1, edge_w2, edge_b2);
  // round 3
  k_aggN<<<ngrid, BLK, 0, stream>>>(e, roff, rlist, soff, nbB, node_w1,
                                    node_b1, node_w2, node_b2, nbA);
  // final: e3 = edgeMLP(e2, nbA) -> decoder -> delta; then residual add
  k_final<<<egrid2, BLK, 0, stream>>>(e, srecv, ssend32, sorig, nbA, edge_w1,
                                      edge_b1, edge_w2, edge_b2, dec_w1,
                                      dec_b1, dec_w2, dec_b2, normbits, alpha,
                                      (float*)d_out);
  k_resid<<<egrid, BLK, 0, stream>>>(edges0, (float*)d_out);
}

// Round 11
// 846.654 us; speedup vs baseline: 3.4239x; 1.0003x over previous
//
#include <hip/hip_runtime.h>
#include <hip/hip_bf16.h>

#define N_NODES 100000
#define N_EDGES 3200000
#define HID 16
#define NB 256       // buckets; bucket = NPB consecutive nodes
#define NPB 391      // 256*391 = 100096 >= 100000
#define SCAP 15360   // per-bucket staging cap (mean 12500, +25 sigma)
#define RCAP 15360
#define FDEPTH 32    // LDS FIFO depth in split kernels
#define LCAP1 8704   // bsort1 LDS chunk entries (12 B) -> ~102 KB
#define LCAP2 26624  // rsort LDS chunk entries (4 B) -> 104 KB (1 chunk/bucket)

static constexpr int BLK = 256;

__device__ __forceinline__ float frelu(float x) { return fmaxf(x, 0.f); }
__device__ __forceinline__ float bflo(unsigned int u) {
  return __uint_as_float(u << 16);
}
__device__ __forceinline__ float bfhi(unsigned int u) {
  return __uint_as_float(u & 0xFFFF0000u);
}
__device__ __forceinline__ unsigned int packbf(float lo, float hi) {
  __hip_bfloat16 hl = __float2bfloat16(lo), hh = __float2bfloat16(hi);
  return ((unsigned int)(*(unsigned short*)&hh) << 16) |
         (unsigned int)(*(unsigned short*)&hl);
}

union E16 {
  float4 f4[2];
  __hip_bfloat16 h[16];
};

// ---------------------------------------------------------------------------
// K0: norm = max |edges_init|
// ---------------------------------------------------------------------------
__global__ __launch_bounds__(256) void k_norm(const float* __restrict__ edges,
                                              unsigned int* __restrict__ normbits) {
  float m = 0.f;
  for (int i = blockIdx.x * blockDim.x + threadIdx.x; i < N_EDGES;
       i += gridDim.x * blockDim.x)
    m = fmaxf(m, fabsf(edges[i]));
#pragma unroll
  for (int off = 32; off > 0; off >>= 1)
    m = fmaxf(m, __shfl_down(m, off, 64));
  __shared__ float smax[BLK / 64];
  if ((threadIdx.x & 63) == 0) smax[threadIdx.x >> 6] = m;
  __syncthreads();
  if (threadIdx.x == 0) {
    float b = smax[0];
#pragma unroll
    for (int w = 1; w < BLK / 64; ++w) b = fmaxf(b, smax[w]);
    atomicMax(normbits, __float_as_uint(b));
  }
}

// ---------------------------------------------------------------------------
// K1: bucket edges by SENDER via LDS FIFOs (line-granular flushes).
// record: m = (sender_local<<22) | orig_edge(22b), v = edges_init, o = recv
// ---------------------------------------------------------------------------
__global__ __launch_bounds__(1024) void k_split(
    const int* __restrict__ senders, const int* __restrict__ receivers,
    const float* __restrict__ edges, int* __restrict__ gcnt,
    unsigned int* __restrict__ pM, float* __restrict__ pV,
    unsigned int* __restrict__ pO) {
  __shared__ __align__(16) unsigned int fM[NB][FDEPTH];
  __shared__ __align__(16) unsigned int fV[NB][FDEPTH];
  __shared__ __align__(16) unsigned int fO[NB][FDEPTH];
  __shared__ int fcnt[NB];
  const int t = threadIdx.x;
  if (t < NB) fcnt[t] = 0;
  __syncthreads();
  const int e0 = blockIdx.x * (N_EDGES / 256);
  const int e1 = e0 + (N_EDGES / 256);
  for (int base = e0; base < e1; base += 1024) {
    const int i = base + t;
    if (i < e1) {
      int s = senders[i];
      unsigned int b = (unsigned int)s / NPB;
      unsigned int m = (((unsigned int)s - b * NPB) << 22) | (unsigned int)i;
      unsigned int v = __float_as_uint(edges[i]);
      unsigned int o = (unsigned int)receivers[i];
      int pos = atomicAdd(&fcnt[b], 1);
      if (pos < FDEPTH) {
        fM[b][pos] = m; fV[b][pos] = v; fO[b][pos] = o;
      } else {  // rare overflow: direct append
        int gb = atomicAdd(&gcnt[b], 1);
        if (gb < SCAP) {
          pM[(size_t)b * SCAP + gb] = m;
          pV[(size_t)b * SCAP + gb] = __uint_as_float(v);
          pO[(size_t)b * SCAP + gb] = o;
        }
      }
    }
    __syncthreads();
    const bool last = (base + 1024 >= e1);
    if (t < NB) {
      int c = fcnt[t]; if (c > FDEPTH) c = FDEPTH;
      int nf = last ? c : (c & ~15);
      if (nf > 0) {
        int gb = atomicAdd(&gcnt[t], nf);
        size_t db = (size_t)t * SCAP + gb;
        if ((gb & 3) == 0 && gb + nf <= SCAP) {
          int k = 0;
          for (; k + 4 <= nf; k += 4) {
            *(uint4*)(pM + db + k) = *(const uint4*)(&fM[t][k]);
            *(uint4*)((unsigned int*)pV + db + k) = *(const uint4*)(&fV[t][k]);
            *(uint4*)(pO + db + k) = *(const uint4*)(&fO[t][k]);
          }
          for (; k < nf; ++k) {
            pM[db + k] = fM[t][k]; pV[db + k] = __uint_as_float(fV[t][k]);
            pO[db + k] = fO[t][k];
          }
        } else {
          for (int k = 0; k < nf; ++k)
            if (gb + k < SCAP) {
              pM[db + k] = fM[t][k]; pV[db + k] = __uint_as_float(fV[t][k]);
              pO[db + k] = fO[t][k];
            }
        }
        int res = c - nf;
        for (int k = 0; k < res; ++k) {
          fM[t][k] = fM[t][nf + k]; fV[t][k] = fV[t][nf + k];
          fO[t][k] = fO[t][nf + k];
        }
        fcnt[t] = res;
      } else fcnt[t] = c;
    }
    __syncthreads();
  }
}

// ---------------------------------------------------------------------------
// K2: per-bucket counting sort by sender_local -> EXACT global sender CSR.
// Writes srecv/sorig/svalbf/ssend32 (global sender id) + soff.
// ---------------------------------------------------------------------------
__global__ __launch_bounds__(1024) void k_bsort1(
    const unsigned int* __restrict__ pM, const float* __restrict__ pV,
    const unsigned int* __restrict__ pO, const int* __restrict__ gcnt,
    unsigned int* __restrict__ srecv, unsigned int* __restrict__ sorig,
    unsigned short* __restrict__ svalbf, unsigned int* __restrict__ ssend32,
    int* __restrict__ soff) {
  __shared__ unsigned int sM[LCAP1];
  __shared__ float sV[LCAP1];
  __shared__ unsigned int sO[LCAP1];
  __shared__ int hist[NPB], pref[NPB + 1], sc[NPB], cur[NPB];
  __shared__ int bb[NB];
  __shared__ int base_s;
  const int b = blockIdx.x, t = threadIdx.x, nt = blockDim.x;
  if (t < NB) { int c = gcnt[t]; bb[t] = c > SCAP ? SCAP : c; }
  for (int k = t; k < NPB; k += nt) hist[k] = 0;
  __syncthreads();
  if (t == 0) { int s = 0; for (int k = 0; k < b; ++k) s += bb[k]; base_s = s; }
  int nb = gcnt[b]; if (nb > SCAP) nb = SCAP;
  const unsigned int* PM = pM + (size_t)b * SCAP;
  const float* PV = pV + (size_t)b * SCAP;
  const unsigned int* PO = pO + (size_t)b * SCAP;
  for (int i = t; i < nb; i += nt) atomicAdd(&hist[PM[i] >> 22], 1);
  __syncthreads();
  if (t < NPB) sc[t] = hist[t];
  __syncthreads();
  for (int d = 1; d < NPB; d <<= 1) {
    int add = 0;
    if (t < NPB && t >= d) add = sc[t - d];
    __syncthreads();
    if (t < NPB && t >= d) sc[t] += add;
    __syncthreads();
  }
  if (t < NPB) pref[t] = sc[t] - hist[t];
  if (t == 0) pref[NPB] = sc[NPB - 1];
  __syncthreads();
  const int base = base_s;
  const int node0 = b * NPB;
  for (int k = t; k < NPB; k += nt) {
    int n = node0 + k;
    if (n < N_NODES) soff[n] = base + pref[k];
  }
  if (b == NB - 1 && t == 0) soff[N_NODES] = base + nb;
  __syncthreads();
  int klo = 0;
  while (klo < NPB) {
    int base0 = pref[klo];
    int khi = klo;
    while (khi < NPB && pref[khi + 1] - base0 <= LCAP1) ++khi;
    if (khi == klo) khi = klo + 1;  // safety
    for (int k = klo + t; k < khi; k += nt) cur[k] = pref[k];
    __syncthreads();
    for (int i = t; i < nb; i += nt) {
      unsigned int m = PM[i];
      int key = (int)(m >> 22);
      if (key >= klo && key < khi) {
        int p = atomicAdd(&cur[key], 1) - base0;
        if (p < LCAP1) { sM[p] = m; sV[p] = PV[i]; sO[p] = PO[i]; }
      }
    }
    __syncthreads();
    int csz = pref[khi] - base0;
    for (int i = t; i < csz; i += nt) {
      int g = base + base0 + i;
      unsigned int m = sM[i];
      srecv[g] = sO[i]; sorig[g] = m & 0x3FFFFFu;
      ssend32[g] = (unsigned int)(node0 + (int)(m >> 22));
      __hip_bfloat16 hb = __float2bfloat16(sV[i]);
      svalbf[g] = *(unsigned short*)&hb;
    }
    __syncthreads();
    klo = khi;
  }
}

// ---------------------------------------------------------------------------
// K3: bucket sorted edges by RECEIVER. a = (recv_local<<22) | sorted_idx
// ---------------------------------------------------------------------------
__global__ __launch_bounds__(1024) void k_rsplit(
    const unsigned int* __restrict__ srecv, int* __restrict__ gcnt2,
    unsigned int* __restrict__ rpA) {
  __shared__ __align__(16) unsigned int fA[NB][FDEPTH];
  __shared__ int fcnt[NB];
  const int t = threadIdx.x;
  if (t < NB) fcnt[t] = 0;
  __syncthreads();
  const int e0 = blockIdx.x * (N_EDGES / 256);
  const int e1 = e0 + (N_EDGES / 256);
  for (int base = e0; base < e1; base += 1024) {
    const int i = base + t;
    if (i < e1) {
      unsigned int r = srecv[i];
      unsigned int b = r / NPB;
      unsigned int a = ((r - b * NPB) << 22) | (unsigned int)i;
      int pos = atomicAdd(&fcnt[b], 1);
      if (pos < FDEPTH) {
        fA[b][pos] = a;
      } else {
        int gb = atomicAdd(&gcnt2[b], 1);
        if (gb < RCAP) rpA[(size_t)b * RCAP + gb] = a;
      }
    }
    __syncthreads();
    const bool last = (base + 1024 >= e1);
    if (t < NB) {
      int c = fcnt[t]; if (c > FDEPTH) c = FDEPTH;
      int nf = last ? c : (c & ~15);
      if (nf > 0) {
        int gb = atomicAdd(&gcnt2[t], nf);
        size_t db = (size_t)t * RCAP + gb;
        if ((gb & 3) == 0 && gb + nf <= RCAP) {
          int k = 0;
          for (; k + 4 <= nf; k += 4)
            *(uint4*)(rpA + db + k) = *(const uint4*)(&fA[t][k]);
          for (; k < nf; ++k) rpA[db + k] = fA[t][k];
        } else {
          for (int k = 0; k < nf; ++k)
            if (gb + k < RCAP) rpA[db + k] = fA[t][k];
        }
        int res = c - nf;
        for (int k = 0; k < res; ++k) fA[t][k] = fA[t][nf + k];
        fcnt[t] = res;
      } else fcnt[t] = c;
    }
    __syncthreads();
  }
}

// ---------------------------------------------------------------------------
// K4: per-bucket counting sort by recv_local -> receiver CSR (roff) + rlist.
// ---------------------------------------------------------------------------
__global__ __launch_bounds__(1024) void k_rsort(
    const unsigned int* __restrict__ rpA, const int* __restrict__ gcnt2,
    unsigned int* __restrict__ rlist, int* __restrict__ roff) {
  __shared__ unsigned int sA[LCAP2];
  __shared__ int hist[NPB], pref[NPB + 1], sc[NPB], cur[NPB];
  __shared__ int bb[NB];
  __shared__ int base_s;
  const int b = blockIdx.x, t = threadIdx.x, nt = blockDim.x;
  if (t < NB) { int c = gcnt2[t]; bb[t] = c > RCAP ? RCAP : c; }
  for (int k = t; k < NPB; k += nt) hist[k] = 0;
  __syncthreads();
  if (t == 0) { int s = 0; for (int k = 0; k < b; ++k) s += bb[k]; base_s = s; }
  int nb = gcnt2[b]; if (nb > RCAP) nb = RCAP;
  const unsigned int* PA = rpA + (size_t)b * RCAP;
  for (int i = t; i < nb; i += nt) atomicAdd(&hist[PA[i] >> 22], 1);
  __syncthreads();
  if (t < NPB) sc[t] = hist[t];
  __syncthreads();
  for (int d = 1; d < NPB; d <<= 1) {
    int add = 0;
    if (t < NPB && t >= d) add = sc[t - d];
    __syncthreads();
    if (t < NPB && t >= d) sc[t] += add;
    __syncthreads();
  }
  if (t < NPB) pref[t] = sc[t] - hist[t];
  if (t == 0) pref[NPB] = sc[NPB - 1];
  __syncthreads();
  const int base = base_s;
  const int node0 = b * NPB;
  for (int k = t; k < NPB; k += nt) {
    int n = node0 + k;
    if (n < N_NODES) roff[n] = base + pref[k];
  }
  if (b == NB - 1 && t == 0) roff[N_NODES] = base + nb;
  __syncthreads();
  int klo = 0;
  while (klo < NPB) {
    int base0 = pref[klo];
    int khi = klo;
    while (khi < NPB && pref[khi + 1] - base0 <= LCAP2) ++khi;
    if (khi == klo) khi = klo + 1;
    for (int k = klo + t; k < khi; k += nt) cur[k] = pref[k];
    __syncthreads();
    for (int i = t; i < nb; i += nt) {
      unsigned int a = PA[i];
      int key = (int)(a >> 22);
      if (key >= klo && key < khi) {
        int p = atomicAdd(&cur[key], 1) - base0;
        if (p < LCAP2) sA[p] = a;
      }
    }
    __syncthreads();
    int csz = pref[khi] - base0;
    for (int i = t; i < csz; i += nt)
      rlist[base + base0 + i] = sA[i] & 0x3FFFFFu;
    __syncthreads();
    klo = khi;
  }
}

// ---------------------------------------------------------------------------
// K5: edge encoder (1 -> HID -> HID) in sorted order, coalesced.
// ---------------------------------------------------------------------------
__global__ __launch_bounds__(256) void k_encode(
    const unsigned short* __restrict__ svalbf, const float* __restrict__ w1,
    const float* __restrict__ b1, const float* __restrict__ w2,
    const float* __restrict__ b2, const unsigned int* __restrict__ normbits,
    unsigned short* __restrict__ e) {
  int i = blockIdx.x * blockDim.x + threadIdx.x;
  float norm = __uint_as_float(*normbits);
  float x = bflo((unsigned int)svalbf[i]) / norm;
  float h[HID];
#pragma unroll
  for (int j = 0; j < HID; ++j) h[j] = frelu(fmaf(w1[j], x, b1[j]));
  E16 o;
#pragma unroll
  for (int j = 0; j < HID; ++j) {
    float acc = b2[j];
#pragma unroll
    for (int k = 0; k < HID; ++k) acc = fmaf(w2[j * HID + k], h[k], acc);
    o.h[j] = __float2bfloat16(acc);
  }
  float4* ep = (float4*)(e + (size_t)i * HID);
  ep[0] = o.f4[0];
  ep[1] = o.f4[1];
}

// ---------------------------------------------------------------------------
// K6: FUSED receiver-gather + sender-stream + node MLP. Phase A unrolled x2:
// two rlist entries (adjacent, coalesced) and two INDEPENDENT scattered 16 B
// loads in flight per lane per iteration — round-10 counters (VALU 31%, BW
// 35% of peak, dep chain rlist->e) say phase A is latency-depth-bound, not
// pipe-bound. Full chunks unmasked; tail predicated, mask-as-FMA.
// ---------------------------------------------------------------------------
__global__ __launch_bounds__(256) void k_aggN(
    const unsigned short* __restrict__ e, const int* __restrict__ roff,
    const unsigned int* __restrict__ rlist, const int* __restrict__ soff,
    const float* __restrict__ nodesr, const float* __restrict__ nw1,
    const float* __restrict__ nb1_, const float* __restrict__ nw2,
    const float* __restrict__ nb2_, float* __restrict__ nodesw) {
  int wave = (blockIdx.x * blockDim.x + threadIdx.x) >> 6;
  int lane = threadIdx.x & 63, half = lane >> 5, l32 = lane & 31;
  int n = wave * 2 + half;
  // ---- phase A: receiver-side scattered gather (x2 unrolled) ----
  int sub = l32 & 1, j16 = l32 >> 1;
  int r0 = roff[n], rdeg = roff[n + 1] - r0;
  float ar[8] = {0, 0, 0, 0, 0, 0, 0, 0};
  int q0 = 0;
  int full2 = rdeg & ~31;
  for (; q0 < full2; q0 += 32) {
    int idx0 = r0 + q0 + j16;
    unsigned int si0 = rlist[idx0];
    unsigned int si1 = rlist[idx0 + 16];
    uint4 ra = *(const uint4*)(e + (size_t)si0 * HID + sub * 8);
    uint4 rb = *(const uint4*)(e + (size_t)si1 * HID + sub * 8);
    ar[0] += bflo(ra.x); ar[1] += bfhi(ra.x);
    ar[2] += bflo(ra.y); ar[3] += bfhi(ra.y);
    ar[4] += bflo(ra.z); ar[5] += bfhi(ra.z);
    ar[6] += bflo(ra.w); ar[7] += bfhi(ra.w);
    ar[0] += bflo(rb.x); ar[1] += bfhi(rb.x);
    ar[2] += bflo(rb.y); ar[3] += bfhi(rb.y);
    ar[4] += bflo(rb.z); ar[5] += bfhi(rb.z);
    ar[6] += bflo(rb.w); ar[7] += bfhi(rb.w);
  }
  if (q0 + 16 <= rdeg) {  // one full unmasked step
    int idx = r0 + q0 + j16;
    unsigned int si = rlist[idx];
    uint4 raw = *(const uint4*)(e + (size_t)si * HID + sub * 8);
    ar[0] += bflo(raw.x); ar[1] += bfhi(raw.x);
    ar[2] += bflo(raw.y); ar[3] += bfhi(raw.y);
    ar[4] += bflo(raw.z); ar[5] += bfhi(raw.z);
    ar[6] += bflo(raw.w); ar[7] += bfhi(raw.w);
    q0 += 16;
  }
  if (q0 < rdeg) {  // masked tail
    int slot = q0 + j16;
    bool ok = slot < rdeg;
    int idx = r0 + (ok ? slot : 0);
    unsigned int si = rlist[idx];
    uint4 raw = *(const uint4*)(e + (size_t)si * HID + sub * 8);
    float okf = ok ? 1.f : 0.f;
    ar[0] = fmaf(bflo(raw.x), okf, ar[0]); ar[1] = fmaf(bfhi(raw.x), okf, ar[1]);
    ar[2] = fmaf(bflo(raw.y), okf, ar[2]); ar[3] = fmaf(bfhi(raw.y), okf, ar[3]);
    ar[4] = fmaf(bflo(raw.z), okf, ar[4]); ar[5] = fmaf(bfhi(raw.z), okf, ar[5]);
    ar[6] = fmaf(bflo(raw.w), okf, ar[6]); ar[7] = fmaf(bfhi(raw.w), okf, ar[7]);
  }
#pragma unroll
  for (int off = 16; off >= 2; off >>= 1)
#pragma unroll
    for (int c = 0; c < 8; ++c) ar[c] += __shfl_down(ar[c], off, 64);
  // ---- phase B: sender-side coalesced stream ----
  int s0 = soff[n], sdeg = soff[n + 1] - s0;
  float as[16];
#pragma unroll
  for (int c = 0; c < 16; ++c) as[c] = 0.f;
  int fullB = sdeg & ~31;
  int c0 = 0;
  for (; c0 < fullB; c0 += 32) {
    int idx = s0 + c0 + l32;
    uint4 ra = *(const uint4*)(e + (size_t)idx * HID);
    uint4 rb = *(const uint4*)(e + (size_t)idx * HID + 8);
    as[0] += bflo(ra.x);  as[1] += bfhi(ra.x);
    as[2] += bflo(ra.y);  as[3] += bfhi(ra.y);
    as[4] += bflo(ra.z);  as[5] += bfhi(ra.z);
    as[6] += bflo(ra.w);  as[7] += bfhi(ra.w);
    as[8] += bflo(rb.x);  as[9] += bfhi(rb.x);
    as[10] += bflo(rb.y); as[11] += bfhi(rb.y);
    as[12] += bflo(rb.z); as[13] += bfhi(rb.z);
    as[14] += bflo(rb.w); as[15] += bfhi(rb.w);
  }
  if (c0 < sdeg) {
    int k = c0 + l32;
    bool ok = k < sdeg;
    int idx = s0 + (ok ? k : 0);
    uint4 ra = *(const uint4*)(e + (size_t)idx * HID);
    uint4 rb = *(const uint4*)(e + (size_t)idx * HID + 8);
    float okf = ok ? 1.f : 0.f;
    as[0] = fmaf(bflo(ra.x), okf, as[0]);  as[1] = fmaf(bfhi(ra.x), okf, as[1]);
    as[2] = fmaf(bflo(ra.y), okf, as[2]);  as[3] = fmaf(bfhi(ra.y), okf, as[3]);
    as[4] = fmaf(bflo(ra.z), okf, as[4]);  as[5] = fmaf(bfhi(ra.z), okf, as[5]);
    as[6] = fmaf(bflo(ra.w), okf, as[6]);  as[7] = fmaf(bfhi(ra.w), okf, as[7]);
    as[8] = fmaf(bflo(rb.x), okf, as[8]);  as[9] = fmaf(bfhi(rb.x), okf, as[9]);
    as[10] = fmaf(bflo(rb.y), okf, as[10]); as[11] = fmaf(bfhi(rb.y), okf, as[11]);
    as[12] = fmaf(bflo(rb.z), okf, as[12]); as[13] = fmaf(bfhi(rb.z), okf, as[13]);
    as[14] = fmaf(bflo(rb.w), okf, as[14]); as[15] = fmaf(bfhi(rb.w), okf, as[15]);
  }
#pragma unroll
  for (int off = 16; off >= 1; off >>= 1)
#pragma unroll
    for (int c = 0; c < 16; ++c) as[c] += __shfl_down(as[c], off, 64);
  // ---- node MLP on lanes l32<16 ----
  float aS[16], aR[16];
#pragma unroll
  for (int c = 0; c < 16; ++c) aS[c] = __shfl(as[c], half * 32, 64);
#pragma unroll
  for (int k = 0; k < 8; ++k) aR[k] = __shfl(ar[k], half * 32, 64);
#pragma unroll
  for (int k = 0; k < 8; ++k) aR[8 + k] = __shfl(ar[k], half * 32 + 1, 64);
  float nsv = nodesr[n];
  float pv = 0.f;
  if (l32 < 16) {
    int j = l32;
    float a1 = fmaf(nw1[j * 33], nsv, nb1_[j]);
#pragma unroll
    for (int k = 0; k < 16; ++k) a1 = fmaf(nw1[j * 33 + 1 + k], aS[k], a1);
#pragma unroll
    for (int k = 0; k < 16; ++k) a1 = fmaf(nw1[j * 33 + 17 + k], aR[k], a1);
    pv = nw2[j] * frelu(a1);
  }
#pragma unroll
  for (int off = 8; off >= 1; off >>= 1) pv += __shfl_down(pv, off, 64);
  if (l32 == 0) nodesw[n] = pv + nb2_[0];
}

// ---------------------------------------------------------------------------
// K7: edge MLP, 2 EDGES PER THREAD. Layer-2 chunked by 8 outputs with
// immediate 16 B stores. (256,4): 128-VGPR cap, >=4 waves/SIMD.
// ---------------------------------------------------------------------------
__global__ __launch_bounds__(256, 4) void k_edgeE(
    unsigned short* __restrict__ e, const unsigned int* __restrict__ srecv,
    const unsigned int* __restrict__ ssend32, const float* __restrict__ nodes,
    const float* __restrict__ w1, const float* __restrict__ b1,
    const float* __restrict__ w2, const float* __restrict__ b2) {
  int i0 = (blockIdx.x * blockDim.x + threadIdx.x) * 2;
  float ns[2], nr[2];
#pragma unroll
  for (int q = 0; q < 2; ++q) {
    ns[q] = nodes[ssend32[i0 + q]];
    nr[q] = nodes[srecv[i0 + q]];
  }
  unsigned int pk[2][8];
#pragma unroll
  for (int q = 0; q < 2; ++q) {
    const uint4* ep = (const uint4*)(e + (size_t)(i0 + q) * HID);
    uint4 ra = ep[0], rb = ep[1];
    pk[q][0] = ra.x; pk[q][1] = ra.y; pk[q][2] = ra.z; pk[q][3] = ra.w;
    pk[q][4] = rb.x; pk[q][5] = rb.y; pk[q][6] = rb.z; pk[q][7] = rb.w;
  }
  float h[2][16];
#pragma unroll
  for (int j = 0; j < 16; ++j) {
    float wA = w1[j * 18 + 16], wB = w1[j * 18 + 17], bb = b1[j];
#pragma unroll
    for (int q = 0; q < 2; ++q)
      h[q][j] = fmaf(wA, ns[q], fmaf(wB, nr[q], bb));
  }
#pragma unroll
  for (int kp = 0; kp < 8; ++kp) {
    float x0[2], x1[2];
#pragma unroll
    for (int q = 0; q < 2; ++q) {
      x0[q] = bflo(pk[q][kp]);
      x1[q] = bfhi(pk[q][kp]);
    }
#pragma unroll
    for (int j = 0; j < 16; ++j) {
      float wA = w1[j * 18 + 2 * kp], wB = w1[j * 18 + 2 * kp + 1];
#pragma unroll
      for (int q = 0; q < 2; ++q)
        h[q][j] = fmaf(wB, x1[q], fmaf(wA, x0[q], h[q][j]));
    }
  }
#pragma unroll
  for (int j = 0; j < 16; ++j)
#pragma unroll
    for (int q = 0; q < 2; ++q) h[q][j] = frelu(h[q][j]);
#pragma unroll
  for (int c0 = 0; c0 < 16; c0 += 8) {
    float y[2][8];
#pragma unroll
    for (int cc = 0; cc < 8; ++cc) {
      float bv = b2[c0 + cc];
#pragma unroll
      for (int q = 0; q < 2; ++q) y[q][cc] = bv;
    }
#pragma unroll
    for (int j = 0; j < 16; ++j) {
#pragma unroll
      for (int cc = 0; cc < 8; ++cc) {
        float wv = w2[(c0 + cc) * HID + j];
#pragma unroll
        for (int q = 0; q < 2; ++q) y[q][cc] = fmaf(wv, h[q][j], y[q][cc]);
      }
    }
#pragma unroll
    for (int q = 0; q < 2; ++q) {
      uint4 o = make_uint4(packbf(y[q][0], y[q][1]), packbf(y[q][2], y[q][3]),
                           packbf(y[q][4], y[q][5]), packbf(y[q][6], y[q][7]));
      *(uint4*)(e + (size_t)(i0 + q) * HID + c0) = o;
    }
  }
}

// ---------------------------------------------------------------------------
// K8: final — round-3 edge MLP + decoder, 2 EDGES PER THREAD. (256,4).
// Writes delta only.
// ---------------------------------------------------------------------------
__global__ __launch_bounds__(256, 4) void k_final(
    const unsigned short* __restrict__ e, const unsigned int* __restrict__ srecv,
    const unsigned int* __restrict__ ssend32, const unsigned int* __restrict__ sorig,
    const float* __restrict__ nodes, const float* __restrict__ ew1,
    const float* __restrict__ eb1, const float* __restrict__ ew2,
    const float* __restrict__ eb2, const float* __restrict__ dw1,
    const float* __restrict__ db1, const float* __restrict__ dw2,
    const float* __restrict__ db2, const unsigned int* __restrict__ normbits,
    const float* __restrict__ alpha, float* __restrict__ out) {
  int i0 = (blockIdx.x * blockDim.x + threadIdx.x) * 2;
  float ns[2], nr[2];
#pragma unroll
  for (int q = 0; q < 2; ++q) {
    ns[q] = nodes[ssend32[i0 + q]];
    nr[q] = nodes[srecv[i0 + q]];
  }
  unsigned int pk[2][8];
#pragma unroll
  for (int q = 0; q < 2; ++q) {
    const uint4* ep = (const uint4*)(e + (size_t)(i0 + q) * HID);
    uint4 ra = ep[0], rb = ep[1];
    pk[q][0] = ra.x; pk[q][1] = ra.y; pk[q][2] = ra.z; pk[q][3] = ra.w;
    pk[q][4] = rb.x; pk[q][5] = rb.y; pk[q][6] = rb.z; pk[q][7] = rb.w;
  }
  float h[2][16];
#pragma unroll
  for (int j = 0; j < 16; ++j) {
    float wA = ew1[j * 18 + 16], wB = ew1[j * 18 + 17], bb = eb1[j];
#pragma unroll
    for (int q = 0; q < 2; ++q)
      h[q][j] = fmaf(wA, ns[q], fmaf(wB, nr[q], bb));
  }
#pragma unroll
  for (int kp = 0; kp < 8; ++kp) {
    float x0[2], x1[2];
#pragma unroll
    for (int q = 0; q < 2; ++q) {
      x0[q] = bflo(pk[q][kp]);
      x1[q] = bfhi(pk[q][kp]);
    }
#pragma unroll
    for (int j = 0; j < 16; ++j) {
      float wA = ew1[j * 18 + 2 * kp], wB = ew1[j * 18 + 2 * kp + 1];
#pragma unroll
      for (int q = 0; q < 2; ++q)
        h[q][j] = fmaf(wB, x1[q], fmaf(wA, x0[q], h[q][j]));
    }
  }
#pragma unroll
  for (int j = 0; j < 16; ++j)
#pragma unroll
    for (int q = 0; q < 2; ++q) h[q][j] = frelu(h[q][j]);
  float y[2][16];
#pragma unroll
  for (int c = 0; c < 16; ++c) {
    float bv = eb2[c];
#pragma unroll
    for (int q = 0; q < 2; ++q) y[q][c] = bv;
  }
#pragma unroll
  for (int j = 0; j < 16; ++j) {
#pragma unroll
    for (int c = 0; c < 16; ++c) {
      float wv = ew2[c * HID + j];
#pragma unroll
      for (int q = 0; q < 2; ++q) y[q][c] = fmaf(wv, h[q][j], y[q][c]);
    }
  }
  float d[2] = {db2[0], db2[0]};
#pragma unroll
  for (int j = 0; j < 16; ++j) {
    float a1[2] = {db1[j], db1[j]};
#pragma unroll
    for (int k = 0; k < 16; ++k) {
      float wv = dw1[j * HID + k];
#pragma unroll
      for (int q = 0; q < 2; ++q) a1[q] = fmaf(wv, y[q][k], a1[q]);
    }
    float wd = dw2[j];
#pragma unroll
    for (int q = 0; q < 2; ++q) d[q] = fmaf(wd, frelu(a1[q]), d[q]);
  }
  float alphaN = alpha[0] * __uint_as_float(*normbits);
#pragma unroll
  for (int q = 0; q < 2; ++q) out[sorig[i0 + q]] = alphaN * d[q];
}

// ---------------------------------------------------------------------------
// K9: residual add, fully coalesced: out[i] += edges_init[i]
// ---------------------------------------------------------------------------
__global__ __launch_bounds__(256) void k_resid(const float* __restrict__ edges,
                                               float* __restrict__ out) {
  int i = blockIdx.x * blockDim.x + threadIdx.x;
  out[i] += edges[i];
}

// ---------------------------------------------------------------------------
extern "C" void kernel_launch(void* const* d_in, const int* in_sizes, int n_in,
                              void* d_out, int out_size, void* d_ws,
                              size_t ws_size, hipStream_t stream) {
  const float* nodes0 = (const float*)d_in[0];
  const float* edges0 = (const float*)d_in[1];
  const int* senders = (const int*)d_in[2];
  const int* receivers = (const int*)d_in[3];
  const float* enc_w1 = (const float*)d_in[4];
  const float* enc_b1 = (const float*)d_in[5];
  const float* enc_w2 = (const float*)d_in[6];
  const float* enc_b2 = (const float*)d_in[7];
  const float* node_w1 = (const float*)d_in[8];
  const float* node_b1 = (const float*)d_in[9];
  const float* node_w2 = (const float*)d_in[10];
  const float* node_b2 = (const float*)d_in[11];
  const float* edge_w1 = (const float*)d_in[12];
  const float* edge_b1 = (const float*)d_in[13];
  const float* edge_w2 = (const float*)d_in[14];
  const float* edge_b2 = (const float*)d_in[15];
  const float* dec_w1 = (const float*)d_in[16];
  const float* dec_b1 = (const float*)d_in[17];
  const float* dec_w2 = (const float*)d_in[18];
  const float* dec_b2 = (const float*)d_in[19];
  const float* alpha = (const float*)d_in[20];

  // Workspace layout: ~162 MB (< proven 167.6 MB budget).
  char* ws = (char*)d_ws;
  unsigned short* e = (unsigned short*)ws;  // 3.2M x 32 B = 102.4 MB (sorted)
  char* p = ws + (size_t)N_EDGES * HID * 2;
  unsigned int* srecv = (unsigned int*)p;    p += (size_t)N_EDGES * 4;  // 12.8
  unsigned int* sorig = (unsigned int*)p;    p += (size_t)N_EDGES * 4;  // 12.8
  unsigned int* rlist = (unsigned int*)p;    p += (size_t)N_EDGES * 4;  // 12.8
  unsigned int* ssend32 = (unsigned int*)p;  p += (size_t)N_EDGES * 4;  // 12.8
  unsigned short* svalbf = (unsigned short*)p; p += (size_t)N_EDGES * 2;  // 6.4
  int* soff = (int*)p;                       p += (size_t)(N_NODES + 16) * 4;
  int* roff = (int*)p;                       p += (size_t)(N_NODES + 16) * 4;
  float* nbA = (float*)p;                    p += (size_t)N_NODES * 4;
  float* nbB = (float*)p;                    p += (size_t)N_NODES * 4;
  unsigned int* normbits = (unsigned int*)p; p += 64;
  int* gcnt = (int*)p;                       p += NB * 4;
  int* gcnt2 = (int*)p;                      p += NB * 4;
  // build staging aliases e (dead until k_encode):
  unsigned int* pM = (unsigned int*)ws;
  float* pV = (float*)(ws + (size_t)NB * SCAP * 4);
  unsigned int* pO = (unsigned int*)(ws + (size_t)NB * SCAP * 8);
  unsigned int* rpA = (unsigned int*)(ws + (size_t)NB * SCAP * 12);

  const int ngrid = 12500;   // 2 nodes/wave x 4 waves/block -> 100000 nodes
  const int egrid = N_EDGES / BLK;        // 12500
  const int egrid2 = N_EDGES / (BLK * 2); // 6250 (2 edges/thread)

  hipMemsetAsync(normbits, 0, 64 + 2 * NB * 4, stream);  // norm + gcnt + gcnt2
  k_norm<<<512, BLK, 0, stream>>>(edges0, normbits);
  k_split<<<256, 1024, 0, stream>>>(senders, receivers, edges0, gcnt, pM, pV, pO);
  k_bsort1<<<NB, 1024, 0, stream>>>(pM, pV, pO, gcnt, srecv, sorig, svalbf,
                                    ssend32, soff);
  k_rsplit<<<256, 1024, 0, stream>>>(srecv, gcnt2, rpA);
  k_rsort<<<NB, 1024, 0, stream>>>(rpA, gcnt2, rlist, roff);
  k_encode<<<egrid, BLK, 0, stream>>>(svalbf, enc_w1, enc_b1, enc_w2, enc_b2,
                                      normbits, e);  // clobbers staging
  // round 1
  k_aggN<<<ngrid, BLK, 0, stream>>>(e, roff, rlist, soff, nodes0, node_w1,
                                    node_b1, node_w2, node_b2, nbA);
  k_edgeE<<<egrid2, BLK, 0, stream>>>(e, srecv, ssend32, nbA, edge_w1,
                                      edge_b1, edge_w2, edge_b2);
  // round 2
  k_aggN<<<ngrid, BLK, 0, stream>>>(e, roff, rlist, soff, nbA, node_w1,
                                    node_b1, node_w2, node_b2, nbB);
  k_edgeE<<<egrid2, BLK, 0, stream>>>(e, srecv, ssend32, nbB, edge_w1,
                                      edge_b1, edge_w2, edge_b2);
  // round 3
  k_aggN<<<ngrid, BLK, 0, stream>>>(e, roff, rlist, soff, nbB, node_w1,
                                    node_b1, node_w2, node_b2, nbA);
  // final: e3 = edgeMLP(e2, nbA) -> decoder -> delta; then residual add
  k_final<<<egrid2, BLK, 0, stream>>>(e, srecv, ssend32, sorig, nbA, edge_w1,
                                      edge_b1, edge_w2, edge_b2, dec_w1,
                                      dec_b1, dec_w2, dec_b2, normbits, alpha,
                                      (float*)d_out);
  k_resid<<<egrid, BLK, 0, stream>>>(edges0, (float*)d_out);
}